// Round 1
// baseline (693.315 us; speedup 1.0000x reference)
//
#include <hip/hip_runtime.h>
#include <math.h>

#define NB 32
#define ND 128
#define NC 1024
#define NQ 256
#define NEGV (-1e30f)

// ---------------- K0: bias vectors cb[b,i] = sum_k C[b,k,i]*w1[k]; qb[b,j] = sum_k Q[b,k,j]*w2[k]
__global__ __launch_bounds__(256) void k0_bias(const float* __restrict__ C, const float* __restrict__ Q,
                                               const float* __restrict__ W0,
                                               float* __restrict__ cb, float* __restrict__ qb) {
  int idx = blockIdx.x * 256 + threadIdx.x;
  if (idx < NB * NC) {
    int b = idx >> 10, i = idx & (NC - 1);
    const float* base = C + ((size_t)b * ND) * NC + i;
    float s = 0.f;
    #pragma unroll 8
    for (int k = 0; k < ND; ++k) s += base[(size_t)k * NC] * W0[k];
    cb[idx] = s;
  } else {
    int r = idx - NB * NC;
    if (r < NB * NQ) {
      int b = r >> 8, j = r & (NQ - 1);
      const float* base = Q + ((size_t)b * ND) * NQ + j;
      float s = 0.f;
      #pragma unroll 8
      for (int k = 0; k < ND; ++k) s += base[(size_t)k * NQ] * W0[ND + k];
      qb[r] = s;
    }
  }
}

// ---------------- K1: S[b,i,j] = sum_k (C*w3)[b,k,i]*Q[b,k,j] + cb[b,i] + qb[b,j]
__global__ __launch_bounds__(256) void k1_s(const float* __restrict__ C, const float* __restrict__ Q,
                                            const float* __restrict__ W0,
                                            const float* __restrict__ cb, const float* __restrict__ qb,
                                            float* __restrict__ S) {
  extern __shared__ float sm1[];
  float* Cs = sm1;             // [128][64]
  float* Qs = sm1 + ND * 64;   // [128][64]
  int b = blockIdx.y;
  int i0 = (blockIdx.x & 15) * 64;
  int j0 = (blockIdx.x >> 4) * 64;
  int t = threadIdx.x;
  const float* Cb = C + (size_t)b * ND * NC;
  const float* Qb = Q + (size_t)b * ND * NQ;
  int f4 = (t & 15) * 4;
  #pragma unroll
  for (int it = 0; it < 8; ++it) {
    int k = (t >> 4) + it * 16;
    float w = W0[2 * ND + k];
    float4 v = *(const float4*)(Cb + (size_t)k * NC + i0 + f4);
    v.x *= w; v.y *= w; v.z *= w; v.w *= w;
    *(float4*)(&Cs[k * 64 + f4]) = v;
    *(float4*)(&Qs[k * 64 + f4]) = *(const float4*)(Qb + (size_t)k * NQ + j0 + f4);
  }
  __syncthreads();
  int tj = t & 15, ti = t >> 4;
  float acc[4][4] = {};
  for (int k = 0; k < ND; ++k) {
    float4 c4 = *(const float4*)(&Cs[k * 64 + ti * 4]);
    float4 q4 = *(const float4*)(&Qs[k * 64 + tj * 4]);
    const float cv[4] = {c4.x, c4.y, c4.z, c4.w};
    const float qv[4] = {q4.x, q4.y, q4.z, q4.w};
    #pragma unroll
    for (int a = 0; a < 4; ++a)
      #pragma unroll
      for (int e = 0; e < 4; ++e)
        acc[a][e] = fmaf(cv[a], qv[e], acc[a][e]);
  }
  float qbv[4];
  #pragma unroll
  for (int e = 0; e < 4; ++e) qbv[e] = qb[b * NQ + j0 + tj * 4 + e];
  #pragma unroll
  for (int a = 0; a < 4; ++a) {
    int i = i0 + ti * 4 + a;
    float cbv = cb[b * NC + i];
    float4 o;
    o.x = acc[a][0] + cbv + qbv[0];
    o.y = acc[a][1] + cbv + qbv[1];
    o.z = acc[a][2] + cbv + qbv[2];
    o.w = acc[a][3] + cbv + qbv[3];
    *(float4*)(S + ((size_t)b * NC + i) * NQ + j0 + tj * 4) = o;
  }
}

// ---------------- K2: row stats (softmax over j with q_mask)
__global__ __launch_bounds__(256) void k2_rowstat(const float* __restrict__ S, const float* __restrict__ q_mask,
                                                  float* __restrict__ rowmax, float* __restrict__ rowsum) {
  int wave = threadIdx.x >> 6;
  int lane = threadIdx.x & 63;
  int row = blockIdx.x * 4 + wave;         // b*NC + i
  int b = row >> 10;
  const float* Srow = S + (size_t)row * NQ;
  const float* qm = q_mask + b * NQ;
  float m = -3.0e38f, s = 0.f;
  #pragma unroll
  for (int q = 0; q < 4; ++q) {
    int j = lane + q * 64;
    float qv = qm[j];
    float v = Srow[j] * qv + NEGV * (1.f - qv);
    float mn = fmaxf(m, v);
    s = s * __expf(m - mn) + __expf(v - mn);
    m = mn;
  }
  #pragma unroll
  for (int off = 1; off < 64; off <<= 1) {
    float mo = __shfl_xor(m, off);
    float so = __shfl_xor(s, off);
    float mn = fmaxf(m, mo);
    s = s * __expf(m - mn) + so * __expf(mo - mn);
    m = mn;
  }
  if (lane == 0) { rowmax[row] = m; rowsum[row] = s; }
}

// ---------------- K3: col stats (softmax over i with c_mask)
__global__ __launch_bounds__(256) void k3_colstat(const float* __restrict__ S, const float* __restrict__ c_mask,
                                                  float* __restrict__ colmax, float* __restrict__ colsum) {
  __shared__ float ms[16][17], ss[16][17];
  int b = blockIdx.y;
  int j0 = blockIdx.x * 16;
  int t = threadIdx.x;
  int jj = t & 15, iq = t >> 4;
  const float* Sb = S + (size_t)b * NC * NQ;
  const float* cm = c_mask + b * NC;
  float m = -3.0e38f, s = 0.f;
  for (int i = iq; i < NC; i += 16) {
    float cv = cm[i];
    float v = Sb[(size_t)i * NQ + j0 + jj] * cv + NEGV * (1.f - cv);
    float mn = fmaxf(m, v);
    s = s * __expf(m - mn) + __expf(v - mn);
    m = mn;
  }
  ms[iq][jj] = m; ss[iq][jj] = s;
  __syncthreads();
  if (iq == 0) {
    #pragma unroll
    for (int q = 1; q < 16; ++q) {
      float mo = ms[q][jj], so = ss[q][jj];
      float mn = fmaxf(m, mo);
      s = s * __expf(m - mn) + so * __expf(mo - mn);
      m = mn;
    }
    colmax[b * NQ + j0 + jj] = m;
    colsum[b * NQ + j0 + jj] = s;
  }
}

// ---------------- K4: inner[b,j,d] = sum_i S_bbar[b,i,j] * C[b,d,i]
__global__ __launch_bounds__(256) void k4_inner(const float* __restrict__ S, const float* __restrict__ C,
                                                const float* __restrict__ c_mask,
                                                const float* __restrict__ colmax, const float* __restrict__ colsum,
                                                float* __restrict__ inner) {
  __shared__ float Ps[32][64];
  __shared__ float Cs[ND][33];
  int b = blockIdx.y;
  int j0 = blockIdx.x * 64;
  int t = threadIdx.x;
  int dt = t & 15, jt = t >> 4;
  const float* Sb = S + (size_t)b * NC * NQ;
  const float* Cb = C + (size_t)b * ND * NC;
  const float* cm = c_mask + b * NC;
  int jl = t & 63;
  float cmax = colmax[b * NQ + j0 + jl];
  float cinv = 1.0f / colsum[b * NQ + j0 + jl];
  float acc[4][8] = {};
  for (int ic = 0; ic < NC; ic += 32) {
    __syncthreads();
    #pragma unroll
    for (int k = 0; k < 8; ++k) {
      int ii = (t >> 6) + k * 4;
      int i = ic + ii;
      float cv = cm[i];
      float v = Sb[(size_t)i * NQ + j0 + jl];
      float se = v * cv + NEGV * (1.f - cv);
      Ps[ii][jl] = __expf(se - cmax) * cinv;
    }
    #pragma unroll
    for (int k = 0; k < 16; ++k) {
      int idx = t + k * 256;
      int ii = idx & 31, dd = idx >> 5;
      Cs[dd][ii] = Cb[(size_t)dd * NC + ic + ii];
    }
    __syncthreads();
    #pragma unroll
    for (int ii = 0; ii < 32; ++ii) {
      float4 pv = *(const float4*)(&Ps[ii][jt * 4]);
      const float pa[4] = {pv.x, pv.y, pv.z, pv.w};
      float cvals[8];
      #pragma unroll
      for (int dd = 0; dd < 8; ++dd) cvals[dd] = Cs[dt + 16 * dd][ii];
      #pragma unroll
      for (int q = 0; q < 4; ++q)
        #pragma unroll
        for (int dd = 0; dd < 8; ++dd)
          acc[q][dd] = fmaf(pa[q], cvals[dd], acc[q][dd]);
    }
  }
  #pragma unroll
  for (int q = 0; q < 4; ++q) {
    int j = j0 + jt * 4 + q;
    #pragma unroll
    for (int dd = 0; dd < 8; ++dd)
      inner[((size_t)b * NQ + j) * ND + dt + 16 * dd] = acc[q][dd];
  }
}

// ---------------- K5: A = S_bar @ Q_t ; Bm = S_bar @ inner ; write concat x (B,4D,NC)
__global__ __launch_bounds__(256) void k5_abm(const float* __restrict__ S, const float* __restrict__ C,
                                              const float* __restrict__ Q, const float* __restrict__ inner,
                                              const float* __restrict__ q_mask,
                                              const float* __restrict__ rowmax, const float* __restrict__ rowsum,
                                              float* __restrict__ x) {
  extern __shared__ float sm5[];
  float* Ps = sm5;                 // [32][64]
  float* Qs = sm5 + 2048;          // [128][65]
  float* Is = sm5 + 2048 + 8320;   // [64][128]
  float* As = sm5;                 // [32][129] (aliases Ps/Qs after sync)
  float* Bs = sm5 + 4128;          // [32][129]
  float* Cs2 = sm5 + 8256;         // [32][129]
  int b = blockIdx.y;
  int i0 = blockIdx.x * 32;
  int t = threadIdx.x;
  int dt = t & 31, it = t >> 5;    // d = dt + 32*dd, i = it*4 + a
  const float* Sb = S + (size_t)b * NC * NQ;
  const float* Qb = Q + (size_t)b * ND * NQ;
  const float* Ib = inner + (size_t)b * NQ * ND;
  const float* qm = q_mask + b * NQ;
  float aA[4][4] = {}, aB[4][4] = {};
  int jl = t & 63;
  for (int jc = 0; jc < 4; ++jc) {
    int j0 = jc * 64;
    __syncthreads();
    {
      float qv = qm[j0 + jl];
      float maskb = NEGV * (1.f - qv);
      #pragma unroll
      for (int k = 0; k < 8; ++k) {
        int ii = (t >> 6) + k * 4;
        float v = Sb[(size_t)(i0 + ii) * NQ + j0 + jl];
        float se = v * qv + maskb;
        Ps[ii * 64 + jl] = __expf(se - rowmax[b * NC + i0 + ii]);
      }
      #pragma unroll
      for (int k = 0; k < 32; ++k) {
        int idx = t + k * 256;
        int j2 = idx & 63, d2 = idx >> 6;
        Qs[d2 * 65 + j2] = Qb[(size_t)d2 * NQ + j0 + j2];
      }
      #pragma unroll
      for (int k = 0; k < 32; ++k) {
        int idx = t + k * 256;
        int d2 = idx & 127, j2 = idx >> 7;
        Is[j2 * 128 + d2] = Ib[(size_t)(j0 + j2) * ND + d2];
      }
    }
    __syncthreads();
    for (int jj = 0; jj < 64; ++jj) {
      float p[4], qv4[4], iv[4];
      #pragma unroll
      for (int a = 0; a < 4; ++a) p[a] = Ps[(it * 4 + a) * 64 + jj];
      #pragma unroll
      for (int dd = 0; dd < 4; ++dd) {
        qv4[dd] = Qs[(dt + 32 * dd) * 65 + jj];
        iv[dd] = Is[jj * 128 + dt + 32 * dd];
      }
      #pragma unroll
      for (int a = 0; a < 4; ++a)
        #pragma unroll
        for (int dd = 0; dd < 4; ++dd) {
          aA[a][dd] = fmaf(p[a], qv4[dd], aA[a][dd]);
          aB[a][dd] = fmaf(p[a], iv[dd], aB[a][dd]);
        }
    }
  }
  __syncthreads();
  #pragma unroll
  for (int a = 0; a < 4; ++a) {
    float inv = 1.0f / rowsum[b * NC + i0 + it * 4 + a];
    #pragma unroll
    for (int dd = 0; dd < 4; ++dd) { aA[a][dd] *= inv; aB[a][dd] *= inv; }
  }
  #pragma unroll
  for (int a = 0; a < 4; ++a)
    #pragma unroll
    for (int dd = 0; dd < 4; ++dd) {
      As[(it * 4 + a) * 129 + dt + 32 * dd] = aA[a][dd];
      Bs[(it * 4 + a) * 129 + dt + 32 * dd] = aB[a][dd];
    }
  const float* Cb = C + (size_t)b * ND * NC;
  #pragma unroll
  for (int k = 0; k < 16; ++k) {
    int idx = t + k * 256;
    int ii = idx & 31, d2 = idx >> 5;
    Cs2[ii * 129 + d2] = Cb[(size_t)d2 * NC + i0 + ii];
  }
  __syncthreads();
  int il = t & 7, cr = t >> 3;
  #pragma unroll
  for (int s = 0; s < 16; ++s) {
    int c = s * 32 + cr;
    int part = c >> 7, d2 = c & 127;
    float ov[4];
    #pragma unroll
    for (int a = 0; a < 4; ++a) {
      int i = il * 4 + a;
      float cvv = Cs2[i * 129 + d2];
      float av = As[i * 129 + d2];
      float bv = Bs[i * 129 + d2];
      ov[a] = (part == 0) ? cvv : (part == 1) ? av : (part == 2) ? cvv * av : cvv * bv;
    }
    float4 o; o.x = ov[0]; o.y = ov[1]; o.z = ov[2]; o.w = ov[3];
    *(float4*)(x + ((size_t)b * 4 * ND + c) * NC + i0 + il * 4) = o;
  }
}

// ---------------- K6: fused depthwise(k=5,pad2) + pointwise (128 out ch) conv
__global__ __launch_bounds__(256) void k6_conv(const float* __restrict__ x, const float* __restrict__ dwW,
                                               const float* __restrict__ dwB, const float* __restrict__ pwW,
                                               const float* __restrict__ pwB, float* __restrict__ out) {
  extern __shared__ float sm6[];
  float* u = sm6;                  // union: xtile [128][69] (8832) / pws [128][129] (16512)
  float* x1s = sm6 + 16512;        // [128][64]
  int b = blockIdx.y;
  int l0 = blockIdx.x * 64;
  int t = threadIdx.x;
  int lt = t & 15, ot = t >> 4;    // l = lt*4+la, o = ot + 16*od
  float acc[8][4] = {};
  const float* xb = x + (size_t)b * 4 * ND * NC;
  for (int ch = 0; ch < 4; ++ch) {
    __syncthreads();
    #pragma unroll
    for (int k = 0; k < 34; ++k) {
      int idx = t + k * 256;       // 0..8703
      int ll = idx % 68;
      int c = idx / 68;
      int l = l0 - 2 + ll;
      float v = (l >= 0 && l < NC) ? xb[(size_t)(ch * 128 + c) * NC + l] : 0.f;
      u[c * 69 + ll] = v;
    }
    __syncthreads();
    {
      int l = t & 63, c0 = t >> 6;
      for (int c = c0; c < 128; c += 4) {
        int cg = ch * 128 + c;
        float a = dwB[cg];
        #pragma unroll
        for (int tap = 0; tap < 5; ++tap)
          a = fmaf(u[c * 69 + l + tap], dwW[cg * 5 + tap], a);
        x1s[c * 64 + l] = a;
      }
    }
    __syncthreads();
    #pragma unroll
    for (int k = 0; k < 64; ++k) {
      int idx = t + k * 256;
      int cc = idx & 127, o = idx >> 7;
      u[o * 129 + cc] = pwW[(size_t)o * 512 + ch * 128 + cc];
    }
    __syncthreads();
    for (int cc = 0; cc < 128; ++cc) {
      float4 xv4 = *(const float4*)(&x1s[cc * 64 + lt * 4]);
      const float xv[4] = {xv4.x, xv4.y, xv4.z, xv4.w};
      float pv[8];
      #pragma unroll
      for (int od = 0; od < 8; ++od) pv[od] = u[(ot + 16 * od) * 129 + cc];
      #pragma unroll
      for (int od = 0; od < 8; ++od)
        #pragma unroll
        for (int la = 0; la < 4; ++la)
          acc[od][la] = fmaf(pv[od], xv[la], acc[od][la]);
    }
  }
  #pragma unroll
  for (int od = 0; od < 8; ++od) {
    int o = ot + 16 * od;
    float bv = pwB[o];
    float4 ov;
    ov.x = acc[od][0] + bv; ov.y = acc[od][1] + bv; ov.z = acc[od][2] + bv; ov.w = acc[od][3] + bv;
    *(float4*)(out + ((size_t)b * ND + o) * NC + l0 + lt * 4) = ov;
  }
}

extern "C" void kernel_launch(void* const* d_in, const int* in_sizes, int n_in,
                              void* d_out, int out_size, void* d_ws, size_t ws_size,
                              hipStream_t stream) {
  const float* C = (const float*)d_in[0];
  const float* Q = (const float*)d_in[1];
  const float* c_mask = (const float*)d_in[2];
  const float* q_mask = (const float*)d_in[3];
  const float* W0 = (const float*)d_in[4];
  const float* dwW = (const float*)d_in[5];
  const float* dwB = (const float*)d_in[6];
  const float* pwW = (const float*)d_in[7];
  const float* pwB = (const float*)d_in[8];
  float* out = (float*)d_out;
  float* ws = (float*)d_ws;

  float* S = ws;                                   // 32*1024*256
  float* rowmax = S + (size_t)NB * NC * NQ;        // 32768
  float* rowsum = rowmax + NB * NC;                // 32768
  float* colmax = rowsum + NB * NC;                // 8192
  float* colsum = colmax + NB * NQ;                // 8192
  float* cb = colsum + NB * NQ;                    // 32768
  float* qb = cb + NB * NC;                        // 8192
  float* inner = qb + NB * NQ;                     // 32*256*128
  float* x = inner + (size_t)NB * NQ * ND;         // 32*512*1024

  k0_bias<<<dim3((NB * (NC + NQ) + 255) / 256), 256, 0, stream>>>(C, Q, W0, cb, qb);
  k1_s<<<dim3(64, NB), 256, 2 * ND * 64 * sizeof(float), stream>>>(C, Q, W0, cb, qb, S);
  k2_rowstat<<<dim3(NB * NC / 4), 256, 0, stream>>>(S, q_mask, rowmax, rowsum);
  k3_colstat<<<dim3(NQ / 16, NB), 256, 0, stream>>>(S, c_mask, colmax, colsum);
  k4_inner<<<dim3(NQ / 64, NB), 256, 0, stream>>>(S, C, c_mask, colmax, colsum, inner);
  k5_abm<<<dim3(NC / 32, NB), 256, 18560 * sizeof(float), stream>>>(S, C, Q, inner, q_mask, rowmax, rowsum, x);
  k6_conv<<<dim3(NC / 64, NB), 256, (16512 + 8192) * sizeof(float), stream>>>(x, dwW, dwB, pwW, pwB, out);
}

// Round 2
// 506.348 us; speedup vs baseline: 1.3692x; 1.3692x over previous
//
#include <hip/hip_runtime.h>
#include <math.h>

#define NB 32
#define ND 128
#define NC 1024
#define NQ 256
#define NEGV (-1e30f)

// ---------------- K0: bias vectors cb[b,i] = sum_k C[b,k,i]*w1[k]; qb[b,j] = sum_k Q[b,k,j]*w2[k]
__global__ __launch_bounds__(256) void k0_bias(const float* __restrict__ C, const float* __restrict__ Q,
                                               const float* __restrict__ W0,
                                               float* __restrict__ cb, float* __restrict__ qb) {
  int idx = blockIdx.x * 256 + threadIdx.x;
  if (idx < NB * NC) {
    int b = idx >> 10, i = idx & (NC - 1);
    const float* base = C + ((size_t)b * ND) * NC + i;
    float s = 0.f;
    #pragma unroll 8
    for (int k = 0; k < ND; ++k) s += base[(size_t)k * NC] * W0[k];
    cb[idx] = s;
  } else {
    int r = idx - NB * NC;
    if (r < NB * NQ) {
      int b = r >> 8, j = r & (NQ - 1);
      const float* base = Q + ((size_t)b * ND) * NQ + j;
      float s = 0.f;
      #pragma unroll 8
      for (int k = 0; k < ND; ++k) s += base[(size_t)k * NQ] * W0[ND + k];
      qb[r] = s;
    }
  }
}

// ---------------- K1: S[b,i,j] = sum_k (C*w3)[b,k,i]*Q[b,k,j] + cb[b,i] + qb[b,j]
__global__ __launch_bounds__(256) void k1_s(const float* __restrict__ C, const float* __restrict__ Q,
                                            const float* __restrict__ W0,
                                            const float* __restrict__ cb, const float* __restrict__ qb,
                                            float* __restrict__ S) {
  extern __shared__ float sm1[];
  float* Cs = sm1;             // [128][64]
  float* Qs = sm1 + ND * 64;   // [128][64]
  int b = blockIdx.y;
  int i0 = (blockIdx.x & 15) * 64;
  int j0 = (blockIdx.x >> 4) * 64;
  int t = threadIdx.x;
  const float* Cb = C + (size_t)b * ND * NC;
  const float* Qb = Q + (size_t)b * ND * NQ;
  int f4 = (t & 15) * 4;
  #pragma unroll
  for (int it = 0; it < 8; ++it) {
    int k = (t >> 4) + it * 16;
    float w = W0[2 * ND + k];
    float4 v = *(const float4*)(Cb + (size_t)k * NC + i0 + f4);
    v.x *= w; v.y *= w; v.z *= w; v.w *= w;
    *(float4*)(&Cs[k * 64 + f4]) = v;
    *(float4*)(&Qs[k * 64 + f4]) = *(const float4*)(Qb + (size_t)k * NQ + j0 + f4);
  }
  __syncthreads();
  int tj = t & 15, ti = t >> 4;
  float acc[4][4] = {};
  for (int k = 0; k < ND; ++k) {
    float4 c4 = *(const float4*)(&Cs[k * 64 + ti * 4]);
    float4 q4 = *(const float4*)(&Qs[k * 64 + tj * 4]);
    const float cv[4] = {c4.x, c4.y, c4.z, c4.w};
    const float qv[4] = {q4.x, q4.y, q4.z, q4.w};
    #pragma unroll
    for (int a = 0; a < 4; ++a)
      #pragma unroll
      for (int e = 0; e < 4; ++e)
        acc[a][e] = fmaf(cv[a], qv[e], acc[a][e]);
  }
  float qbv[4];
  #pragma unroll
  for (int e = 0; e < 4; ++e) qbv[e] = qb[b * NQ + j0 + tj * 4 + e];
  #pragma unroll
  for (int a = 0; a < 4; ++a) {
    int i = i0 + ti * 4 + a;
    float cbv = cb[b * NC + i];
    float4 o;
    o.x = acc[a][0] + cbv + qbv[0];
    o.y = acc[a][1] + cbv + qbv[1];
    o.z = acc[a][2] + cbv + qbv[2];
    o.w = acc[a][3] + cbv + qbv[3];
    *(float4*)(S + ((size_t)b * NC + i) * NQ + j0 + tj * 4) = o;
  }
}

// ---------------- K2: row stats (softmax over j with q_mask)
__global__ __launch_bounds__(256) void k2_rowstat(const float* __restrict__ S, const float* __restrict__ q_mask,
                                                  float* __restrict__ rowmax, float* __restrict__ rowsum) {
  int wave = threadIdx.x >> 6;
  int lane = threadIdx.x & 63;
  int row = blockIdx.x * 4 + wave;         // b*NC + i
  int b = row >> 10;
  const float* Srow = S + (size_t)row * NQ;
  const float* qm = q_mask + b * NQ;
  float m = -3.0e38f, s = 0.f;
  #pragma unroll
  for (int q = 0; q < 4; ++q) {
    int j = lane + q * 64;
    float qv = qm[j];
    float v = Srow[j] * qv + NEGV * (1.f - qv);
    float mn = fmaxf(m, v);
    s = s * __expf(m - mn) + __expf(v - mn);
    m = mn;
  }
  #pragma unroll
  for (int off = 1; off < 64; off <<= 1) {
    float mo = __shfl_xor(m, off);
    float so = __shfl_xor(s, off);
    float mn = fmaxf(m, mo);
    s = s * __expf(m - mn) + so * __expf(mo - mn);
    m = mn;
  }
  if (lane == 0) { rowmax[row] = m; rowsum[row] = s; }
}

// ---------------- K3: col stats (softmax over i with c_mask)
__global__ __launch_bounds__(256) void k3_colstat(const float* __restrict__ S, const float* __restrict__ c_mask,
                                                  float* __restrict__ colmax, float* __restrict__ colsum) {
  __shared__ float ms[16][17], ss[16][17];
  int b = blockIdx.y;
  int j0 = blockIdx.x * 16;
  int t = threadIdx.x;
  int jj = t & 15, iq = t >> 4;
  const float* Sb = S + (size_t)b * NC * NQ;
  const float* cm = c_mask + b * NC;
  float m = -3.0e38f, s = 0.f;
  for (int i = iq; i < NC; i += 16) {
    float cv = cm[i];
    float v = Sb[(size_t)i * NQ + j0 + jj] * cv + NEGV * (1.f - cv);
    float mn = fmaxf(m, v);
    s = s * __expf(m - mn) + __expf(v - mn);
    m = mn;
  }
  ms[iq][jj] = m; ss[iq][jj] = s;
  __syncthreads();
  if (iq == 0) {
    #pragma unroll
    for (int q = 1; q < 16; ++q) {
      float mo = ms[q][jj], so = ss[q][jj];
      float mn = fmaxf(m, mo);
      s = s * __expf(m - mn) + so * __expf(mo - mn);
      m = mn;
    }
    colmax[b * NQ + j0 + jj] = m;
    colsum[b * NQ + j0 + jj] = s;
  }
}

// ---------------- K4: inner[b,j,d] = sum_i S_bbar[b,i,j] * C[b,d,i]
__global__ __launch_bounds__(256) void k4_inner(const float* __restrict__ S, const float* __restrict__ C,
                                                const float* __restrict__ c_mask,
                                                const float* __restrict__ colmax, const float* __restrict__ colsum,
                                                float* __restrict__ inner) {
  __shared__ float Ps[32][64];
  __shared__ float Cs[ND][33];
  int b = blockIdx.y;
  int j0 = blockIdx.x * 64;
  int t = threadIdx.x;
  int dt = t & 15, jt = t >> 4;
  const float* Sb = S + (size_t)b * NC * NQ;
  const float* Cb = C + (size_t)b * ND * NC;
  const float* cm = c_mask + b * NC;
  int jl = t & 63;
  float cmax = colmax[b * NQ + j0 + jl];
  float cinv = 1.0f / colsum[b * NQ + j0 + jl];
  float acc[4][8] = {};
  for (int ic = 0; ic < NC; ic += 32) {
    __syncthreads();
    #pragma unroll
    for (int k = 0; k < 8; ++k) {
      int ii = (t >> 6) + k * 4;
      int i = ic + ii;
      float cv = cm[i];
      float v = Sb[(size_t)i * NQ + j0 + jl];
      float se = v * cv + NEGV * (1.f - cv);
      Ps[ii][jl] = __expf(se - cmax) * cinv;
    }
    #pragma unroll
    for (int k = 0; k < 16; ++k) {
      int idx = t + k * 256;
      int ii = idx & 31, dd = idx >> 5;
      Cs[dd][ii] = Cb[(size_t)dd * NC + ic + ii];
    }
    __syncthreads();
    #pragma unroll
    for (int ii = 0; ii < 32; ++ii) {
      float4 pv = *(const float4*)(&Ps[ii][jt * 4]);
      const float pa[4] = {pv.x, pv.y, pv.z, pv.w};
      float cvals[8];
      #pragma unroll
      for (int dd = 0; dd < 8; ++dd) cvals[dd] = Cs[dt + 16 * dd][ii];
      #pragma unroll
      for (int q = 0; q < 4; ++q)
        #pragma unroll
        for (int dd = 0; dd < 8; ++dd)
          acc[q][dd] = fmaf(pa[q], cvals[dd], acc[q][dd]);
    }
  }
  #pragma unroll
  for (int q = 0; q < 4; ++q) {
    int j = j0 + jt * 4 + q;
    #pragma unroll
    for (int dd = 0; dd < 8; ++dd)
      inner[((size_t)b * NQ + j) * ND + dt + 16 * dd] = acc[q][dd];
  }
}

// ---------------- K5: A = S_bar @ Q_t ; Bm = S_bar @ inner ; write concat x (B,4D,NC)
__global__ __launch_bounds__(256) void k5_abm(const float* __restrict__ S, const float* __restrict__ C,
                                              const float* __restrict__ Q, const float* __restrict__ inner,
                                              const float* __restrict__ q_mask,
                                              const float* __restrict__ rowmax, const float* __restrict__ rowsum,
                                              float* __restrict__ x) {
  extern __shared__ float sm5[];
  float* Ps = sm5;                 // [32][64]
  float* Qs = sm5 + 2048;          // [128][65]
  float* Is = sm5 + 2048 + 8320;   // [64][128]
  float* As = sm5;                 // [32][129] (aliases Ps/Qs after sync)
  float* Bs = sm5 + 4128;          // [32][129]
  float* Cs2 = sm5 + 8256;         // [32][129]
  int b = blockIdx.y;
  int i0 = blockIdx.x * 32;
  int t = threadIdx.x;
  int dt = t & 31, it = t >> 5;    // d = dt + 32*dd, i = it*4 + a
  const float* Sb = S + (size_t)b * NC * NQ;
  const float* Qb = Q + (size_t)b * ND * NQ;
  const float* Ib = inner + (size_t)b * NQ * ND;
  const float* qm = q_mask + b * NQ;
  float aA[4][4] = {}, aB[4][4] = {};
  int jl = t & 63;
  for (int jc = 0; jc < 4; ++jc) {
    int j0 = jc * 64;
    __syncthreads();
    {
      float qv = qm[j0 + jl];
      float maskb = NEGV * (1.f - qv);
      #pragma unroll
      for (int k = 0; k < 8; ++k) {
        int ii = (t >> 6) + k * 4;
        float v = Sb[(size_t)(i0 + ii) * NQ + j0 + jl];
        float se = v * qv + maskb;
        Ps[ii * 64 + jl] = __expf(se - rowmax[b * NC + i0 + ii]);
      }
      #pragma unroll
      for (int k = 0; k < 32; ++k) {
        int idx = t + k * 256;
        int j2 = idx & 63, d2 = idx >> 6;
        Qs[d2 * 65 + j2] = Qb[(size_t)d2 * NQ + j0 + j2];
      }
      #pragma unroll
      for (int k = 0; k < 32; ++k) {
        int idx = t + k * 256;
        int d2 = idx & 127, j2 = idx >> 7;
        Is[j2 * 128 + d2] = Ib[(size_t)(j0 + j2) * ND + d2];
      }
    }
    __syncthreads();
    for (int jj = 0; jj < 64; ++jj) {
      float p[4], qv4[4], iv[4];
      #pragma unroll
      for (int a = 0; a < 4; ++a) p[a] = Ps[(it * 4 + a) * 64 + jj];
      #pragma unroll
      for (int dd = 0; dd < 4; ++dd) {
        qv4[dd] = Qs[(dt + 32 * dd) * 65 + jj];
        iv[dd] = Is[jj * 128 + dt + 32 * dd];
      }
      #pragma unroll
      for (int a = 0; a < 4; ++a)
        #pragma unroll
        for (int dd = 0; dd < 4; ++dd) {
          aA[a][dd] = fmaf(p[a], qv4[dd], aA[a][dd]);
          aB[a][dd] = fmaf(p[a], iv[dd], aB[a][dd]);
        }
    }
  }
  __syncthreads();
  #pragma unroll
  for (int a = 0; a < 4; ++a) {
    float inv = 1.0f / rowsum[b * NC + i0 + it * 4 + a];
    #pragma unroll
    for (int dd = 0; dd < 4; ++dd) { aA[a][dd] *= inv; aB[a][dd] *= inv; }
  }
  #pragma unroll
  for (int a = 0; a < 4; ++a)
    #pragma unroll
    for (int dd = 0; dd < 4; ++dd) {
      As[(it * 4 + a) * 129 + dt + 32 * dd] = aA[a][dd];
      Bs[(it * 4 + a) * 129 + dt + 32 * dd] = aB[a][dd];
    }
  const float* Cb = C + (size_t)b * ND * NC;
  #pragma unroll
  for (int k = 0; k < 16; ++k) {
    int idx = t + k * 256;
    int ii = idx & 31, d2 = idx >> 5;
    Cs2[ii * 129 + d2] = Cb[(size_t)d2 * NC + i0 + ii];
  }
  __syncthreads();
  int il = t & 7, cr = t >> 3;
  #pragma unroll
  for (int s = 0; s < 16; ++s) {
    int c = s * 32 + cr;
    int part = c >> 7, d2 = c & 127;
    float ov[4];
    #pragma unroll
    for (int a = 0; a < 4; ++a) {
      int i = il * 4 + a;
      float cvv = Cs2[i * 129 + d2];
      float av = As[i * 129 + d2];
      float bv = Bs[i * 129 + d2];
      ov[a] = (part == 0) ? cvv : (part == 1) ? av : (part == 2) ? cvv * av : cvv * bv;
    }
    float4 o; o.x = ov[0]; o.y = ov[1]; o.z = ov[2]; o.w = ov[3];
    *(float4*)(x + ((size_t)b * 4 * ND + c) * NC + i0 + il * 4) = o;
  }
}

// ---------------- K6 (new): fused depthwise(k=5,pad2) + pointwise GEMM, K-chunked, LDS-aliased
// LDS: uni[64][136] (pw weights transposed [cg][o], also aliased as xtile[64][69])
//      x1s[64][68]
// per block: 128 out-ch x 64 positions; 8 K-chunks of 64 channels
__global__ __launch_bounds__(256) void k6_fused(const float* __restrict__ x, const float* __restrict__ dwW,
                                                const float* __restrict__ dwB, const float* __restrict__ pwW,
                                                const float* __restrict__ pwB, float* __restrict__ out) {
  extern __shared__ float sm6[];
  float* uni = sm6;            // 64*136 = 8704 floats (pws2), aliased as xtile [64][69]
  float* x1s = sm6 + 8704;     // 64*68 = 4352 floats
  int b = blockIdx.y;
  int l0 = blockIdx.x * 64;
  int t = threadIdx.x;
  int lt = t & 15, ot = t >> 4;    // l = l0 + lt*4 + la ; o = ot*8 + od
  const float* xb = x + (size_t)b * 4 * ND * NC;
  float acc[8][4] = {};

  for (int ch = 0; ch < 8; ++ch) {
    int cg0 = ch * 64;
    __syncthreads();   // protect uni (pws2 of prev chunk) before overwrite as xtile
    // stage xtile[ci][ll] = x[b, cg0+ci, l0-2+ll], 64x68
    #pragma unroll
    for (int k = 0; k < 17; ++k) {
      int idx = t + k * 256;         // 0..4351
      int ci = idx / 68;
      int ll = idx - ci * 68;
      int l = l0 - 2 + ll;
      float v = ((unsigned)l < (unsigned)NC) ? xb[(size_t)(cg0 + ci) * NC + l] : 0.f;
      uni[ci * 69 + ll] = v;
    }
    __syncthreads();
    // depthwise into x1s[ci][li]
    #pragma unroll
    for (int k = 0; k < 16; ++k) {
      int idx = t + k * 256;
      int ci = idx >> 6, li = idx & 63;
      int cg = cg0 + ci;
      float a = dwB[cg];
      #pragma unroll
      for (int tap = 0; tap < 5; ++tap)
        a = fmaf(uni[ci * 69 + li + tap], dwW[cg * 5 + tap], a);
      x1s[ci * 68 + li] = a;
    }
    __syncthreads();
    // stage pws2[ci][o] = pwW[o, cg0+ci]  (overwrites xtile)
    #pragma unroll
    for (int k = 0; k < 8; ++k) {
      int idx = t + k * 256;           // 0..2047
      int o = idx >> 4;                // 0..127
      int c4 = (idx & 15) * 4;
      float4 w = *(const float4*)(pwW + (size_t)o * 512 + cg0 + c4);
      uni[(c4 + 0) * 136 + o] = w.x;
      uni[(c4 + 1) * 136 + o] = w.y;
      uni[(c4 + 2) * 136 + o] = w.z;
      uni[(c4 + 3) * 136 + o] = w.w;
    }
    __syncthreads();
    // GEMM: acc[od][la] += pws2[ci][ot*8+od] * x1s[ci][lt*4+la]
    #pragma unroll 4
    for (int ci = 0; ci < 64; ++ci) {
      float4 xv4 = *(const float4*)(&x1s[ci * 68 + lt * 4]);
      float4 p0 = *(const float4*)(&uni[ci * 136 + ot * 8]);
      float4 p1 = *(const float4*)(&uni[ci * 136 + ot * 8 + 4]);
      const float xv[4] = {xv4.x, xv4.y, xv4.z, xv4.w};
      const float pv[8] = {p0.x, p0.y, p0.z, p0.w, p1.x, p1.y, p1.z, p1.w};
      #pragma unroll
      for (int od = 0; od < 8; ++od)
        #pragma unroll
        for (int la = 0; la < 4; ++la)
          acc[od][la] = fmaf(pv[od], xv[la], acc[od][la]);
    }
  }
  #pragma unroll
  for (int od = 0; od < 8; ++od) {
    int o = ot * 8 + od;
    float bv = pwB[o];
    float4 ov;
    ov.x = acc[od][0] + bv; ov.y = acc[od][1] + bv; ov.z = acc[od][2] + bv; ov.w = acc[od][3] + bv;
    *(float4*)(out + ((size_t)b * ND + o) * NC + l0 + lt * 4) = ov;
  }
}

extern "C" void kernel_launch(void* const* d_in, const int* in_sizes, int n_in,
                              void* d_out, int out_size, void* d_ws, size_t ws_size,
                              hipStream_t stream) {
  const float* C = (const float*)d_in[0];
  const float* Q = (const float*)d_in[1];
  const float* c_mask = (const float*)d_in[2];
  const float* q_mask = (const float*)d_in[3];
  const float* W0 = (const float*)d_in[4];
  const float* dwW = (const float*)d_in[5];
  const float* dwB = (const float*)d_in[6];
  const float* pwW = (const float*)d_in[7];
  const float* pwB = (const float*)d_in[8];
  float* out = (float*)d_out;
  float* ws = (float*)d_ws;

  float* S = ws;                                   // 32*1024*256
  float* rowmax = S + (size_t)NB * NC * NQ;        // 32768
  float* rowsum = rowmax + NB * NC;                // 32768
  float* colmax = rowsum + NB * NC;                // 8192
  float* colsum = colmax + NB * NQ;                // 8192
  float* cb = colsum + NB * NQ;                    // 32768
  float* qb = cb + NB * NC;                        // 8192
  float* inner = qb + NB * NQ;                     // 32*256*128
  float* x = inner + (size_t)NB * NQ * ND;         // 32*512*1024

  k0_bias<<<dim3((NB * (NC + NQ) + 255) / 256), 256, 0, stream>>>(C, Q, W0, cb, qb);
  k1_s<<<dim3(64, NB), 256, 2 * ND * 64 * sizeof(float), stream>>>(C, Q, W0, cb, qb, S);
  k2_rowstat<<<dim3(NB * NC / 4), 256, 0, stream>>>(S, q_mask, rowmax, rowsum);
  k3_colstat<<<dim3(NQ / 16, NB), 256, 0, stream>>>(S, c_mask, colmax, colsum);
  k4_inner<<<dim3(NQ / 64, NB), 256, 0, stream>>>(S, C, c_mask, colmax, colsum, inner);
  k5_abm<<<dim3(NC / 32, NB), 256, 18560 * sizeof(float), stream>>>(S, C, Q, inner, q_mask, rowmax, rowsum, x);
  k6_fused<<<dim3(NC / 64, NB), 256, (8704 + 4352) * sizeof(float), stream>>>(x, dwW, dwB, pwW, pwB, out);
}

// Round 3
// 342.047 us; speedup vs baseline: 2.0270x; 1.4803x over previous
//
#include <hip/hip_runtime.h>
#include <math.h>

#define NB 32
#define ND 128
#define NC 1024
#define NQ 256
#define NEGV (-1e30f)

typedef __attribute__((ext_vector_type(8))) __bf16 bf16x8;
typedef __attribute__((ext_vector_type(4))) float f32x4;
typedef __attribute__((ext_vector_type(8))) unsigned short u16x8;

__device__ inline unsigned short f2bf(float f) {
  unsigned u = __builtin_bit_cast(unsigned, f);
  u += 0x7FFFu + ((u >> 16) & 1u);
  return (unsigned short)(u >> 16);
}

// ---------------- K0: bias vectors
__global__ __launch_bounds__(256) void k0_bias(const float* __restrict__ C, const float* __restrict__ Q,
                                               const float* __restrict__ W0,
                                               float* __restrict__ cb, float* __restrict__ qb) {
  int idx = blockIdx.x * 256 + threadIdx.x;
  if (idx < NB * NC) {
    int b = idx >> 10, i = idx & (NC - 1);
    const float* base = C + ((size_t)b * ND) * NC + i;
    float s = 0.f;
    #pragma unroll 8
    for (int k = 0; k < ND; ++k) s += base[(size_t)k * NC] * W0[k];
    cb[idx] = s;
  } else {
    int r = idx - NB * NC;
    if (r < NB * NQ) {
      int b = r >> 8, j = r & (NQ - 1);
      const float* base = Q + ((size_t)b * ND) * NQ + j;
      float s = 0.f;
      #pragma unroll 8
      for (int k = 0; k < ND; ++k) s += base[(size_t)k * NQ] * W0[ND + k];
      qb[r] = s;
    }
  }
}

// ---------------- K1: S[b,i,j]
__global__ __launch_bounds__(256) void k1_s(const float* __restrict__ C, const float* __restrict__ Q,
                                            const float* __restrict__ W0,
                                            const float* __restrict__ cb, const float* __restrict__ qb,
                                            float* __restrict__ S) {
  extern __shared__ float sm1[];
  float* Cs = sm1;             // [128][64]
  float* Qs = sm1 + ND * 64;   // [128][64]
  int b = blockIdx.y;
  int i0 = (blockIdx.x & 15) * 64;
  int j0 = (blockIdx.x >> 4) * 64;
  int t = threadIdx.x;
  const float* Cb = C + (size_t)b * ND * NC;
  const float* Qb = Q + (size_t)b * ND * NQ;
  int f4 = (t & 15) * 4;
  #pragma unroll
  for (int it = 0; it < 8; ++it) {
    int k = (t >> 4) + it * 16;
    float w = W0[2 * ND + k];
    float4 v = *(const float4*)(Cb + (size_t)k * NC + i0 + f4);
    v.x *= w; v.y *= w; v.z *= w; v.w *= w;
    *(float4*)(&Cs[k * 64 + f4]) = v;
    *(float4*)(&Qs[k * 64 + f4]) = *(const float4*)(Qb + (size_t)k * NQ + j0 + f4);
  }
  __syncthreads();
  int tj = t & 15, ti = t >> 4;
  float acc[4][4] = {};
  for (int k = 0; k < ND; ++k) {
    float4 c4 = *(const float4*)(&Cs[k * 64 + ti * 4]);
    float4 q4 = *(const float4*)(&Qs[k * 64 + tj * 4]);
    const float cv[4] = {c4.x, c4.y, c4.z, c4.w};
    const float qv[4] = {q4.x, q4.y, q4.z, q4.w};
    #pragma unroll
    for (int a = 0; a < 4; ++a)
      #pragma unroll
      for (int e = 0; e < 4; ++e)
        acc[a][e] = fmaf(cv[a], qv[e], acc[a][e]);
  }
  float qbv[4];
  #pragma unroll
  for (int e = 0; e < 4; ++e) qbv[e] = qb[b * NQ + j0 + tj * 4 + e];
  #pragma unroll
  for (int a = 0; a < 4; ++a) {
    int i = i0 + ti * 4 + a;
    float cbv = cb[b * NC + i];
    float4 o;
    o.x = acc[a][0] + cbv + qbv[0];
    o.y = acc[a][1] + cbv + qbv[1];
    o.z = acc[a][2] + cbv + qbv[2];
    o.w = acc[a][3] + cbv + qbv[3];
    *(float4*)(S + ((size_t)b * NC + i) * NQ + j0 + tj * 4) = o;
  }
}

// ---------------- K2: row stats
__global__ __launch_bounds__(256) void k2_rowstat(const float* __restrict__ S, const float* __restrict__ q_mask,
                                                  float* __restrict__ rowmax, float* __restrict__ rowsum) {
  int wave = threadIdx.x >> 6;
  int lane = threadIdx.x & 63;
  int row = blockIdx.x * 4 + wave;         // b*NC + i
  int b = row >> 10;
  const float* Srow = S + (size_t)row * NQ;
  const float* qm = q_mask + b * NQ;
  float m = -3.0e38f, s = 0.f;
  #pragma unroll
  for (int q = 0; q < 4; ++q) {
    int j = lane + q * 64;
    float qv = qm[j];
    float v = Srow[j] * qv + NEGV * (1.f - qv);
    float mn = fmaxf(m, v);
    s = s * __expf(m - mn) + __expf(v - mn);
    m = mn;
  }
  #pragma unroll
  for (int off = 1; off < 64; off <<= 1) {
    float mo = __shfl_xor(m, off);
    float so = __shfl_xor(s, off);
    float mn = fmaxf(m, mo);
    s = s * __expf(m - mn) + so * __expf(mo - mn);
    m = mn;
  }
  if (lane == 0) { rowmax[row] = m; rowsum[row] = s; }
}

// ---------------- K3: col stats
__global__ __launch_bounds__(256) void k3_colstat(const float* __restrict__ S, const float* __restrict__ c_mask,
                                                  float* __restrict__ colmax, float* __restrict__ colsum) {
  __shared__ float ms[16][17], ss[16][17];
  int b = blockIdx.y;
  int j0 = blockIdx.x * 16;
  int t = threadIdx.x;
  int jj = t & 15, iq = t >> 4;
  const float* Sb = S + (size_t)b * NC * NQ;
  const float* cm = c_mask + b * NC;
  float m = -3.0e38f, s = 0.f;
  for (int i = iq; i < NC; i += 16) {
    float cv = cm[i];
    float v = Sb[(size_t)i * NQ + j0 + jj] * cv + NEGV * (1.f - cv);
    float mn = fmaxf(m, v);
    s = s * __expf(m - mn) + __expf(v - mn);
    m = mn;
  }
  ms[iq][jj] = m; ss[iq][jj] = s;
  __syncthreads();
  if (iq == 0) {
    #pragma unroll
    for (int q = 1; q < 16; ++q) {
      float mo = ms[q][jj], so = ss[q][jj];
      float mn = fmaxf(m, mo);
      s = s * __expf(m - mn) + so * __expf(mo - mn);
      m = mn;
    }
    colmax[b * NQ + j0 + jj] = m;
    colsum[b * NQ + j0 + jj] = s;
  }
}

// ---------------- K4: innerT[b,d,j] (bf16) = sum_i S_bbar[b,i,j] * C[b,d,i]
__global__ __launch_bounds__(256) void k4_inner(const float* __restrict__ S, const float* __restrict__ C,
                                                const float* __restrict__ c_mask,
                                                const float* __restrict__ colmax, const float* __restrict__ colsum,
                                                unsigned short* __restrict__ innerT) {
  __shared__ float Ps[32][64];
  __shared__ float Cs[ND][33];
  __shared__ unsigned short Tb[ND][72];
  int b = blockIdx.y;
  int j0 = blockIdx.x * 64;
  int t = threadIdx.x;
  int dt = t & 15, jt = t >> 4;
  const float* Sb = S + (size_t)b * NC * NQ;
  const float* Cb = C + (size_t)b * ND * NC;
  const float* cm = c_mask + b * NC;
  int jl = t & 63;
  float cmax = colmax[b * NQ + j0 + jl];
  float cinv = 1.0f / colsum[b * NQ + j0 + jl];
  float acc[4][8] = {};
  for (int ic = 0; ic < NC; ic += 32) {
    __syncthreads();
    #pragma unroll
    for (int k = 0; k < 8; ++k) {
      int ii = (t >> 6) + k * 4;
      int i = ic + ii;
      float cv = cm[i];
      float v = Sb[(size_t)i * NQ + j0 + jl];
      float se = v * cv + NEGV * (1.f - cv);
      Ps[ii][jl] = __expf(se - cmax) * cinv;
    }
    #pragma unroll
    for (int k = 0; k < 16; ++k) {
      int idx = t + k * 256;
      int ii = idx & 31, dd = idx >> 5;
      Cs[dd][ii] = Cb[(size_t)dd * NC + ic + ii];
    }
    __syncthreads();
    #pragma unroll
    for (int ii = 0; ii < 32; ++ii) {
      float4 pv = *(const float4*)(&Ps[ii][jt * 4]);
      const float pa[4] = {pv.x, pv.y, pv.z, pv.w};
      float cvals[8];
      #pragma unroll
      for (int dd = 0; dd < 8; ++dd) cvals[dd] = Cs[dt + 16 * dd][ii];
      #pragma unroll
      for (int q = 0; q < 4; ++q)
        #pragma unroll
        for (int dd = 0; dd < 8; ++dd)
          acc[q][dd] = fmaf(pa[q], cvals[dd], acc[q][dd]);
    }
  }
  // epilogue: acc -> Tb (bf16, [d][j_local]) -> coalesced global innerT
  #pragma unroll
  for (int q = 0; q < 4; ++q)
    #pragma unroll
    for (int dd = 0; dd < 8; ++dd)
      Tb[dt + 16 * dd][jt * 4 + q] = f2bf(acc[q][dd]);
  __syncthreads();
  {
    int d = t >> 1, jh = (t & 1) * 32;
    unsigned short* dst = innerT + ((size_t)b * ND + d) * NQ + j0 + jh;
    #pragma unroll
    for (int s = 0; s < 4; ++s) {
      u16x8 v = *(const u16x8*)&Tb[d][jh + s * 8];
      *(u16x8*)(dst + s * 8) = v;
    }
  }
}

// ---------------- K5 (MFMA): A[i][d] = P@Q^T, Bm[i][d] = P@inner; write concat x
// M=i(32), N=d(128), K=j(256). P bf16 [32][64/chunk], Qb/Ib bf16 [128][64/chunk], XOR slot swizzle.
__global__ __launch_bounds__(256) void k5_mfma(const float* __restrict__ S, const float* __restrict__ C,
                                               const float* __restrict__ Q,
                                               const unsigned short* __restrict__ innerT,
                                               const float* __restrict__ q_mask,
                                               const float* __restrict__ rowmax, const float* __restrict__ rowsum,
                                               float* __restrict__ x) {
  extern __shared__ char sm[];
  unsigned short* Pl = (unsigned short*)sm;            // [32][64] bf16
  unsigned short* Qb = (unsigned short*)(sm + 4096);   // [128][64] bf16
  unsigned short* Ib = (unsigned short*)(sm + 20480);  // [128][64] bf16
  float* As = (float*)sm;                              // [32][133] f32 (aliases, post-compute)
  float* Bs = (float*)(sm + 17024);                    // [32][133] f32
  int b = blockIdx.y, i0 = blockIdx.x * 32;
  int t = threadIdx.x, w = t >> 6, l = t & 63;
  const float* Sb = S + ((size_t)b * NC + i0) * NQ;
  const float* Qg = Q + (size_t)b * ND * NQ;
  const unsigned short* Ig = innerT + (size_t)b * ND * NQ;
  const float* qm = q_mask + b * NQ;

  f32x4 accA[2][2] = {};
  f32x4 accB[2][2] = {};

  int pi = t >> 3, psj = t & 7;      // P staging: row i=pi (8 thr/row, 8 j each)
  int qd = t >> 1, qh = t & 1;       // Q/I staging: row d=qd, half j-32
  float rmax = rowmax[b * NC + i0 + pi];
  float rinv = 1.0f / rowsum[b * NC + i0 + pi];
  int h = l >> 4, lr = l & 15;

  for (int jc = 0; jc < 4; ++jc) {
    int j0 = jc * 64;
    __syncthreads();
    // --- stage P (exp(S-max)/sum -> bf16)
    {
      const float* srow = Sb + (size_t)pi * NQ + j0 + psj * 8;
      float4 s0 = *(const float4*)srow;
      float4 s1 = *(const float4*)(srow + 4);
      float sv[8] = {s0.x, s0.y, s0.z, s0.w, s1.x, s1.y, s1.z, s1.w};
      u16x8 ov;
      #pragma unroll
      for (int e = 0; e < 8; ++e) {
        float qv = qm[j0 + psj * 8 + e];
        float se = sv[e] * qv + NEGV * (1.f - qv);
        ov[e] = f2bf(__expf(se - rmax) * rinv);
      }
      *(u16x8*)&Pl[pi * 64 + (psj ^ (pi & 7)) * 8] = ov;
    }
    // --- stage Q chunk (f32 -> bf16), layout [d][j] j-contig, swizzled 16B slots
    {
      const float* qrow = Qg + (size_t)qd * NQ + j0 + qh * 32;
      #pragma unroll
      for (int s = 0; s < 4; ++s) {
        float4 v0 = *(const float4*)(qrow + s * 8);
        float4 v1 = *(const float4*)(qrow + s * 8 + 4);
        u16x8 ov;
        ov[0] = f2bf(v0.x); ov[1] = f2bf(v0.y); ov[2] = f2bf(v0.z); ov[3] = f2bf(v0.w);
        ov[4] = f2bf(v1.x); ov[5] = f2bf(v1.y); ov[6] = f2bf(v1.z); ov[7] = f2bf(v1.w);
        int slot = (qh * 4 + s) ^ (qd & 7);
        *(u16x8*)&Qb[qd * 64 + slot * 8] = ov;
      }
    }
    // --- stage innerT chunk (bf16 copy)
    {
      const unsigned short* irow = Ig + (size_t)qd * NQ + j0 + qh * 32;
      #pragma unroll
      for (int s = 0; s < 4; ++s) {
        u16x8 v = *(const u16x8*)(irow + s * 8);
        int slot = (qh * 4 + s) ^ (qd & 7);
        *(u16x8*)&Ib[qd * 64 + slot * 8] = v;
      }
    }
    __syncthreads();
    // --- MFMA: 2 K-steps of 32
    #pragma unroll
    for (int ks = 0; ks < 2; ++ks) {
      bf16x8 aP[2], bQ[2], bI[2];
      #pragma unroll
      for (int mi = 0; mi < 2; ++mi) {
        int i = mi * 16 + lr;
        int slot = (ks * 4 + h) ^ (i & 7);
        aP[mi] = *(const bf16x8*)&Pl[i * 64 + slot * 8];
      }
      #pragma unroll
      for (int nd = 0; nd < 2; ++nd) {
        int d = w * 32 + nd * 16 + lr;
        int slot = (ks * 4 + h) ^ (d & 7);
        bQ[nd] = *(const bf16x8*)&Qb[d * 64 + slot * 8];
        bI[nd] = *(const bf16x8*)&Ib[d * 64 + slot * 8];
      }
      #pragma unroll
      for (int mi = 0; mi < 2; ++mi)
        #pragma unroll
        for (int nd = 0; nd < 2; ++nd) {
          accA[mi][nd] = __builtin_amdgcn_mfma_f32_16x16x32_bf16(aP[mi], bQ[nd], accA[mi][nd], 0, 0, 0);
          accB[mi][nd] = __builtin_amdgcn_mfma_f32_16x16x32_bf16(aP[mi], bI[nd], accB[mi][nd], 0, 0, 0);
        }
    }
  }
  __syncthreads();
  // --- dump accs to LDS [i][d] (pad 133 => conflict-free epilogue reads)
  #pragma unroll
  for (int mi = 0; mi < 2; ++mi)
    #pragma unroll
    for (int nd = 0; nd < 2; ++nd) {
      int d = w * 32 + nd * 16 + lr;
      #pragma unroll
      for (int r = 0; r < 4; ++r) {
        int i = mi * 16 + h * 4 + r;
        As[i * 133 + d] = accA[mi][nd][r];
        Bs[i * 133 + d] = accB[mi][nd][r];
      }
    }
  __syncthreads();
  // --- write x: part0=C, part1=A, part2=C*A, part3=C*Bm (all [d][i], coalesced)
  {
    int i4 = (t & 7) * 4, db = t >> 3;
    const float* Cb = C + (size_t)b * ND * NC;
    float* xb = x + (size_t)b * 4 * ND * NC;
    #pragma unroll
    for (int p = 0; p < 4; ++p) {
      int d = db + p * 32;
      float4 c4 = *(const float4*)&Cb[(size_t)d * NC + i0 + i4];
      float4 a4, b4;
      a4.x = As[(i4 + 0) * 133 + d]; a4.y = As[(i4 + 1) * 133 + d];
      a4.z = As[(i4 + 2) * 133 + d]; a4.w = As[(i4 + 3) * 133 + d];
      b4.x = Bs[(i4 + 0) * 133 + d]; b4.y = Bs[(i4 + 1) * 133 + d];
      b4.z = Bs[(i4 + 2) * 133 + d]; b4.w = Bs[(i4 + 3) * 133 + d];
      float4 p2, p3;
      p2.x = c4.x * a4.x; p2.y = c4.y * a4.y; p2.z = c4.z * a4.z; p2.w = c4.w * a4.w;
      p3.x = c4.x * b4.x; p3.y = c4.y * b4.y; p3.z = c4.z * b4.z; p3.w = c4.w * b4.w;
      *(float4*)&xb[(size_t)(0 * ND + d) * NC + i0 + i4] = c4;
      *(float4*)&xb[(size_t)(1 * ND + d) * NC + i0 + i4] = a4;
      *(float4*)&xb[(size_t)(2 * ND + d) * NC + i0 + i4] = p2;
      *(float4*)&xb[(size_t)(3 * ND + d) * NC + i0 + i4] = p3;
    }
  }
}

// ---------------- K6: fused depthwise(k=5,pad2) + pointwise GEMM
__global__ __launch_bounds__(256) void k6_fused(const float* __restrict__ x, const float* __restrict__ dwW,
                                                const float* __restrict__ dwB, const float* __restrict__ pwW,
                                                const float* __restrict__ pwB, float* __restrict__ out) {
  extern __shared__ float sm6[];
  float* uni = sm6;            // 64*136 (pws2), aliased as xtile [64][69]
  float* x1s = sm6 + 8704;     // [64][68]
  int b = blockIdx.y;
  int l0 = blockIdx.x * 64;
  int t = threadIdx.x;
  int lt = t & 15, ot = t >> 4;
  const float* xb = x + (size_t)b * 4 * ND * NC;
  float acc[8][4] = {};

  for (int ch = 0; ch < 8; ++ch) {
    int cg0 = ch * 64;
    __syncthreads();
    #pragma unroll
    for (int k = 0; k < 17; ++k) {
      int idx = t + k * 256;
      int ci = idx / 68;
      int ll = idx - ci * 68;
      int l = l0 - 2 + ll;
      float v = ((unsigned)l < (unsigned)NC) ? xb[(size_t)(cg0 + ci) * NC + l] : 0.f;
      uni[ci * 69 + ll] = v;
    }
    __syncthreads();
    #pragma unroll
    for (int k = 0; k < 16; ++k) {
      int idx = t + k * 256;
      int ci = idx >> 6, li = idx & 63;
      int cg = cg0 + ci;
      float a = dwB[cg];
      #pragma unroll
      for (int tap = 0; tap < 5; ++tap)
        a = fmaf(uni[ci * 69 + li + tap], dwW[cg * 5 + tap], a);
      x1s[ci * 68 + li] = a;
    }
    __syncthreads();
    #pragma unroll
    for (int k = 0; k < 8; ++k) {
      int idx = t + k * 256;
      int o = idx >> 4;
      int c4 = (idx & 15) * 4;
      float4 wv = *(const float4*)(pwW + (size_t)o * 512 + cg0 + c4);
      uni[(c4 + 0) * 136 + o] = wv.x;
      uni[(c4 + 1) * 136 + o] = wv.y;
      uni[(c4 + 2) * 136 + o] = wv.z;
      uni[(c4 + 3) * 136 + o] = wv.w;
    }
    __syncthreads();
    #pragma unroll 4
    for (int ci = 0; ci < 64; ++ci) {
      float4 xv4 = *(const float4*)(&x1s[ci * 68 + lt * 4]);
      float4 p0 = *(const float4*)(&uni[ci * 136 + ot * 8]);
      float4 p1 = *(const float4*)(&uni[ci * 136 + ot * 8 + 4]);
      const float xv[4] = {xv4.x, xv4.y, xv4.z, xv4.w};
      const float pv[8] = {p0.x, p0.y, p0.z, p0.w, p1.x, p1.y, p1.z, p1.w};
      #pragma unroll
      for (int od = 0; od < 8; ++od)
        #pragma unroll
        for (int la = 0; la < 4; ++la)
          acc[od][la] = fmaf(pv[od], xv[la], acc[od][la]);
    }
  }
  #pragma unroll
  for (int od = 0; od < 8; ++od) {
    int o = ot * 8 + od;
    float bv = pwB[o];
    float4 ov;
    ov.x = acc[od][0] + bv; ov.y = acc[od][1] + bv; ov.z = acc[od][2] + bv; ov.w = acc[od][3] + bv;
    *(float4*)(out + ((size_t)b * ND + o) * NC + l0 + lt * 4) = ov;
  }
}

extern "C" void kernel_launch(void* const* d_in, const int* in_sizes, int n_in,
                              void* d_out, int out_size, void* d_ws, size_t ws_size,
                              hipStream_t stream) {
  const float* C = (const float*)d_in[0];
  const float* Q = (const float*)d_in[1];
  const float* c_mask = (const float*)d_in[2];
  const float* q_mask = (const float*)d_in[3];
  const float* W0 = (const float*)d_in[4];
  const float* dwW = (const float*)d_in[5];
  const float* dwB = (const float*)d_in[6];
  const float* pwW = (const float*)d_in[7];
  const float* pwB = (const float*)d_in[8];
  float* out = (float*)d_out;
  float* ws = (float*)d_ws;

  float* S = ws;                                   // 32*1024*256
  float* rowmax = S + (size_t)NB * NC * NQ;        // 32768
  float* rowsum = rowmax + NB * NC;                // 32768
  float* colmax = rowsum + NB * NC;                // 8192
  float* colsum = colmax + NB * NQ;                // 8192
  float* cb = colsum + NB * NQ;                    // 32768
  float* qb = cb + NB * NC;                        // 8192
  unsigned short* innerT = (unsigned short*)(qb + NB * NQ);   // 32*128*256 bf16
  float* x = (float*)(innerT + (size_t)NB * ND * NQ);         // 32*512*1024 f32

  k0_bias<<<dim3((NB * (NC + NQ) + 255) / 256), 256, 0, stream>>>(C, Q, W0, cb, qb);
  k1_s<<<dim3(64, NB), 256, 2 * ND * 64 * sizeof(float), stream>>>(C, Q, W0, cb, qb, S);
  k2_rowstat<<<dim3(NB * NC / 4), 256, 0, stream>>>(S, q_mask, rowmax, rowsum);
  k3_colstat<<<dim3(NQ / 16, NB), 256, 0, stream>>>(S, c_mask, colmax, colsum);
  k4_inner<<<dim3(NQ / 64, NB), 256, 0, stream>>>(S, C, c_mask, colmax, colsum, innerT);
  k5_mfma<<<dim3(NC / 32, NB), 256, 36864, stream>>>(S, C, Q, innerT, q_mask, rowmax, rowsum, x);
  k6_fused<<<dim3(NC / 64, NB), 256, (8704 + 4352) * sizeof(float), stream>>>(x, dwW, dwB, pwW, pwB, out);
}

// Round 4
// 238.317 us; speedup vs baseline: 2.9092x; 1.4353x over previous
//
#include <hip/hip_runtime.h>
#include <math.h>

#define NB 32
#define ND 128
#define NC 1024
#define NQ 256
#define NEGV (-1e30f)

typedef __attribute__((ext_vector_type(8))) __bf16 bf16x8;
typedef __attribute__((ext_vector_type(4))) float f32x4;
typedef __attribute__((ext_vector_type(8))) unsigned short u16x8;
typedef __attribute__((ext_vector_type(4))) unsigned short u16x4;

__device__ inline unsigned short f2bf(float f) {
  unsigned u = __builtin_bit_cast(unsigned, f);
  u += 0x7FFFu + ((u >> 16) & 1u);
  return (unsigned short)(u >> 16);
}
__device__ inline float bf2f(unsigned short u) {
  return __builtin_bit_cast(float, (unsigned)u << 16);
}

// ---------------- K0: bias vectors
__global__ __launch_bounds__(256) void k0_bias(const float* __restrict__ C, const float* __restrict__ Q,
                                               const float* __restrict__ W0,
                                               float* __restrict__ cb, float* __restrict__ qb) {
  int idx = blockIdx.x * 256 + threadIdx.x;
  if (idx < NB * NC) {
    int b = idx >> 10, i = idx & (NC - 1);
    const float* base = C + ((size_t)b * ND) * NC + i;
    float s = 0.f;
    #pragma unroll 8
    for (int k = 0; k < ND; ++k) s += base[(size_t)k * NC] * W0[k];
    cb[idx] = s;
  } else {
    int r = idx - NB * NC;
    if (r < NB * NQ) {
      int b = r >> 8, j = r & (NQ - 1);
      const float* base = Q + ((size_t)b * ND) * NQ + j;
      float s = 0.f;
      #pragma unroll 8
      for (int k = 0; k < ND; ++k) s += base[(size_t)k * NQ] * W0[ND + k];
      qb[r] = s;
    }
  }
}

// ---------------- K0b: pwW f32 -> bf16
__global__ __launch_bounds__(256) void k_pwcvt(const float* __restrict__ pwW, unsigned short* __restrict__ pwB16) {
  int idx = blockIdx.x * 256 + threadIdx.x;   // 0..8191
  const float4* src = (const float4*)pwW;
  float4 v0 = src[idx * 2], v1 = src[idx * 2 + 1];
  u16x8 o;
  o[0] = f2bf(v0.x); o[1] = f2bf(v0.y); o[2] = f2bf(v0.z); o[3] = f2bf(v0.w);
  o[4] = f2bf(v1.x); o[5] = f2bf(v1.y); o[6] = f2bf(v1.z); o[7] = f2bf(v1.w);
  ((u16x8*)pwB16)[idx] = o;
}

// ---------------- K1: S[b,i,j]
__global__ __launch_bounds__(256) void k1_s(const float* __restrict__ C, const float* __restrict__ Q,
                                            const float* __restrict__ W0,
                                            const float* __restrict__ cb, const float* __restrict__ qb,
                                            float* __restrict__ S) {
  extern __shared__ float sm1[];
  float* Cs = sm1;             // [128][64]
  float* Qs = sm1 + ND * 64;   // [128][64]
  int b = blockIdx.y;
  int i0 = (blockIdx.x & 15) * 64;
  int j0 = (blockIdx.x >> 4) * 64;
  int t = threadIdx.x;
  const float* Cb = C + (size_t)b * ND * NC;
  const float* Qb = Q + (size_t)b * ND * NQ;
  int f4 = (t & 15) * 4;
  #pragma unroll
  for (int it = 0; it < 8; ++it) {
    int k = (t >> 4) + it * 16;
    float w = W0[2 * ND + k];
    float4 v = *(const float4*)(Cb + (size_t)k * NC + i0 + f4);
    v.x *= w; v.y *= w; v.z *= w; v.w *= w;
    *(float4*)(&Cs[k * 64 + f4]) = v;
    *(float4*)(&Qs[k * 64 + f4]) = *(const float4*)(Qb + (size_t)k * NQ + j0 + f4);
  }
  __syncthreads();
  int tj = t & 15, ti = t >> 4;
  float acc[4][4] = {};
  for (int k = 0; k < ND; ++k) {
    float4 c4 = *(const float4*)(&Cs[k * 64 + ti * 4]);
    float4 q4 = *(const float4*)(&Qs[k * 64 + tj * 4]);
    const float cv[4] = {c4.x, c4.y, c4.z, c4.w};
    const float qv[4] = {q4.x, q4.y, q4.z, q4.w};
    #pragma unroll
    for (int a = 0; a < 4; ++a)
      #pragma unroll
      for (int e = 0; e < 4; ++e)
        acc[a][e] = fmaf(cv[a], qv[e], acc[a][e]);
  }
  float qbv[4];
  #pragma unroll
  for (int e = 0; e < 4; ++e) qbv[e] = qb[b * NQ + j0 + tj * 4 + e];
  #pragma unroll
  for (int a = 0; a < 4; ++a) {
    int i = i0 + ti * 4 + a;
    float cbv = cb[b * NC + i];
    float4 o;
    o.x = acc[a][0] + cbv + qbv[0];
    o.y = acc[a][1] + cbv + qbv[1];
    o.z = acc[a][2] + cbv + qbv[2];
    o.w = acc[a][3] + cbv + qbv[3];
    *(float4*)(S + ((size_t)b * NC + i) * NQ + j0 + tj * 4) = o;
  }
}

// ---------------- K2: row stats
__global__ __launch_bounds__(256) void k2_rowstat(const float* __restrict__ S, const float* __restrict__ q_mask,
                                                  float* __restrict__ rowmax, float* __restrict__ rowsum) {
  int wave = threadIdx.x >> 6;
  int lane = threadIdx.x & 63;
  int row = blockIdx.x * 4 + wave;         // b*NC + i
  int b = row >> 10;
  const float* Srow = S + (size_t)row * NQ;
  const float* qm = q_mask + b * NQ;
  float m = -3.0e38f, s = 0.f;
  #pragma unroll
  for (int q = 0; q < 4; ++q) {
    int j = lane + q * 64;
    float qv = qm[j];
    float v = Srow[j] * qv + NEGV * (1.f - qv);
    float mn = fmaxf(m, v);
    s = s * __expf(m - mn) + __expf(v - mn);
    m = mn;
  }
  #pragma unroll
  for (int off = 1; off < 64; off <<= 1) {
    float mo = __shfl_xor(m, off);
    float so = __shfl_xor(s, off);
    float mn = fmaxf(m, mo);
    s = s * __expf(m - mn) + so * __expf(mo - mn);
    m = mn;
  }
  if (lane == 0) { rowmax[row] = m; rowsum[row] = s; }
}

// ---------------- K3: col stats
__global__ __launch_bounds__(256) void k3_colstat(const float* __restrict__ S, const float* __restrict__ c_mask,
                                                  float* __restrict__ colmax, float* __restrict__ colsum) {
  __shared__ float ms[16][17], ss[16][17];
  int b = blockIdx.y;
  int j0 = blockIdx.x * 16;
  int t = threadIdx.x;
  int jj = t & 15, iq = t >> 4;
  const float* Sb = S + (size_t)b * NC * NQ;
  const float* cm = c_mask + b * NC;
  float m = -3.0e38f, s = 0.f;
  for (int i = iq; i < NC; i += 16) {
    float cv = cm[i];
    float v = Sb[(size_t)i * NQ + j0 + jj] * cv + NEGV * (1.f - cv);
    float mn = fmaxf(m, v);
    s = s * __expf(m - mn) + __expf(v - mn);
    m = mn;
  }
  ms[iq][jj] = m; ss[iq][jj] = s;
  __syncthreads();
  if (iq == 0) {
    #pragma unroll
    for (int q = 1; q < 16; ++q) {
      float mo = ms[q][jj], so = ss[q][jj];
      float mn = fmaxf(m, mo);
      s = s * __expf(m - mn) + so * __expf(mo - mn);
      m = mn;
    }
    colmax[b * NQ + j0 + jj] = m;
    colsum[b * NQ + j0 + jj] = s;
  }
}

// ---------------- K4: innerT[b,d,j] (bf16) = sum_i S_bbar[b,i,j] * C[b,d,i]
__global__ __launch_bounds__(256) void k4_inner(const float* __restrict__ S, const float* __restrict__ C,
                                                const float* __restrict__ c_mask,
                                                const float* __restrict__ colmax, const float* __restrict__ colsum,
                                                unsigned short* __restrict__ innerT) {
  __shared__ float Ps[32][64];
  __shared__ float Cs[ND][33];
  __shared__ unsigned short Tb[ND][72];
  int b = blockIdx.y;
  int j0 = blockIdx.x * 64;
  int t = threadIdx.x;
  int dt = t & 15, jt = t >> 4;
  const float* Sb = S + (size_t)b * NC * NQ;
  const float* Cb = C + (size_t)b * ND * NC;
  const float* cm = c_mask + b * NC;
  int jl = t & 63;
  float cmax = colmax[b * NQ + j0 + jl];
  float cinv = 1.0f / colsum[b * NQ + j0 + jl];
  float acc[4][8] = {};
  for (int ic = 0; ic < NC; ic += 32) {
    __syncthreads();
    #pragma unroll
    for (int k = 0; k < 8; ++k) {
      int ii = (t >> 6) + k * 4;
      int i = ic + ii;
      float cv = cm[i];
      float v = Sb[(size_t)i * NQ + j0 + jl];
      float se = v * cv + NEGV * (1.f - cv);
      Ps[ii][jl] = __expf(se - cmax) * cinv;
    }
    #pragma unroll
    for (int k = 0; k < 16; ++k) {
      int idx = t + k * 256;
      int ii = idx & 31, dd = idx >> 5;
      Cs[dd][ii] = Cb[(size_t)dd * NC + ic + ii];
    }
    __syncthreads();
    #pragma unroll
    for (int ii = 0; ii < 32; ++ii) {
      float4 pv = *(const float4*)(&Ps[ii][jt * 4]);
      const float pa[4] = {pv.x, pv.y, pv.z, pv.w};
      float cvals[8];
      #pragma unroll
      for (int dd = 0; dd < 8; ++dd) cvals[dd] = Cs[dt + 16 * dd][ii];
      #pragma unroll
      for (int q = 0; q < 4; ++q)
        #pragma unroll
        for (int dd = 0; dd < 8; ++dd)
          acc[q][dd] = fmaf(pa[q], cvals[dd], acc[q][dd]);
    }
  }
  #pragma unroll
  for (int q = 0; q < 4; ++q)
    #pragma unroll
    for (int dd = 0; dd < 8; ++dd)
      Tb[dt + 16 * dd][jt * 4 + q] = f2bf(acc[q][dd]);
  __syncthreads();
  {
    int d = t >> 1, jh = (t & 1) * 32;
    unsigned short* dst = innerT + ((size_t)b * ND + d) * NQ + j0 + jh;
    #pragma unroll
    for (int s = 0; s < 4; ++s) {
      u16x8 v = *(const u16x8*)&Tb[d][jh + s * 8];
      *(u16x8*)(dst + s * 8) = v;
    }
  }
}

// ---------------- K5 (MFMA): A[i][d] = P@Q^T, Bm[i][d] = P@inner; write concat x (bf16)
__global__ __launch_bounds__(256) void k5_mfma(const float* __restrict__ S, const float* __restrict__ C,
                                               const float* __restrict__ Q,
                                               const unsigned short* __restrict__ innerT,
                                               const float* __restrict__ q_mask,
                                               const float* __restrict__ rowmax, const float* __restrict__ rowsum,
                                               unsigned short* __restrict__ xB) {
  extern __shared__ char sm[];
  unsigned short* Pl = (unsigned short*)sm;            // [32][64] bf16
  unsigned short* Qb = (unsigned short*)(sm + 4096);   // [128][64] bf16
  unsigned short* Ib = (unsigned short*)(sm + 20480);  // [128][64] bf16
  float* As = (float*)sm;                              // [32][133] f32 (aliases, post-compute)
  float* Bs = (float*)(sm + 17024);                    // [32][133] f32
  int b = blockIdx.y, i0 = blockIdx.x * 32;
  int t = threadIdx.x, w = t >> 6, l = t & 63;
  const float* Sb = S + ((size_t)b * NC + i0) * NQ;
  const float* Qg = Q + (size_t)b * ND * NQ;
  const unsigned short* Ig = innerT + (size_t)b * ND * NQ;
  const float* qm = q_mask + b * NQ;

  f32x4 accA[2][2] = {};
  f32x4 accB[2][2] = {};

  int pi = t >> 3, psj = t & 7;
  int qd = t >> 1, qh = t & 1;
  float rmax = rowmax[b * NC + i0 + pi];
  float rinv = 1.0f / rowsum[b * NC + i0 + pi];
  int h = l >> 4, lr = l & 15;

  for (int jc = 0; jc < 4; ++jc) {
    int j0 = jc * 64;
    __syncthreads();
    {
      const float* srow = Sb + (size_t)pi * NQ + j0 + psj * 8;
      float4 s0 = *(const float4*)srow;
      float4 s1 = *(const float4*)(srow + 4);
      float sv[8] = {s0.x, s0.y, s0.z, s0.w, s1.x, s1.y, s1.z, s1.w};
      u16x8 ov;
      #pragma unroll
      for (int e = 0; e < 8; ++e) {
        float qv = qm[j0 + psj * 8 + e];
        float se = sv[e] * qv + NEGV * (1.f - qv);
        ov[e] = f2bf(__expf(se - rmax) * rinv);
      }
      *(u16x8*)&Pl[pi * 64 + (psj ^ (pi & 7)) * 8] = ov;
    }
    {
      const float* qrow = Qg + (size_t)qd * NQ + j0 + qh * 32;
      #pragma unroll
      for (int s = 0; s < 4; ++s) {
        float4 v0 = *(const float4*)(qrow + s * 8);
        float4 v1 = *(const float4*)(qrow + s * 8 + 4);
        u16x8 ov;
        ov[0] = f2bf(v0.x); ov[1] = f2bf(v0.y); ov[2] = f2bf(v0.z); ov[3] = f2bf(v0.w);
        ov[4] = f2bf(v1.x); ov[5] = f2bf(v1.y); ov[6] = f2bf(v1.z); ov[7] = f2bf(v1.w);
        int slot = (qh * 4 + s) ^ (qd & 7);
        *(u16x8*)&Qb[qd * 64 + slot * 8] = ov;
      }
    }
    {
      const unsigned short* irow = Ig + (size_t)qd * NQ + j0 + qh * 32;
      #pragma unroll
      for (int s = 0; s < 4; ++s) {
        u16x8 v = *(const u16x8*)(irow + s * 8);
        int slot = (qh * 4 + s) ^ (qd & 7);
        *(u16x8*)&Ib[qd * 64 + slot * 8] = v;
      }
    }
    __syncthreads();
    #pragma unroll
    for (int ks = 0; ks < 2; ++ks) {
      bf16x8 aP[2], bQ[2], bI[2];
      #pragma unroll
      for (int mi = 0; mi < 2; ++mi) {
        int i = mi * 16 + lr;
        int slot = (ks * 4 + h) ^ (i & 7);
        aP[mi] = *(const bf16x8*)&Pl[i * 64 + slot * 8];
      }
      #pragma unroll
      for (int nd = 0; nd < 2; ++nd) {
        int d = w * 32 + nd * 16 + lr;
        int slot = (ks * 4 + h) ^ (d & 7);
        bQ[nd] = *(const bf16x8*)&Qb[d * 64 + slot * 8];
        bI[nd] = *(const bf16x8*)&Ib[d * 64 + slot * 8];
      }
      #pragma unroll
      for (int mi = 0; mi < 2; ++mi)
        #pragma unroll
        for (int nd = 0; nd < 2; ++nd) {
          accA[mi][nd] = __builtin_amdgcn_mfma_f32_16x16x32_bf16(aP[mi], bQ[nd], accA[mi][nd], 0, 0, 0);
          accB[mi][nd] = __builtin_amdgcn_mfma_f32_16x16x32_bf16(aP[mi], bI[nd], accB[mi][nd], 0, 0, 0);
        }
    }
  }
  __syncthreads();
  #pragma unroll
  for (int mi = 0; mi < 2; ++mi)
    #pragma unroll
    for (int nd = 0; nd < 2; ++nd) {
      int d = w * 32 + nd * 16 + lr;
      #pragma unroll
      for (int r = 0; r < 4; ++r) {
        int i = mi * 16 + h * 4 + r;
        As[i * 133 + d] = accA[mi][nd][r];
        Bs[i * 133 + d] = accB[mi][nd][r];
      }
    }
  __syncthreads();
  {
    int i4 = (t & 7) * 4, db = t >> 3;
    const float* Cb = C + (size_t)b * ND * NC;
    unsigned short* xb = xB + (size_t)b * 4 * ND * NC;
    #pragma unroll
    for (int p = 0; p < 4; ++p) {
      int d = db + p * 32;
      float4 c4 = *(const float4*)&Cb[(size_t)d * NC + i0 + i4];
      float4 a4, b4;
      a4.x = As[(i4 + 0) * 133 + d]; a4.y = As[(i4 + 1) * 133 + d];
      a4.z = As[(i4 + 2) * 133 + d]; a4.w = As[(i4 + 3) * 133 + d];
      b4.x = Bs[(i4 + 0) * 133 + d]; b4.y = Bs[(i4 + 1) * 133 + d];
      b4.z = Bs[(i4 + 2) * 133 + d]; b4.w = Bs[(i4 + 3) * 133 + d];
      u16x4 o0, o1, o2, o3;
      o0[0] = f2bf(c4.x); o0[1] = f2bf(c4.y); o0[2] = f2bf(c4.z); o0[3] = f2bf(c4.w);
      o1[0] = f2bf(a4.x); o1[1] = f2bf(a4.y); o1[2] = f2bf(a4.z); o1[3] = f2bf(a4.w);
      o2[0] = f2bf(c4.x * a4.x); o2[1] = f2bf(c4.y * a4.y); o2[2] = f2bf(c4.z * a4.z); o2[3] = f2bf(c4.w * a4.w);
      o3[0] = f2bf(c4.x * b4.x); o3[1] = f2bf(c4.y * b4.y); o3[2] = f2bf(c4.z * b4.z); o3[3] = f2bf(c4.w * b4.w);
      *(u16x4*)&xb[(size_t)(0 * ND + d) * NC + i0 + i4] = o0;
      *(u16x4*)&xb[(size_t)(1 * ND + d) * NC + i0 + i4] = o1;
      *(u16x4*)&xb[(size_t)(2 * ND + d) * NC + i0 + i4] = o2;
      *(u16x4*)&xb[(size_t)(3 * ND + d) * NC + i0 + i4] = o3;
    }
  }
}

// ---------------- K6 (MFMA): depthwise(k=5,pad2) + pointwise GEMM
// block: 128 out-ch x 32 positions; K=512 in 8 chunks of 64.
// LDS: xs [64][56] shorts @0 (7168B), x1s [32][72] @7168 (4608B), pws [128][72] @11776 (18432B)
__global__ __launch_bounds__(256) void k6_mfma(const unsigned short* __restrict__ x,
                                               const float* __restrict__ dwW, const float* __restrict__ dwB,
                                               const unsigned short* __restrict__ pwB16,
                                               const float* __restrict__ pwB, float* __restrict__ out) {
  extern __shared__ char sm6[];
  unsigned short* xs = (unsigned short*)sm6;            // [64][56]
  unsigned short* x1s = (unsigned short*)(sm6 + 7168);  // [32][72]
  unsigned short* pws = (unsigned short*)(sm6 + 11776); // [128][72]
  int b = blockIdx.y, l0 = blockIdx.x * 32;
  int t = threadIdx.x, w = t >> 6, l = t & 63, h = l >> 4, lr = l & 15;
  const unsigned short* xb = x + (size_t)b * 4 * ND * NC;
  f32x4 acc[2][2] = {};
  int cgw = t & 63, lb = w * 8;

  for (int ch = 0; ch < 8; ++ch) {
    int cg0 = ch * 64;
    __syncthreads();
    // stage xs: window [l0-8, l0+40), 64 rows x 6 segs of 8 shorts
    #pragma unroll
    for (int k = 0; k < 2; ++k) {
      int id2 = t + k * 256;
      if (id2 < 384) {
        int row = id2 / 6, seg = id2 % 6;
        int gl = l0 - 8 + seg * 8;
        u16x8 v = {};
        if ((unsigned)gl <= 1016u)
          v = *(const u16x8*)(xb + (size_t)(cg0 + row) * NC + gl);
        *(u16x8*)&xs[row * 56 + seg * 8] = v;
      }
    }
    // stage pw chunk: [128 o][64 cg]
    #pragma unroll
    for (int k = 0; k < 4; ++k) {
      int id2 = t + k * 256;
      int o = id2 >> 3, s8 = id2 & 7;
      *(u16x8*)&pws[o * 72 + s8 * 8] = *(const u16x8*)(pwB16 + (size_t)o * 512 + cg0 + s8 * 8);
    }
    __syncthreads();
    // depthwise: thread -> channel cgw, 8 outputs l = l0+lb..l0+lb+7
    {
      int gch = cg0 + cgw;
      float bias = dwB[gch];
      float dwv[5];
      #pragma unroll
      for (int tp = 0; tp < 5; ++tp) dwv[tp] = dwW[gch * 5 + tp];
      float f[24];
      #pragma unroll
      for (int s = 0; s < 3; ++s) {
        u16x8 v = *(const u16x8*)&xs[cgw * 56 + lb + s * 8];
        #pragma unroll
        for (int e = 0; e < 8; ++e) f[s * 8 + e] = bf2f(v[e]);
      }
      #pragma unroll
      for (int e = 0; e < 8; ++e) {
        float a = bias;
        #pragma unroll
        for (int tp = 0; tp < 5; ++tp)
          a = fmaf(f[e + 6 + tp], dwv[tp], a);
        x1s[(lb + e) * 72 + cgw] = f2bf(a);
      }
    }
    __syncthreads();
    // MFMA: per wave: o in [w*32, w*32+32), l in [0,32), K chunk 64
    #pragma unroll
    for (int ks = 0; ks < 2; ++ks) {
      bf16x8 aW[2], bX[2];
      #pragma unroll
      for (int mi = 0; mi < 2; ++mi) {
        int o = w * 32 + mi * 16 + lr;
        aW[mi] = *(const bf16x8*)&pws[o * 72 + ks * 32 + h * 8];
      }
      #pragma unroll
      for (int nf = 0; nf < 2; ++nf) {
        int ll = nf * 16 + lr;
        bX[nf] = *(const bf16x8*)&x1s[ll * 72 + ks * 32 + h * 8];
      }
      #pragma unroll
      for (int mi = 0; mi < 2; ++mi)
        #pragma unroll
        for (int nf = 0; nf < 2; ++nf)
          acc[mi][nf] = __builtin_amdgcn_mfma_f32_16x16x32_bf16(aW[mi], bX[nf], acc[mi][nf], 0, 0, 0);
    }
  }
  // epilogue
  #pragma unroll
  for (int mi = 0; mi < 2; ++mi) {
    #pragma unroll
    for (int r = 0; r < 4; ++r) {
      int o = w * 32 + mi * 16 + h * 4 + r;
      float bv = pwB[o];
      #pragma unroll
      for (int nf = 0; nf < 2; ++nf)
        out[((size_t)b * ND + o) * NC + l0 + nf * 16 + lr] = acc[mi][nf][r] + bv;
    }
  }
}

extern "C" void kernel_launch(void* const* d_in, const int* in_sizes, int n_in,
                              void* d_out, int out_size, void* d_ws, size_t ws_size,
                              hipStream_t stream) {
  const float* C = (const float*)d_in[0];
  const float* Q = (const float*)d_in[1];
  const float* c_mask = (const float*)d_in[2];
  const float* q_mask = (const float*)d_in[3];
  const float* W0 = (const float*)d_in[4];
  const float* dwW = (const float*)d_in[5];
  const float* dwB = (const float*)d_in[6];
  const float* pwW = (const float*)d_in[7];
  const float* pwB = (const float*)d_in[8];
  float* out = (float*)d_out;
  float* ws = (float*)d_ws;

  float* S = ws;                                   // 32*1024*256 f32
  float* rowmax = S + (size_t)NB * NC * NQ;
  float* rowsum = rowmax + NB * NC;
  float* colmax = rowsum + NB * NC;
  float* colsum = colmax + NB * NQ;
  float* cb = colsum + NB * NQ;
  float* qb = cb + NB * NC;
  unsigned short* innerT = (unsigned short*)(qb + NB * NQ);   // 32*128*256 bf16
  unsigned short* xB = innerT + (size_t)NB * ND * NQ;         // 32*512*1024 bf16
  unsigned short* pwB16 = xB + (size_t)NB * 4 * ND * NC;      // 128*512 bf16

  k_pwcvt<<<dim3(32), 256, 0, stream>>>(pwW, pwB16);
  k0_bias<<<dim3((NB * (NC + NQ) + 255) / 256), 256, 0, stream>>>(C, Q, W0, cb, qb);
  k1_s<<<dim3(64, NB), 256, 2 * ND * 64 * sizeof(float), stream>>>(C, Q, W0, cb, qb, S);
  k2_rowstat<<<dim3(NB * NC / 4), 256, 0, stream>>>(S, q_mask, rowmax, rowsum);
  k3_colstat<<<dim3(NQ / 16, NB), 256, 0, stream>>>(S, c_mask, colmax, colsum);
  k4_inner<<<dim3(NQ / 64, NB), 256, 0, stream>>>(S, C, c_mask, colmax, colsum, innerT);
  k5_mfma<<<dim3(NC / 32, NB), 256, 36864, stream>>>(S, C, Q, innerT, q_mask, rowmax, rowsum, xB);
  k6_mfma<<<dim3(NC / 32, NB), 256, 30208, stream>>>(xB, dwW, dwB, pwB16, pwB, out);
}

// Round 5
// 216.838 us; speedup vs baseline: 3.1974x; 1.0991x over previous
//
#include <hip/hip_runtime.h>
#include <math.h>

#define NB 32
#define ND 128
#define NC 1024
#define NQ 256
#define NEGV (-1e30f)

typedef __attribute__((ext_vector_type(8))) __bf16 bf16x8;
typedef __attribute__((ext_vector_type(4))) float f32x4;
typedef __attribute__((ext_vector_type(8))) unsigned short u16x8;
typedef __attribute__((ext_vector_type(4))) unsigned short u16x4;

__device__ inline unsigned short f2bf(float f) {
  unsigned u = __builtin_bit_cast(unsigned, f);
  u += 0x7FFFu + ((u >> 16) & 1u);
  return (unsigned short)(u >> 16);
}
__device__ inline float bf2f(unsigned short u) {
  return __builtin_bit_cast(float, (unsigned)u << 16);
}

// ---------------- K0: bias vectors
__global__ __launch_bounds__(256) void k0_bias(const float* __restrict__ C, const float* __restrict__ Q,
                                               const float* __restrict__ W0,
                                               float* __restrict__ cb, float* __restrict__ qb) {
  int idx = blockIdx.x * 256 + threadIdx.x;
  if (idx < NB * NC) {
    int b = idx >> 10, i = idx & (NC - 1);
    const float* base = C + ((size_t)b * ND) * NC + i;
    float s = 0.f;
    #pragma unroll 8
    for (int k = 0; k < ND; ++k) s += base[(size_t)k * NC] * W0[k];
    cb[idx] = s;
  } else {
    int r = idx - NB * NC;
    if (r < NB * NQ) {
      int b = r >> 8, j = r & (NQ - 1);
      const float* base = Q + ((size_t)b * ND) * NQ + j;
      float s = 0.f;
      #pragma unroll 8
      for (int k = 0; k < ND; ++k) s += base[(size_t)k * NQ] * W0[ND + k];
      qb[r] = s;
    }
  }
}

// ---------------- K0b: pwW f32 -> bf16
__global__ __launch_bounds__(256) void k_pwcvt(const float* __restrict__ pwW, unsigned short* __restrict__ pwB16) {
  int idx = blockIdx.x * 256 + threadIdx.x;   // 0..8191
  const float4* src = (const float4*)pwW;
  float4 v0 = src[idx * 2], v1 = src[idx * 2 + 1];
  u16x8 o;
  o[0] = f2bf(v0.x); o[1] = f2bf(v0.y); o[2] = f2bf(v0.z); o[3] = f2bf(v0.w);
  o[4] = f2bf(v1.x); o[5] = f2bf(v1.y); o[6] = f2bf(v1.z); o[7] = f2bf(v1.w);
  ((u16x8*)pwB16)[idx] = o;
}

// ---------------- K1: S[b,i,j]
__global__ __launch_bounds__(256) void k1_s(const float* __restrict__ C, const float* __restrict__ Q,
                                            const float* __restrict__ W0,
                                            const float* __restrict__ cb, const float* __restrict__ qb,
                                            float* __restrict__ S) {
  extern __shared__ float sm1[];
  float* Cs = sm1;             // [128][64]
  float* Qs = sm1 + ND * 64;   // [128][64]
  int b = blockIdx.y;
  int i0 = (blockIdx.x & 15) * 64;
  int j0 = (blockIdx.x >> 4) * 64;
  int t = threadIdx.x;
  const float* Cb = C + (size_t)b * ND * NC;
  const float* Qb = Q + (size_t)b * ND * NQ;
  int f4 = (t & 15) * 4;
  #pragma unroll
  for (int it = 0; it < 8; ++it) {
    int k = (t >> 4) + it * 16;
    float w = W0[2 * ND + k];
    float4 v = *(const float4*)(Cb + (size_t)k * NC + i0 + f4);
    v.x *= w; v.y *= w; v.z *= w; v.w *= w;
    *(float4*)(&Cs[k * 64 + f4]) = v;
    *(float4*)(&Qs[k * 64 + f4]) = *(const float4*)(Qb + (size_t)k * NQ + j0 + f4);
  }
  __syncthreads();
  int tj = t & 15, ti = t >> 4;
  float acc[4][4] = {};
  for (int k = 0; k < ND; ++k) {
    float4 c4 = *(const float4*)(&Cs[k * 64 + ti * 4]);
    float4 q4 = *(const float4*)(&Qs[k * 64 + tj * 4]);
    const float cv[4] = {c4.x, c4.y, c4.z, c4.w};
    const float qv[4] = {q4.x, q4.y, q4.z, q4.w};
    #pragma unroll
    for (int a = 0; a < 4; ++a)
      #pragma unroll
      for (int e = 0; e < 4; ++e)
        acc[a][e] = fmaf(cv[a], qv[e], acc[a][e]);
  }
  float qbv[4];
  #pragma unroll
  for (int e = 0; e < 4; ++e) qbv[e] = qb[b * NQ + j0 + tj * 4 + e];
  #pragma unroll
  for (int a = 0; a < 4; ++a) {
    int i = i0 + ti * 4 + a;
    float cbv = cb[b * NC + i];
    float4 o;
    o.x = acc[a][0] + cbv + qbv[0];
    o.y = acc[a][1] + cbv + qbv[1];
    o.z = acc[a][2] + cbv + qbv[2];
    o.w = acc[a][3] + cbv + qbv[3];
    *(float4*)(S + ((size_t)b * NC + i) * NQ + j0 + tj * 4) = o;
  }
}

// ---------------- K2: row stats
__global__ __launch_bounds__(256) void k2_rowstat(const float* __restrict__ S, const float* __restrict__ q_mask,
                                                  float* __restrict__ rowmax, float* __restrict__ rowsum) {
  int wave = threadIdx.x >> 6;
  int lane = threadIdx.x & 63;
  int row = blockIdx.x * 4 + wave;         // b*NC + i
  int b = row >> 10;
  const float* Srow = S + (size_t)row * NQ;
  const float* qm = q_mask + b * NQ;
  float m = -3.0e38f, s = 0.f;
  #pragma unroll
  for (int q = 0; q < 4; ++q) {
    int j = lane + q * 64;
    float qv = qm[j];
    float v = Srow[j] * qv + NEGV * (1.f - qv);
    float mn = fmaxf(m, v);
    s = s * __expf(m - mn) + __expf(v - mn);
    m = mn;
  }
  #pragma unroll
  for (int off = 1; off < 64; off <<= 1) {
    float mo = __shfl_xor(m, off);
    float so = __shfl_xor(s, off);
    float mn = fmaxf(m, mo);
    s = s * __expf(m - mn) + so * __expf(mo - mn);
    m = mn;
  }
  if (lane == 0) { rowmax[row] = m; rowsum[row] = s; }
}

// ---------------- K3: col stats
__global__ __launch_bounds__(256) void k3_colstat(const float* __restrict__ S, const float* __restrict__ c_mask,
                                                  float* __restrict__ colmax, float* __restrict__ colsum) {
  __shared__ float ms[16][17], ss[16][17];
  int b = blockIdx.y;
  int j0 = blockIdx.x * 16;
  int t = threadIdx.x;
  int jj = t & 15, iq = t >> 4;
  const float* Sb = S + (size_t)b * NC * NQ;
  const float* cm = c_mask + b * NC;
  float m = -3.0e38f, s = 0.f;
  for (int i = iq; i < NC; i += 16) {
    float cv = cm[i];
    float v = Sb[(size_t)i * NQ + j0 + jj] * cv + NEGV * (1.f - cv);
    float mn = fmaxf(m, v);
    s = s * __expf(m - mn) + __expf(v - mn);
    m = mn;
  }
  ms[iq][jj] = m; ss[iq][jj] = s;
  __syncthreads();
  if (iq == 0) {
    #pragma unroll
    for (int q = 1; q < 16; ++q) {
      float mo = ms[q][jj], so = ss[q][jj];
      float mn = fmaxf(m, mo);
      s = s * __expf(m - mn) + so * __expf(mo - mn);
      m = mn;
    }
    colmax[b * NQ + j0 + jj] = m;
    colsum[b * NQ + j0 + jj] = s;
  }
}

// ---------------- K4 (MFMA): innerT[b,d,j] = sum_i P[i,j]*C[b,d,i]
// block: 64d x 64j, K=1024 in 16 chunks of 64. grid (8, NB) = 256 blocks.
// LDS: Cs [64][64] bf16 XOR-swz, Pt [64][64] bf16 XOR-swz (16 KB total).
__global__ __launch_bounds__(256) void k4_mfma(const float* __restrict__ S, const float* __restrict__ C,
                                               const float* __restrict__ c_mask,
                                               const float* __restrict__ colmax, const float* __restrict__ colsum,
                                               unsigned short* __restrict__ innerT) {
  __shared__ unsigned short Cs[64 * 64];
  __shared__ unsigned short Pt[64 * 64];
  int b = blockIdx.y;
  int d0 = (blockIdx.x & 1) * 64;
  int j0 = (blockIdx.x >> 1) * 64;
  int t = threadIdx.x, w = t >> 6, l = t & 63, h = l >> 4, lr = l & 15;
  const float* Sb = S + (size_t)b * NC * NQ;
  const float* Cb = C + (size_t)b * ND * NC;
  const float* cm = c_mask + b * NC;
  int jl = t & 63, ib = t >> 6;        // Pt staging: j = j0+jl, i = ic+ib*16+e
  int crow = t >> 2, cq = t & 3;       // Cs staging: d = d0+crow, i = ic+cq*16+e
  float cmax = colmax[b * NQ + j0 + jl];
  float cinv = 1.0f / colsum[b * NQ + j0 + jl];
  int wd = (w >> 1) * 32, wj = (w & 1) * 32;
  f32x4 acc[2][2] = {};

  for (int ic = 0; ic < NC; ic += 64) {
    __syncthreads();
    // --- stage Cs (f32 -> bf16), row crow, 16 i's
    {
      const float* src = Cb + (size_t)(d0 + crow) * NC + ic + cq * 16;
      float4 v0 = *(const float4*)(src);
      float4 v1 = *(const float4*)(src + 4);
      float4 v2 = *(const float4*)(src + 8);
      float4 v3 = *(const float4*)(src + 12);
      u16x8 o0, o1;
      o0[0] = f2bf(v0.x); o0[1] = f2bf(v0.y); o0[2] = f2bf(v0.z); o0[3] = f2bf(v0.w);
      o0[4] = f2bf(v1.x); o0[5] = f2bf(v1.y); o0[6] = f2bf(v1.z); o0[7] = f2bf(v1.w);
      o1[0] = f2bf(v2.x); o1[1] = f2bf(v2.y); o1[2] = f2bf(v2.z); o1[3] = f2bf(v2.w);
      o1[4] = f2bf(v3.x); o1[5] = f2bf(v3.y); o1[6] = f2bf(v3.z); o1[7] = f2bf(v3.w);
      int s0 = (cq * 2 + 0) ^ (crow & 7), s1 = (cq * 2 + 1) ^ (crow & 7);
      *(u16x8*)&Cs[crow * 64 + s0 * 8] = o0;
      *(u16x8*)&Cs[crow * 64 + s1 * 8] = o1;
    }
    // --- stage Pt: thread owns one j, 16 consecutive i -> vectorized transposed write
    {
      float pv[16];
      #pragma unroll
      for (int e = 0; e < 16; ++e) {
        int i = ic + ib * 16 + e;
        float cv = cm[i];
        float sv = Sb[(size_t)i * NQ + j0 + jl];
        float se = sv * cv + NEGV * (1.f - cv);
        pv[e] = __expf(se - cmax) * cinv;
      }
      u16x8 o0, o1;
      #pragma unroll
      for (int e = 0; e < 8; ++e) { o0[e] = f2bf(pv[e]); o1[e] = f2bf(pv[8 + e]); }
      int s0 = (ib * 2 + 0) ^ (jl & 7), s1 = (ib * 2 + 1) ^ (jl & 7);
      *(u16x8*)&Pt[jl * 64 + s0 * 8] = o0;
      *(u16x8*)&Pt[jl * 64 + s1 * 8] = o1;
    }
    __syncthreads();
    // --- MFMA: 2 K-steps of 32
    #pragma unroll
    for (int ks = 0; ks < 2; ++ks) {
      bf16x8 aC[2], bP[2];
      #pragma unroll
      for (int mi = 0; mi < 2; ++mi) {
        int row = wd + mi * 16 + lr;
        aC[mi] = *(const bf16x8*)&Cs[row * 64 + (((ks * 4 + h) ^ (lr & 7)) * 8)];
      }
      #pragma unroll
      for (int nf = 0; nf < 2; ++nf) {
        int row = wj + nf * 16 + lr;
        bP[nf] = *(const bf16x8*)&Pt[row * 64 + (((ks * 4 + h) ^ (lr & 7)) * 8)];
      }
      #pragma unroll
      for (int mi = 0; mi < 2; ++mi)
        #pragma unroll
        for (int nf = 0; nf < 2; ++nf)
          acc[mi][nf] = __builtin_amdgcn_mfma_f32_16x16x32_bf16(aC[mi], bP[nf], acc[mi][nf], 0, 0, 0);
    }
  }
  // --- epilogue: innerT[d][j]
  #pragma unroll
  for (int mi = 0; mi < 2; ++mi)
    #pragma unroll
    for (int nf = 0; nf < 2; ++nf)
      #pragma unroll
      for (int r = 0; r < 4; ++r) {
        int d = d0 + wd + mi * 16 + h * 4 + r;
        int j = j0 + wj + nf * 16 + lr;
        innerT[((size_t)b * ND + d) * NQ + j] = f2bf(acc[mi][nf][r]);
      }
}

// ---------------- K5 (MFMA): A[i][d] = P@Q^T, Bm[i][d] = P@inner; write concat x (bf16)
__global__ __launch_bounds__(256) void k5_mfma(const float* __restrict__ S, const float* __restrict__ C,
                                               const float* __restrict__ Q,
                                               const unsigned short* __restrict__ innerT,
                                               const float* __restrict__ q_mask,
                                               const float* __restrict__ rowmax, const float* __restrict__ rowsum,
                                               unsigned short* __restrict__ xB) {
  extern __shared__ char sm[];
  unsigned short* Pl = (unsigned short*)sm;            // [32][64] bf16
  unsigned short* Qb = (unsigned short*)(sm + 4096);   // [128][64] bf16
  unsigned short* Ib = (unsigned short*)(sm + 20480);  // [128][64] bf16
  float* As = (float*)sm;                              // [32][133] f32 (aliases, post-compute)
  float* Bs = (float*)(sm + 17024);                    // [32][133] f32
  int b = blockIdx.y, i0 = blockIdx.x * 32;
  int t = threadIdx.x, w = t >> 6, l = t & 63;
  const float* Sb = S + ((size_t)b * NC + i0) * NQ;
  const float* Qg = Q + (size_t)b * ND * NQ;
  const unsigned short* Ig = innerT + (size_t)b * ND * NQ;
  const float* qm = q_mask + b * NQ;

  f32x4 accA[2][2] = {};
  f32x4 accB[2][2] = {};

  int pi = t >> 3, psj = t & 7;
  int qd = t >> 1, qh = t & 1;
  float rmax = rowmax[b * NC + i0 + pi];
  float rinv = 1.0f / rowsum[b * NC + i0 + pi];
  int h = l >> 4, lr = l & 15;

  for (int jc = 0; jc < 4; ++jc) {
    int j0 = jc * 64;
    __syncthreads();
    {
      const float* srow = Sb + (size_t)pi * NQ + j0 + psj * 8;
      float4 s0 = *(const float4*)srow;
      float4 s1 = *(const float4*)(srow + 4);
      float sv[8] = {s0.x, s0.y, s0.z, s0.w, s1.x, s1.y, s1.z, s1.w};
      u16x8 ov;
      #pragma unroll
      for (int e = 0; e < 8; ++e) {
        float qv = qm[j0 + psj * 8 + e];
        float se = sv[e] * qv + NEGV * (1.f - qv);
        ov[e] = f2bf(__expf(se - rmax) * rinv);
      }
      *(u16x8*)&Pl[pi * 64 + (psj ^ (pi & 7)) * 8] = ov;
    }
    {
      const float* qrow = Qg + (size_t)qd * NQ + j0 + qh * 32;
      #pragma unroll
      for (int s = 0; s < 4; ++s) {
        float4 v0 = *(const float4*)(qrow + s * 8);
        float4 v1 = *(const float4*)(qrow + s * 8 + 4);
        u16x8 ov;
        ov[0] = f2bf(v0.x); ov[1] = f2bf(v0.y); ov[2] = f2bf(v0.z); ov[3] = f2bf(v0.w);
        ov[4] = f2bf(v1.x); ov[5] = f2bf(v1.y); ov[6] = f2bf(v1.z); ov[7] = f2bf(v1.w);
        int slot = (qh * 4 + s) ^ (qd & 7);
        *(u16x8*)&Qb[qd * 64 + slot * 8] = ov;
      }
    }
    {
      const unsigned short* irow = Ig + (size_t)qd * NQ + j0 + qh * 32;
      #pragma unroll
      for (int s = 0; s < 4; ++s) {
        u16x8 v = *(const u16x8*)(irow + s * 8);
        int slot = (qh * 4 + s) ^ (qd & 7);
        *(u16x8*)&Ib[qd * 64 + slot * 8] = v;
      }
    }
    __syncthreads();
    #pragma unroll
    for (int ks = 0; ks < 2; ++ks) {
      bf16x8 aP[2], bQ[2], bI[2];
      #pragma unroll
      for (int mi = 0; mi < 2; ++mi) {
        int i = mi * 16 + lr;
        int slot = (ks * 4 + h) ^ (i & 7);
        aP[mi] = *(const bf16x8*)&Pl[i * 64 + slot * 8];
      }
      #pragma unroll
      for (int nd = 0; nd < 2; ++nd) {
        int d = w * 32 + nd * 16 + lr;
        int slot = (ks * 4 + h) ^ (d & 7);
        bQ[nd] = *(const bf16x8*)&Qb[d * 64 + slot * 8];
        bI[nd] = *(const bf16x8*)&Ib[d * 64 + slot * 8];
      }
      #pragma unroll
      for (int mi = 0; mi < 2; ++mi)
        #pragma unroll
        for (int nd = 0; nd < 2; ++nd) {
          accA[mi][nd] = __builtin_amdgcn_mfma_f32_16x16x32_bf16(aP[mi], bQ[nd], accA[mi][nd], 0, 0, 0);
          accB[mi][nd] = __builtin_amdgcn_mfma_f32_16x16x32_bf16(aP[mi], bI[nd], accB[mi][nd], 0, 0, 0);
        }
    }
  }
  __syncthreads();
  #pragma unroll
  for (int mi = 0; mi < 2; ++mi)
    #pragma unroll
    for (int nd = 0; nd < 2; ++nd) {
      int d = w * 32 + nd * 16 + lr;
      #pragma unroll
      for (int r = 0; r < 4; ++r) {
        int i = mi * 16 + h * 4 + r;
        As[i * 133 + d] = accA[mi][nd][r];
        Bs[i * 133 + d] = accB[mi][nd][r];
      }
    }
  __syncthreads();
  {
    int i4 = (t & 7) * 4, db = t >> 3;
    const float* Cb = C + (size_t)b * ND * NC;
    unsigned short* xb = xB + (size_t)b * 4 * ND * NC;
    #pragma unroll
    for (int p = 0; p < 4; ++p) {
      int d = db + p * 32;
      float4 c4 = *(const float4*)&Cb[(size_t)d * NC + i0 + i4];
      float4 a4, b4;
      a4.x = As[(i4 + 0) * 133 + d]; a4.y = As[(i4 + 1) * 133 + d];
      a4.z = As[(i4 + 2) * 133 + d]; a4.w = As[(i4 + 3) * 133 + d];
      b4.x = Bs[(i4 + 0) * 133 + d]; b4.y = Bs[(i4 + 1) * 133 + d];
      b4.z = Bs[(i4 + 2) * 133 + d]; b4.w = Bs[(i4 + 3) * 133 + d];
      u16x4 o0, o1, o2, o3;
      o0[0] = f2bf(c4.x); o0[1] = f2bf(c4.y); o0[2] = f2bf(c4.z); o0[3] = f2bf(c4.w);
      o1[0] = f2bf(a4.x); o1[1] = f2bf(a4.y); o1[2] = f2bf(a4.z); o1[3] = f2bf(a4.w);
      o2[0] = f2bf(c4.x * a4.x); o2[1] = f2bf(c4.y * a4.y); o2[2] = f2bf(c4.z * a4.z); o2[3] = f2bf(c4.w * a4.w);
      o3[0] = f2bf(c4.x * b4.x); o3[1] = f2bf(c4.y * b4.y); o3[2] = f2bf(c4.z * b4.z); o3[3] = f2bf(c4.w * b4.w);
      *(u16x4*)&xb[(size_t)(0 * ND + d) * NC + i0 + i4] = o0;
      *(u16x4*)&xb[(size_t)(1 * ND + d) * NC + i0 + i4] = o1;
      *(u16x4*)&xb[(size_t)(2 * ND + d) * NC + i0 + i4] = o2;
      *(u16x4*)&xb[(size_t)(3 * ND + d) * NC + i0 + i4] = o3;
    }
  }
}

// ---------------- K6 (MFMA): depthwise(k=5,pad2) + pointwise GEMM
__global__ __launch_bounds__(256) void k6_mfma(const unsigned short* __restrict__ x,
                                               const float* __restrict__ dwW, const float* __restrict__ dwB,
                                               const unsigned short* __restrict__ pwB16,
                                               const float* __restrict__ pwB, float* __restrict__ out) {
  extern __shared__ char sm6[];
  unsigned short* xs = (unsigned short*)sm6;            // [64][56]
  unsigned short* x1s = (unsigned short*)(sm6 + 7168);  // [32][72]
  unsigned short* pws = (unsigned short*)(sm6 + 11776); // [128][72]
  int b = blockIdx.y, l0 = blockIdx.x * 32;
  int t = threadIdx.x, w = t >> 6, l = t & 63, h = l >> 4, lr = l & 15;
  const unsigned short* xb = x + (size_t)b * 4 * ND * NC;
  f32x4 acc[2][2] = {};
  int cgw = t & 63, lb = w * 8;

  for (int ch = 0; ch < 8; ++ch) {
    int cg0 = ch * 64;
    __syncthreads();
    #pragma unroll
    for (int k = 0; k < 2; ++k) {
      int id2 = t + k * 256;
      if (id2 < 384) {
        int row = id2 / 6, seg = id2 % 6;
        int gl = l0 - 8 + seg * 8;
        u16x8 v = {};
        if ((unsigned)gl <= 1016u)
          v = *(const u16x8*)(xb + (size_t)(cg0 + row) * NC + gl);
        *(u16x8*)&xs[row * 56 + seg * 8] = v;
      }
    }
    #pragma unroll
    for (int k = 0; k < 4; ++k) {
      int id2 = t + k * 256;
      int o = id2 >> 3, s8 = id2 & 7;
      *(u16x8*)&pws[o * 72 + s8 * 8] = *(const u16x8*)(pwB16 + (size_t)o * 512 + cg0 + s8 * 8);
    }
    __syncthreads();
    {
      int gch = cg0 + cgw;
      float bias = dwB[gch];
      float dwv[5];
      #pragma unroll
      for (int tp = 0; tp < 5; ++tp) dwv[tp] = dwW[gch * 5 + tp];
      float f[24];
      #pragma unroll
      for (int s = 0; s < 3; ++s) {
        u16x8 v = *(const u16x8*)&xs[cgw * 56 + lb + s * 8];
        #pragma unroll
        for (int e = 0; e < 8; ++e) f[s * 8 + e] = bf2f(v[e]);
      }
      #pragma unroll
      for (int e = 0; e < 8; ++e) {
        float a = bias;
        #pragma unroll
        for (int tp = 0; tp < 5; ++tp)
          a = fmaf(f[e + 6 + tp], dwv[tp], a);
        x1s[(lb + e) * 72 + cgw] = f2bf(a);
      }
    }
    __syncthreads();
    #pragma unroll
    for (int ks = 0; ks < 2; ++ks) {
      bf16x8 aW[2], bX[2];
      #pragma unroll
      for (int mi = 0; mi < 2; ++mi) {
        int o = w * 32 + mi * 16 + lr;
        aW[mi] = *(const bf16x8*)&pws[o * 72 + ks * 32 + h * 8];
      }
      #pragma unroll
      for (int nf = 0; nf < 2; ++nf) {
        int ll = nf * 16 + lr;
        bX[nf] = *(const bf16x8*)&x1s[ll * 72 + ks * 32 + h * 8];
      }
      #pragma unroll
      for (int mi = 0; mi < 2; ++mi)
        #pragma unroll
        for (int nf = 0; nf < 2; ++nf)
          acc[mi][nf] = __builtin_amdgcn_mfma_f32_16x16x32_bf16(aW[mi], bX[nf], acc[mi][nf], 0, 0, 0);
    }
  }
  #pragma unroll
  for (int mi = 0; mi < 2; ++mi) {
    #pragma unroll
    for (int r = 0; r < 4; ++r) {
      int o = w * 32 + mi * 16 + h * 4 + r;
      float bv = pwB[o];
      #pragma unroll
      for (int nf = 0; nf < 2; ++nf)
        out[((size_t)b * ND + o) * NC + l0 + nf * 16 + lr] = acc[mi][nf][r] + bv;
    }
  }
}

extern "C" void kernel_launch(void* const* d_in, const int* in_sizes, int n_in,
                              void* d_out, int out_size, void* d_ws, size_t ws_size,
                              hipStream_t stream) {
  const float* C = (const float*)d_in[0];
  const float* Q = (const float*)d_in[1];
  const float* c_mask = (const float*)d_in[2];
  const float* q_mask = (const float*)d_in[3];
  const float* W0 = (const float*)d_in[4];
  const float* dwW = (const float*)d_in[5];
  const float* dwB = (const float*)d_in[6];
  const float* pwW = (const float*)d_in[7];
  const float* pwB = (const float*)d_in[8];
  float* out = (float*)d_out;
  float* ws = (float*)d_ws;

  float* S = ws;                                   // 32*1024*256 f32
  float* rowmax = S + (size_t)NB * NC * NQ;
  float* rowsum = rowmax + NB * NC;
  float* colmax = rowsum + NB * NC;
  float* colsum = colmax + NB * NQ;
  float* cb = colsum + NB * NQ;
  float* qb = cb + NB * NC;
  unsigned short* innerT = (unsigned short*)(qb + NB * NQ);   // 32*128*256 bf16
  unsigned short* xB = innerT + (size_t)NB * ND * NQ;         // 32*512*1024 bf16
  unsigned short* pwB16 = xB + (size_t)NB * 4 * ND * NC;      // 128*512 bf16

  k_pwcvt<<<dim3(32), 256, 0, stream>>>(pwW, pwB16);
  k0_bias<<<dim3((NB * (NC + NQ) + 255) / 256), 256, 0, stream>>>(C, Q, W0, cb, qb);
  k1_s<<<dim3(64, NB), 256, 2 * ND * 64 * sizeof(float), stream>>>(C, Q, W0, cb, qb, S);
  k2_rowstat<<<dim3(NB * NC / 4), 256, 0, stream>>>(S, q_mask, rowmax, rowsum);
  k3_colstat<<<dim3(NQ / 16, NB), 256, 0, stream>>>(S, c_mask, colmax, colsum);
  k4_mfma<<<dim3(8, NB), 256, 0, stream>>>(S, C, c_mask, colmax, colsum, innerT);
  k5_mfma<<<dim3(NC / 32, NB), 256, 36864, stream>>>(S, C, Q, innerT, q_mask, rowmax, rowsum, xB);
  k6_mfma<<<dim3(NC / 32, NB), 256, 30208, stream>>>(xB, dwW, dwB, pwB16, pwB, out);
}

// Round 6
// 182.642 us; speedup vs baseline: 3.7960x; 1.1872x over previous
//
#include <hip/hip_runtime.h>
#include <math.h>

#define NB 32
#define ND 128
#define NC 1024
#define NQ 256
#define NEGV (-1e30f)
#define K4SPLIT 4

typedef __attribute__((ext_vector_type(8))) __bf16 bf16x8;
typedef __attribute__((ext_vector_type(4))) float f32x4;
typedef __attribute__((ext_vector_type(8))) unsigned short u16x8;
typedef __attribute__((ext_vector_type(4))) unsigned short u16x4;

__device__ inline unsigned short f2bf(float f) {
  unsigned u = __builtin_bit_cast(unsigned, f);
  u += 0x7FFFu + ((u >> 16) & 1u);
  return (unsigned short)(u >> 16);
}
__device__ inline float bf2f(unsigned short u) {
  return __builtin_bit_cast(float, (unsigned)u << 16);
}

// ---------------- K0: bias vectors
__global__ __launch_bounds__(256) void k0_bias(const float* __restrict__ C, const float* __restrict__ Q,
                                               const float* __restrict__ W0,
                                               float* __restrict__ cb, float* __restrict__ qb) {
  int idx = blockIdx.x * 256 + threadIdx.x;
  if (idx < NB * NC) {
    int b = idx >> 10, i = idx & (NC - 1);
    const float* base = C + ((size_t)b * ND) * NC + i;
    float s = 0.f;
    #pragma unroll 8
    for (int k = 0; k < ND; ++k) s += base[(size_t)k * NC] * W0[k];
    cb[idx] = s;
  } else {
    int r = idx - NB * NC;
    if (r < NB * NQ) {
      int b = r >> 8, j = r & (NQ - 1);
      const float* base = Q + ((size_t)b * ND) * NQ + j;
      float s = 0.f;
      #pragma unroll 8
      for (int k = 0; k < ND; ++k) s += base[(size_t)k * NQ] * W0[ND + k];
      qb[r] = s;
    }
  }
}

// ---------------- K0b: pwW f32 -> bf16
__global__ __launch_bounds__(256) void k_pwcvt(const float* __restrict__ pwW, unsigned short* __restrict__ pwB16) {
  int idx = blockIdx.x * 256 + threadIdx.x;   // 0..8191
  const float4* src = (const float4*)pwW;
  float4 v0 = src[idx * 2], v1 = src[idx * 2 + 1];
  u16x8 o;
  o[0] = f2bf(v0.x); o[1] = f2bf(v0.y); o[2] = f2bf(v0.z); o[3] = f2bf(v0.w);
  o[4] = f2bf(v1.x); o[5] = f2bf(v1.y); o[6] = f2bf(v1.z); o[7] = f2bf(v1.w);
  ((u16x8*)pwB16)[idx] = o;
}

// ---------------- K1: S[b,i,j]
__global__ __launch_bounds__(256) void k1_s(const float* __restrict__ C, const float* __restrict__ Q,
                                            const float* __restrict__ W0,
                                            const float* __restrict__ cb, const float* __restrict__ qb,
                                            float* __restrict__ S) {
  extern __shared__ float sm1[];
  float* Cs = sm1;             // [128][64]
  float* Qs = sm1 + ND * 64;   // [128][64]
  int b = blockIdx.y;
  int i0 = (blockIdx.x & 15) * 64;
  int j0 = (blockIdx.x >> 4) * 64;
  int t = threadIdx.x;
  const float* Cb = C + (size_t)b * ND * NC;
  const float* Qb = Q + (size_t)b * ND * NQ;
  int f4 = (t & 15) * 4;
  #pragma unroll
  for (int it = 0; it < 8; ++it) {
    int k = (t >> 4) + it * 16;
    float w = W0[2 * ND + k];
    float4 v = *(const float4*)(Cb + (size_t)k * NC + i0 + f4);
    v.x *= w; v.y *= w; v.z *= w; v.w *= w;
    *(float4*)(&Cs[k * 64 + f4]) = v;
    *(float4*)(&Qs[k * 64 + f4]) = *(const float4*)(Qb + (size_t)k * NQ + j0 + f4);
  }
  __syncthreads();
  int tj = t & 15, ti = t >> 4;
  float acc[4][4] = {};
  for (int k = 0; k < ND; ++k) {
    float4 c4 = *(const float4*)(&Cs[k * 64 + ti * 4]);
    float4 q4 = *(const float4*)(&Qs[k * 64 + tj * 4]);
    const float cv[4] = {c4.x, c4.y, c4.z, c4.w};
    const float qv[4] = {q4.x, q4.y, q4.z, q4.w};
    #pragma unroll
    for (int a = 0; a < 4; ++a)
      #pragma unroll
      for (int e = 0; e < 4; ++e)
        acc[a][e] = fmaf(cv[a], qv[e], acc[a][e]);
  }
  float qbv[4];
  #pragma unroll
  for (int e = 0; e < 4; ++e) qbv[e] = qb[b * NQ + j0 + tj * 4 + e];
  #pragma unroll
  for (int a = 0; a < 4; ++a) {
    int i = i0 + ti * 4 + a;
    float cbv = cb[b * NC + i];
    float4 o;
    o.x = acc[a][0] + cbv + qbv[0];
    o.y = acc[a][1] + cbv + qbv[1];
    o.z = acc[a][2] + cbv + qbv[2];
    o.w = acc[a][3] + cbv + qbv[3];
    *(float4*)(S + ((size_t)b * NC + i) * NQ + j0 + tj * 4) = o;
  }
}

// ---------------- K2: row stats
__global__ __launch_bounds__(256) void k2_rowstat(const float* __restrict__ S, const float* __restrict__ q_mask,
                                                  float* __restrict__ rowmax, float* __restrict__ rowsum) {
  int wave = threadIdx.x >> 6;
  int lane = threadIdx.x & 63;
  int row = blockIdx.x * 4 + wave;         // b*NC + i
  int b = row >> 10;
  const float* Srow = S + (size_t)row * NQ;
  const float* qm = q_mask + b * NQ;
  float m = -3.0e38f, s = 0.f;
  #pragma unroll
  for (int q = 0; q < 4; ++q) {
    int j = lane + q * 64;
    float qv = qm[j];
    float v = Srow[j] * qv + NEGV * (1.f - qv);
    float mn = fmaxf(m, v);
    s = s * __expf(m - mn) + __expf(v - mn);
    m = mn;
  }
  #pragma unroll
  for (int off = 1; off < 64; off <<= 1) {
    float mo = __shfl_xor(m, off);
    float so = __shfl_xor(s, off);
    float mn = fmaxf(m, mo);
    s = s * __expf(m - mn) + so * __expf(mo - mn);
    m = mn;
  }
  if (lane == 0) { rowmax[row] = m; rowsum[row] = s; }
}

// ---------------- K3: col stats
__global__ __launch_bounds__(256) void k3_colstat(const float* __restrict__ S, const float* __restrict__ c_mask,
                                                  float* __restrict__ colmax, float* __restrict__ colsum) {
  __shared__ float ms[16][17], ss[16][17];
  int b = blockIdx.y;
  int j0 = blockIdx.x * 16;
  int t = threadIdx.x;
  int jj = t & 15, iq = t >> 4;
  const float* Sb = S + (size_t)b * NC * NQ;
  const float* cm = c_mask + b * NC;
  float m = -3.0e38f, s = 0.f;
  for (int i = iq; i < NC; i += 16) {
    float cv = cm[i];
    float v = Sb[(size_t)i * NQ + j0 + jj] * cv + NEGV * (1.f - cv);
    float mn = fmaxf(m, v);
    s = s * __expf(m - mn) + __expf(v - mn);
    m = mn;
  }
  ms[iq][jj] = m; ss[iq][jj] = s;
  __syncthreads();
  if (iq == 0) {
    #pragma unroll
    for (int q = 1; q < 16; ++q) {
      float mo = ms[q][jj], so = ss[q][jj];
      float mn = fmaxf(m, mo);
      s = s * __expf(m - mn) + so * __expf(mo - mn);
      m = mn;
    }
    colmax[b * NQ + j0 + jj] = m;
    colsum[b * NQ + j0 + jj] = s;
  }
}

// ---------------- K4 (MFMA, split-K): partial[split][b][d][j] = sum_{i in chunk} P[i,j]*C[b,d,i]
// block: 64d x 64j x 256i; grid (8 tiles * 4 splits, NB) = 1024 blocks.
__global__ __launch_bounds__(256) void k4_mfma(const float* __restrict__ S, const float* __restrict__ C,
                                               const float* __restrict__ c_mask,
                                               const float* __restrict__ colmax, const float* __restrict__ colsum,
                                               float* __restrict__ partial) {
  __shared__ unsigned short Cs[64 * 64];
  __shared__ unsigned short Pt[64 * 64];
  int b = blockIdx.y;
  int tile = blockIdx.x & 7, split = blockIdx.x >> 3;
  int d0 = (tile & 1) * 64;
  int j0 = (tile >> 1) * 64;
  int icb = split * (NC / K4SPLIT);
  int t = threadIdx.x, w = t >> 6, l = t & 63, h = l >> 4, lr = l & 15;
  const float* Sb = S + (size_t)b * NC * NQ;
  const float* Cb = C + (size_t)b * ND * NC;
  const float* cm = c_mask + b * NC;
  int jl = t & 63, ib = t >> 6;        // Pt staging: j = j0+jl, i = ic+ib*16+e
  int crow = t >> 2, cq = t & 3;       // Cs staging: d = d0+crow, i = ic+cq*16+e
  float cmax = colmax[b * NQ + j0 + jl];
  float cinv = 1.0f / colsum[b * NQ + j0 + jl];
  int wd = (w >> 1) * 32, wj = (w & 1) * 32;
  f32x4 acc[2][2] = {};

  for (int ic = icb; ic < icb + NC / K4SPLIT; ic += 64) {
    __syncthreads();
    // --- stage Cs (f32 -> bf16)
    {
      const float* src = Cb + (size_t)(d0 + crow) * NC + ic + cq * 16;
      float4 v0 = *(const float4*)(src);
      float4 v1 = *(const float4*)(src + 4);
      float4 v2 = *(const float4*)(src + 8);
      float4 v3 = *(const float4*)(src + 12);
      u16x8 o0, o1;
      o0[0] = f2bf(v0.x); o0[1] = f2bf(v0.y); o0[2] = f2bf(v0.z); o0[3] = f2bf(v0.w);
      o0[4] = f2bf(v1.x); o0[5] = f2bf(v1.y); o0[6] = f2bf(v1.z); o0[7] = f2bf(v1.w);
      o1[0] = f2bf(v2.x); o1[1] = f2bf(v2.y); o1[2] = f2bf(v2.z); o1[3] = f2bf(v2.w);
      o1[4] = f2bf(v3.x); o1[5] = f2bf(v3.y); o1[6] = f2bf(v3.z); o1[7] = f2bf(v3.w);
      int s0 = (cq * 2 + 0) ^ (crow & 7), s1 = (cq * 2 + 1) ^ (crow & 7);
      *(u16x8*)&Cs[crow * 64 + s0 * 8] = o0;
      *(u16x8*)&Cs[crow * 64 + s1 * 8] = o1;
    }
    // --- stage Pt
    {
      float pv[16];
      #pragma unroll
      for (int e = 0; e < 16; ++e) {
        int i = ic + ib * 16 + e;
        float cv = cm[i];
        float sv = Sb[(size_t)i * NQ + j0 + jl];
        float se = sv * cv + NEGV * (1.f - cv);
        pv[e] = __expf(se - cmax) * cinv;
      }
      u16x8 o0, o1;
      #pragma unroll
      for (int e = 0; e < 8; ++e) { o0[e] = f2bf(pv[e]); o1[e] = f2bf(pv[8 + e]); }
      int s0 = (ib * 2 + 0) ^ (jl & 7), s1 = (ib * 2 + 1) ^ (jl & 7);
      *(u16x8*)&Pt[jl * 64 + s0 * 8] = o0;
      *(u16x8*)&Pt[jl * 64 + s1 * 8] = o1;
    }
    __syncthreads();
    // --- MFMA: 2 K-steps of 32
    #pragma unroll
    for (int ks = 0; ks < 2; ++ks) {
      bf16x8 aC[2], bP[2];
      #pragma unroll
      for (int mi = 0; mi < 2; ++mi) {
        int row = wd + mi * 16 + lr;
        aC[mi] = *(const bf16x8*)&Cs[row * 64 + (((ks * 4 + h) ^ (lr & 7)) * 8)];
      }
      #pragma unroll
      for (int nf = 0; nf < 2; ++nf) {
        int row = wj + nf * 16 + lr;
        bP[nf] = *(const bf16x8*)&Pt[row * 64 + (((ks * 4 + h) ^ (lr & 7)) * 8)];
      }
      #pragma unroll
      for (int mi = 0; mi < 2; ++mi)
        #pragma unroll
        for (int nf = 0; nf < 2; ++nf)
          acc[mi][nf] = __builtin_amdgcn_mfma_f32_16x16x32_bf16(aC[mi], bP[nf], acc[mi][nf], 0, 0, 0);
    }
  }
  // --- epilogue: f32 partial
  float* pout = partial + ((size_t)(split * NB + b) * ND) * NQ;
  #pragma unroll
  for (int mi = 0; mi < 2; ++mi)
    #pragma unroll
    for (int nf = 0; nf < 2; ++nf)
      #pragma unroll
      for (int r = 0; r < 4; ++r) {
        int d = d0 + wd + mi * 16 + h * 4 + r;
        int j = j0 + wj + nf * 16 + lr;
        pout[(size_t)d * NQ + j] = acc[mi][nf][r];
      }
}

// ---------------- K4c: combine split-K partials -> bf16 innerT
__global__ __launch_bounds__(256) void k4_combine(const float* __restrict__ partial,
                                                  unsigned short* __restrict__ innerT) {
  int idx = blockIdx.x * 256 + threadIdx.x;   // over NB*ND*NQ/4
  const size_t n = (size_t)NB * ND * NQ / 4;
  const float4* p = (const float4*)partial;
  float4 a = p[idx], b4 = p[n + idx], c4 = p[2 * n + idx], d4 = p[3 * n + idx];
  u16x4 o;
  o[0] = f2bf(a.x + b4.x + c4.x + d4.x);
  o[1] = f2bf(a.y + b4.y + c4.y + d4.y);
  o[2] = f2bf(a.z + b4.z + c4.z + d4.z);
  o[3] = f2bf(a.w + b4.w + c4.w + d4.w);
  ((u16x4*)innerT)[idx] = o;
}

// ---------------- K5 (MFMA): A[i][d] = P@Q^T, Bm[i][d] = P@inner; write concat x (bf16)
__global__ __launch_bounds__(256) void k5_mfma(const float* __restrict__ S, const float* __restrict__ C,
                                               const float* __restrict__ Q,
                                               const unsigned short* __restrict__ innerT,
                                               const float* __restrict__ q_mask,
                                               const float* __restrict__ rowmax, const float* __restrict__ rowsum,
                                               unsigned short* __restrict__ xB) {
  extern __shared__ char sm[];
  unsigned short* Pl = (unsigned short*)sm;            // [32][64] bf16
  unsigned short* Qb = (unsigned short*)(sm + 4096);   // [128][64] bf16
  unsigned short* Ib = (unsigned short*)(sm + 20480);  // [128][64] bf16
  float* As = (float*)sm;                              // [32][133] f32 (aliases, post-compute)
  float* Bs = (float*)(sm + 17024);                    // [32][133] f32
  int b = blockIdx.y, i0 = blockIdx.x * 32;
  int t = threadIdx.x, w = t >> 6, l = t & 63;
  const float* Sb = S + ((size_t)b * NC + i0) * NQ;
  const float* Qg = Q + (size_t)b * ND * NQ;
  const unsigned short* Ig = innerT + (size_t)b * ND * NQ;
  const float* qm = q_mask + b * NQ;

  f32x4 accA[2][2] = {};
  f32x4 accB[2][2] = {};

  int pi = t >> 3, psj = t & 7;
  int qd = t >> 1, qh = t & 1;
  float rmax = rowmax[b * NC + i0 + pi];
  float rinv = 1.0f / rowsum[b * NC + i0 + pi];
  int h = l >> 4, lr = l & 15;

  for (int jc = 0; jc < 4; ++jc) {
    int j0 = jc * 64;
    __syncthreads();
    {
      const float* srow = Sb + (size_t)pi * NQ + j0 + psj * 8;
      float4 s0 = *(const float4*)srow;
      float4 s1 = *(const float4*)(srow + 4);
      float sv[8] = {s0.x, s0.y, s0.z, s0.w, s1.x, s1.y, s1.z, s1.w};
      u16x8 ov;
      #pragma unroll
      for (int e = 0; e < 8; ++e) {
        float qv = qm[j0 + psj * 8 + e];
        float se = sv[e] * qv + NEGV * (1.f - qv);
        ov[e] = f2bf(__expf(se - rmax) * rinv);
      }
      *(u16x8*)&Pl[pi * 64 + (psj ^ (pi & 7)) * 8] = ov;
    }
    {
      const float* qrow = Qg + (size_t)qd * NQ + j0 + qh * 32;
      #pragma unroll
      for (int s = 0; s < 4; ++s) {
        float4 v0 = *(const float4*)(qrow + s * 8);
        float4 v1 = *(const float4*)(qrow + s * 8 + 4);
        u16x8 ov;
        ov[0] = f2bf(v0.x); ov[1] = f2bf(v0.y); ov[2] = f2bf(v0.z); ov[3] = f2bf(v0.w);
        ov[4] = f2bf(v1.x); ov[5] = f2bf(v1.y); ov[6] = f2bf(v1.z); ov[7] = f2bf(v1.w);
        int slot = (qh * 4 + s) ^ (qd & 7);
        *(u16x8*)&Qb[qd * 64 + slot * 8] = ov;
      }
    }
    {
      const unsigned short* irow = Ig + (size_t)qd * NQ + j0 + qh * 32;
      #pragma unroll
      for (int s = 0; s < 4; ++s) {
        u16x8 v = *(const u16x8*)(irow + s * 8);
        int slot = (qh * 4 + s) ^ (qd & 7);
        *(u16x8*)&Ib[qd * 64 + slot * 8] = v;
      }
    }
    __syncthreads();
    #pragma unroll
    for (int ks = 0; ks < 2; ++ks) {
      bf16x8 aP[2], bQ[2], bI[2];
      #pragma unroll
      for (int mi = 0; mi < 2; ++mi) {
        int i = mi * 16 + lr;
        int slot = (ks * 4 + h) ^ (i & 7);
        aP[mi] = *(const bf16x8*)&Pl[i * 64 + slot * 8];
      }
      #pragma unroll
      for (int nd = 0; nd < 2; ++nd) {
        int d = w * 32 + nd * 16 + lr;
        int slot = (ks * 4 + h) ^ (d & 7);
        bQ[nd] = *(const bf16x8*)&Qb[d * 64 + slot * 8];
        bI[nd] = *(const bf16x8*)&Ib[d * 64 + slot * 8];
      }
      #pragma unroll
      for (int mi = 0; mi < 2; ++mi)
        #pragma unroll
        for (int nd = 0; nd < 2; ++nd) {
          accA[mi][nd] = __builtin_amdgcn_mfma_f32_16x16x32_bf16(aP[mi], bQ[nd], accA[mi][nd], 0, 0, 0);
          accB[mi][nd] = __builtin_amdgcn_mfma_f32_16x16x32_bf16(aP[mi], bI[nd], accB[mi][nd], 0, 0, 0);
        }
    }
  }
  __syncthreads();
  #pragma unroll
  for (int mi = 0; mi < 2; ++mi)
    #pragma unroll
    for (int nd = 0; nd < 2; ++nd) {
      int d = w * 32 + nd * 16 + lr;
      #pragma unroll
      for (int r = 0; r < 4; ++r) {
        int i = mi * 16 + h * 4 + r;
        As[i * 133 + d] = accA[mi][nd][r];
        Bs[i * 133 + d] = accB[mi][nd][r];
      }
    }
  __syncthreads();
  {
    int i4 = (t & 7) * 4, db = t >> 3;
    const float* Cb = C + (size_t)b * ND * NC;
    unsigned short* xb = xB + (size_t)b * 4 * ND * NC;
    #pragma unroll
    for (int p = 0; p < 4; ++p) {
      int d = db + p * 32;
      float4 c4 = *(const float4*)&Cb[(size_t)d * NC + i0 + i4];
      float4 a4, b4;
      a4.x = As[(i4 + 0) * 133 + d]; a4.y = As[(i4 + 1) * 133 + d];
      a4.z = As[(i4 + 2) * 133 + d]; a4.w = As[(i4 + 3) * 133 + d];
      b4.x = Bs[(i4 + 0) * 133 + d]; b4.y = Bs[(i4 + 1) * 133 + d];
      b4.z = Bs[(i4 + 2) * 133 + d]; b4.w = Bs[(i4 + 3) * 133 + d];
      u16x4 o0, o1, o2, o3;
      o0[0] = f2bf(c4.x); o0[1] = f2bf(c4.y); o0[2] = f2bf(c4.z); o0[3] = f2bf(c4.w);
      o1[0] = f2bf(a4.x); o1[1] = f2bf(a4.y); o1[2] = f2bf(a4.z); o1[3] = f2bf(a4.w);
      o2[0] = f2bf(c4.x * a4.x); o2[1] = f2bf(c4.y * a4.y); o2[2] = f2bf(c4.z * a4.z); o2[3] = f2bf(c4.w * a4.w);
      o3[0] = f2bf(c4.x * b4.x); o3[1] = f2bf(c4.y * b4.y); o3[2] = f2bf(c4.z * b4.z); o3[3] = f2bf(c4.w * b4.w);
      *(u16x4*)&xb[(size_t)(0 * ND + d) * NC + i0 + i4] = o0;
      *(u16x4*)&xb[(size_t)(1 * ND + d) * NC + i0 + i4] = o1;
      *(u16x4*)&xb[(size_t)(2 * ND + d) * NC + i0 + i4] = o2;
      *(u16x4*)&xb[(size_t)(3 * ND + d) * NC + i0 + i4] = o3;
    }
  }
}

// ---------------- K6 (MFMA): depthwise(k=5,pad2) + pointwise GEMM
__global__ __launch_bounds__(256) void k6_mfma(const unsigned short* __restrict__ x,
                                               const float* __restrict__ dwW, const float* __restrict__ dwB,
                                               const unsigned short* __restrict__ pwB16,
                                               const float* __restrict__ pwB, float* __restrict__ out) {
  extern __shared__ char sm6[];
  unsigned short* xs = (unsigned short*)sm6;            // [64][56]
  unsigned short* x1s = (unsigned short*)(sm6 + 7168);  // [32][72]
  unsigned short* pws = (unsigned short*)(sm6 + 11776); // [128][72]
  int b = blockIdx.y, l0 = blockIdx.x * 32;
  int t = threadIdx.x, w = t >> 6, l = t & 63, h = l >> 4, lr = l & 15;
  const unsigned short* xb = x + (size_t)b * 4 * ND * NC;
  f32x4 acc[2][2] = {};
  int cgw = t & 63, lb = w * 8;

  for (int ch = 0; ch < 8; ++ch) {
    int cg0 = ch * 64;
    __syncthreads();
    #pragma unroll
    for (int k = 0; k < 2; ++k) {
      int id2 = t + k * 256;
      if (id2 < 384) {
        int row = id2 / 6, seg = id2 % 6;
        int gl = l0 - 8 + seg * 8;
        u16x8 v = {};
        if ((unsigned)gl <= 1016u)
          v = *(const u16x8*)(xb + (size_t)(cg0 + row) * NC + gl);
        *(u16x8*)&xs[row * 56 + seg * 8] = v;
      }
    }
    #pragma unroll
    for (int k = 0; k < 4; ++k) {
      int id2 = t + k * 256;
      int o = id2 >> 3, s8 = id2 & 7;
      *(u16x8*)&pws[o * 72 + s8 * 8] = *(const u16x8*)(pwB16 + (size_t)o * 512 + cg0 + s8 * 8);
    }
    __syncthreads();
    {
      int gch = cg0 + cgw;
      float bias = dwB[gch];
      float dwv[5];
      #pragma unroll
      for (int tp = 0; tp < 5; ++tp) dwv[tp] = dwW[gch * 5 + tp];
      float f[24];
      #pragma unroll
      for (int s = 0; s < 3; ++s) {
        u16x8 v = *(const u16x8*)&xs[cgw * 56 + lb + s * 8];
        #pragma unroll
        for (int e = 0; e < 8; ++e) f[s * 8 + e] = bf2f(v[e]);
      }
      #pragma unroll
      for (int e = 0; e < 8; ++e) {
        float a = bias;
        #pragma unroll
        for (int tp = 0; tp < 5; ++tp)
          a = fmaf(f[e + 6 + tp], dwv[tp], a);
        x1s[(lb + e) * 72 + cgw] = f2bf(a);
      }
    }
    __syncthreads();
    #pragma unroll
    for (int ks = 0; ks < 2; ++ks) {
      bf16x8 aW[2], bX[2];
      #pragma unroll
      for (int mi = 0; mi < 2; ++mi) {
        int o = w * 32 + mi * 16 + lr;
        aW[mi] = *(const bf16x8*)&pws[o * 72 + ks * 32 + h * 8];
      }
      #pragma unroll
      for (int nf = 0; nf < 2; ++nf) {
        int ll = nf * 16 + lr;
        bX[nf] = *(const bf16x8*)&x1s[ll * 72 + ks * 32 + h * 8];
      }
      #pragma unroll
      for (int mi = 0; mi < 2; ++mi)
        #pragma unroll
        for (int nf = 0; nf < 2; ++nf)
          acc[mi][nf] = __builtin_amdgcn_mfma_f32_16x16x32_bf16(aW[mi], bX[nf], acc[mi][nf], 0, 0, 0);
    }
  }
  #pragma unroll
  for (int mi = 0; mi < 2; ++mi) {
    #pragma unroll
    for (int r = 0; r < 4; ++r) {
      int o = w * 32 + mi * 16 + h * 4 + r;
      float bv = pwB[o];
      #pragma unroll
      for (int nf = 0; nf < 2; ++nf)
        out[((size_t)b * ND + o) * NC + l0 + nf * 16 + lr] = acc[mi][nf][r] + bv;
    }
  }
}

extern "C" void kernel_launch(void* const* d_in, const int* in_sizes, int n_in,
                              void* d_out, int out_size, void* d_ws, size_t ws_size,
                              hipStream_t stream) {
  const float* C = (const float*)d_in[0];
  const float* Q = (const float*)d_in[1];
  const float* c_mask = (const float*)d_in[2];
  const float* q_mask = (const float*)d_in[3];
  const float* W0 = (const float*)d_in[4];
  const float* dwW = (const float*)d_in[5];
  const float* dwB = (const float*)d_in[6];
  const float* pwW = (const float*)d_in[7];
  const float* pwB = (const float*)d_in[8];
  float* out = (float*)d_out;
  float* ws = (float*)d_ws;

  float* S = ws;                                   // 32*1024*256 f32
  float* rowmax = S + (size_t)NB * NC * NQ;
  float* rowsum = rowmax + NB * NC;
  float* colmax = rowsum + NB * NC;
  float* colsum = colmax + NB * NQ;
  float* cb = colsum + NB * NQ;
  float* qb = cb + NB * NC;
  unsigned short* innerT = (unsigned short*)(qb + NB * NQ);   // 32*128*256 bf16
  unsigned short* xB = innerT + (size_t)NB * ND * NQ;         // 32*512*1024 bf16
  unsigned short* pwB16 = xB + (size_t)NB * 4 * ND * NC;      // 128*512 bf16
  float* partial = (float*)(pwB16 + ND * 512);                // 4*32*128*256 f32 (16 MB)

  k_pwcvt<<<dim3(32), 256, 0, stream>>>(pwW, pwB16);
  k0_bias<<<dim3((NB * (NC + NQ) + 255) / 256), 256, 0, stream>>>(C, Q, W0, cb, qb);
  k1_s<<<dim3(64, NB), 256, 2 * ND * 64 * sizeof(float), stream>>>(C, Q, W0, cb, qb, S);
  k2_rowstat<<<dim3(NB * NC / 4), 256, 0, stream>>>(S, q_mask, rowmax, rowsum);
  k3_colstat<<<dim3(NQ / 16, NB), 256, 0, stream>>>(S, c_mask, colmax, colsum);
  k4_mfma<<<dim3(8 * K4SPLIT, NB), 256, 0, stream>>>(S, C, c_mask, colmax, colsum, partial);
  k4_combine<<<dim3(NB * ND * NQ / 4 / 256), 256, 0, stream>>>(partial, innerT);
  k5_mfma<<<dim3(NC / 32, NB), 256, 36864, stream>>>(S, C, Q, innerT, q_mask, rowmax, rowsum, xB);
  k6_mfma<<<dim3(NC / 32, NB), 256, 30208, stream>>>(xB, dwW, dwB, pwB16, pwB, out);
}

// Round 7
// 176.781 us; speedup vs baseline: 3.9219x; 1.0332x over previous
//
#include <hip/hip_runtime.h>
#include <math.h>

#define NB 32
#define ND 128
#define NC 1024
#define NQ 256
#define NEGV (-1e30f)
#define K4SPLIT 4

typedef __attribute__((ext_vector_type(8))) __bf16 bf16x8;
typedef __attribute__((ext_vector_type(4))) float f32x4;
typedef __attribute__((ext_vector_type(8))) unsigned short u16x8;
typedef __attribute__((ext_vector_type(4))) unsigned short u16x4;

__device__ inline unsigned short f2bf(float f) {
  unsigned u = __builtin_bit_cast(unsigned, f);
  u += 0x7FFFu + ((u >> 16) & 1u);
  return (unsigned short)(u >> 16);
}
__device__ inline float bf2f(unsigned short u) {
  return __builtin_bit_cast(float, (unsigned)u << 16);
}

// ---------------- K0: bias vectors
__global__ __launch_bounds__(256) void k0_bias(const float* __restrict__ C, const float* __restrict__ Q,
                                               const float* __restrict__ W0,
                                               float* __restrict__ cb, float* __restrict__ qb) {
  int idx = blockIdx.x * 256 + threadIdx.x;
  if (idx < NB * NC) {
    int b = idx >> 10, i = idx & (NC - 1);
    const float* base = C + ((size_t)b * ND) * NC + i;
    float s = 0.f;
    #pragma unroll 8
    for (int k = 0; k < ND; ++k) s += base[(size_t)k * NC] * W0[k];
    cb[idx] = s;
  } else {
    int r = idx - NB * NC;
    if (r < NB * NQ) {
      int b = r >> 8, j = r & (NQ - 1);
      const float* base = Q + ((size_t)b * ND) * NQ + j;
      float s = 0.f;
      #pragma unroll 8
      for (int k = 0; k < ND; ++k) s += base[(size_t)k * NQ] * W0[ND + k];
      qb[r] = s;
    }
  }
}

// ---------------- K0b: pwW f32 -> bf16
__global__ __launch_bounds__(256) void k_pwcvt(const float* __restrict__ pwW, unsigned short* __restrict__ pwB16) {
  int idx = blockIdx.x * 256 + threadIdx.x;   // 0..8191
  const float4* src = (const float4*)pwW;
  float4 v0 = src[idx * 2], v1 = src[idx * 2 + 1];
  u16x8 o;
  o[0] = f2bf(v0.x); o[1] = f2bf(v0.y); o[2] = f2bf(v0.z); o[3] = f2bf(v0.w);
  o[4] = f2bf(v1.x); o[5] = f2bf(v1.y); o[6] = f2bf(v1.z); o[7] = f2bf(v1.w);
  ((u16x8*)pwB16)[idx] = o;
}

// ---------------- K0c: Q f32 -> bf16 pre-swizzled [b][d][jc][slot][e], slot s holds group s^(d&7)
__global__ __launch_bounds__(256) void k_qcvt(const float* __restrict__ Q, unsigned short* __restrict__ qSwz) {
  int t = threadIdx.x;
  int rowg = blockIdx.x * 64 + (t >> 2);   // b*128+d
  int d = rowg & 127;
  int jq = t & 3;
  const float* src = Q + (size_t)rowg * NQ + jq * 64;
  unsigned short* dst = qSwz + (size_t)rowg * NQ + jq * 64;
  #pragma unroll
  for (int g = 0; g < 8; ++g) {
    float4 v0 = ((const float4*)src)[g * 2];
    float4 v1 = ((const float4*)src)[g * 2 + 1];
    u16x8 o;
    o[0] = f2bf(v0.x); o[1] = f2bf(v0.y); o[2] = f2bf(v0.z); o[3] = f2bf(v0.w);
    o[4] = f2bf(v1.x); o[5] = f2bf(v1.y); o[6] = f2bf(v1.z); o[7] = f2bf(v1.w);
    *(u16x8*)&dst[(g ^ (d & 7)) * 8] = o;
  }
}

// ---------------- K1: S[b,i,j]
__global__ __launch_bounds__(256) void k1_s(const float* __restrict__ C, const float* __restrict__ Q,
                                            const float* __restrict__ W0,
                                            const float* __restrict__ cb, const float* __restrict__ qb,
                                            float* __restrict__ S) {
  extern __shared__ float sm1[];
  float* Cs = sm1;             // [128][64]
  float* Qs = sm1 + ND * 64;   // [128][64]
  int b = blockIdx.y;
  int i0 = (blockIdx.x & 15) * 64;
  int j0 = (blockIdx.x >> 4) * 64;
  int t = threadIdx.x;
  const float* Cb = C + (size_t)b * ND * NC;
  const float* Qb = Q + (size_t)b * ND * NQ;
  int f4 = (t & 15) * 4;
  #pragma unroll
  for (int it = 0; it < 8; ++it) {
    int k = (t >> 4) + it * 16;
    float w = W0[2 * ND + k];
    float4 v = *(const float4*)(Cb + (size_t)k * NC + i0 + f4);
    v.x *= w; v.y *= w; v.z *= w; v.w *= w;
    *(float4*)(&Cs[k * 64 + f4]) = v;
    *(float4*)(&Qs[k * 64 + f4]) = *(const float4*)(Qb + (size_t)k * NQ + j0 + f4);
  }
  __syncthreads();
  int tj = t & 15, ti = t >> 4;
  float acc[4][4] = {};
  for (int k = 0; k < ND; ++k) {
    float4 c4 = *(const float4*)(&Cs[k * 64 + ti * 4]);
    float4 q4 = *(const float4*)(&Qs[k * 64 + tj * 4]);
    const float cv[4] = {c4.x, c4.y, c4.z, c4.w};
    const float qv[4] = {q4.x, q4.y, q4.z, q4.w};
    #pragma unroll
    for (int a = 0; a < 4; ++a)
      #pragma unroll
      for (int e = 0; e < 4; ++e)
        acc[a][e] = fmaf(cv[a], qv[e], acc[a][e]);
  }
  float qbv[4];
  #pragma unroll
  for (int e = 0; e < 4; ++e) qbv[e] = qb[b * NQ + j0 + tj * 4 + e];
  #pragma unroll
  for (int a = 0; a < 4; ++a) {
    int i = i0 + ti * 4 + a;
    float cbv = cb[b * NC + i];
    float4 o;
    o.x = acc[a][0] + cbv + qbv[0];
    o.y = acc[a][1] + cbv + qbv[1];
    o.z = acc[a][2] + cbv + qbv[2];
    o.w = acc[a][3] + cbv + qbv[3];
    *(float4*)(S + ((size_t)b * NC + i) * NQ + j0 + tj * 4) = o;
  }
}

// ---------------- K23: fused row stats (complete) + col partial stats (one S read, L2-hot 2nd phase)
__global__ __launch_bounds__(256) void k23_stats(const float* __restrict__ S, const float* __restrict__ q_mask,
                                                 const float* __restrict__ c_mask,
                                                 float* __restrict__ rowmax, float* __restrict__ rowsum,
                                                 float* __restrict__ colPm, float* __restrict__ colPs) {
  int b = blockIdx.y, i0 = blockIdx.x * 64, t = threadIdx.x;
  int li = t >> 2, jq = t & 3;
  const float* srow = S + ((size_t)b * NC + i0 + li) * NQ + jq * 64;
  const float* qm = q_mask + b * NQ + jq * 64;
  float m = -3.0e38f, s = 0.f;
  #pragma unroll
  for (int k = 0; k < 16; ++k) {
    float4 v = ((const float4*)srow)[k];
    float vv[4] = {v.x, v.y, v.z, v.w};
    #pragma unroll
    for (int c = 0; c < 4; ++c) {
      float qv = qm[k * 4 + c];
      float val = vv[c] * qv + NEGV * (1.f - qv);
      float mn = fmaxf(m, val);
      s = s * __expf(m - mn) + __expf(val - mn);
      m = mn;
    }
  }
  #pragma unroll
  for (int off = 1; off < 4; off <<= 1) {
    float mo = __shfl_xor(m, off);
    float so = __shfl_xor(s, off);
    float mn = fmaxf(m, mo);
    s = s * __expf(m - mn) + so * __expf(mo - mn);
    m = mn;
  }
  if (jq == 0) { rowmax[b * NC + i0 + li] = m; rowsum[b * NC + i0 + li] = s; }
  // phase 2: col partials, thread owns column j = t
  const float* Sb = S + (size_t)b * NC * NQ;
  const float* cm = c_mask + b * NC + i0;
  float m2 = -3.0e38f, s2 = 0.f;
  #pragma unroll 8
  for (int ii = 0; ii < 64; ++ii) {
    float cv = cm[ii];
    float v = Sb[(size_t)(i0 + ii) * NQ + t];
    float val = v * cv + NEGV * (1.f - cv);
    float mn = fmaxf(m2, val);
    s2 = s2 * __expf(m2 - mn) + __expf(val - mn);
    m2 = mn;
  }
  colPm[((size_t)blockIdx.x * NB + b) * NQ + t] = m2;
  colPs[((size_t)blockIdx.x * NB + b) * NQ + t] = s2;
}

// ---------------- K3c: combine 16 col partials
__global__ __launch_bounds__(256) void k3c_combine(const float* __restrict__ colPm, const float* __restrict__ colPs,
                                                   float* __restrict__ colmax, float* __restrict__ colsum) {
  int idx = blockIdx.x * 256 + threadIdx.x;   // b*NQ + j
  float m = -3.0e38f, s = 0.f;
  #pragma unroll
  for (int tl = 0; tl < 16; ++tl) {
    float mo = colPm[(size_t)tl * NB * NQ + idx];
    float so = colPs[(size_t)tl * NB * NQ + idx];
    float mn = fmaxf(m, mo);
    s = s * __expf(m - mn) + so * __expf(mo - mn);
    m = mn;
  }
  colmax[idx] = m; colsum[idx] = s;
}

// ---------------- K_pexp: S -> P_bar (row softmax, [b][i][j] swz) + P_bbar^T (col softmax, [b][j][i] swz)
__global__ __launch_bounds__(256) void k_pexp(const float* __restrict__ S, const float* __restrict__ q_mask,
                                              const float* __restrict__ c_mask,
                                              const float* __restrict__ rowmax, const float* __restrict__ rowsum,
                                              const float* __restrict__ colmax, const float* __restrict__ colsum,
                                              unsigned short* __restrict__ pSwz, unsigned short* __restrict__ pSwzC) {
  __shared__ unsigned short T[64 * 256];
  __shared__ float cmxL[256], cinvL[256], qmL[256];
  int b = blockIdx.y, i0 = blockIdx.x * 64, t = threadIdx.x;
  cmxL[t] = colmax[b * NQ + t];
  cinvL[t] = 1.0f / colsum[b * NQ + t];
  qmL[t] = q_mask[b * NQ + t];
  __syncthreads();
  int li = t >> 2, jq = t & 3;
  int i = i0 + li;
  float rmax = rowmax[b * NC + i];
  float rinv = 1.0f / rowsum[b * NC + i];
  float cmi = c_mask[b * NC + i];
  float cbias = NEGV * (1.f - cmi);
  const float* srow = S + ((size_t)b * NC + i) * NQ + jq * 64;
  unsigned short* prow = pSwz + ((size_t)b * NC + i) * NQ + jq * 64;
  #pragma unroll
  for (int g = 0; g < 8; ++g) {
    float4 v0 = ((const float4*)srow)[g * 2];
    float4 v1 = ((const float4*)srow)[g * 2 + 1];
    float sv[8] = {v0.x, v0.y, v0.z, v0.w, v1.x, v1.y, v1.z, v1.w};
    u16x8 pr, pc;
    #pragma unroll
    for (int e = 0; e < 8; ++e) {
      int j = jq * 64 + g * 8 + e;
      float qv = qmL[j];
      pr[e] = f2bf(__expf(sv[e] * qv + NEGV * (1.f - qv) - rmax) * rinv);
      pc[e] = f2bf(__expf(sv[e] * cmi + cbias - cmxL[j]) * cinvL[j]);
    }
    int slot = g ^ (li & 7);
    *(u16x8*)&prow[slot * 8] = pr;
    *(u16x8*)&T[li * 256 + jq * 64 + slot * 8] = pc;
  }
  __syncthreads();
  // phase B: out row j, i-chunk i0; out slot s holds i-group s^(j&7)
  int j = t, jq2 = j >> 6, jg = (j >> 3) & 7, je = j & 7;
  unsigned short* orow = pSwzC + ((size_t)b * NQ + j) * NC + i0;
  #pragma unroll
  for (int s8 = 0; s8 < 8; ++s8) {
    int ig = s8 ^ (j & 7);
    u16x8 o;
    #pragma unroll
    for (int e = 0; e < 8; ++e) {
      int ii = ig * 8 + e;                       // ii&7 == e
      o[e] = T[ii * 256 + jq2 * 64 + ((jg ^ e) << 3) + je];
    }
    *(u16x8*)&orow[s8 * 8] = o;
  }
}

// ---------------- K4 (MFMA, split-K): partial[split][b][d][j] = sum_{i in chunk} Pbbar[i,j]*C[b,d,i]
__global__ __launch_bounds__(256) void k4_mfma(const unsigned short* __restrict__ pSwzC, const float* __restrict__ C,
                                               float* __restrict__ partial) {
  __shared__ unsigned short Cs[64 * 64];
  __shared__ unsigned short Pt[64 * 64];
  int b = blockIdx.y;
  int tile = blockIdx.x & 7, split = blockIdx.x >> 3;
  int d0 = (tile & 1) * 64;
  int j0 = (tile >> 1) * 64;
  int icb = split * (NC / K4SPLIT);
  int t = threadIdx.x, w = t >> 6, l = t & 63, h = l >> 4, lr = l & 15;
  const float* Cb = C + (size_t)b * ND * NC;
  int crow = t >> 2, cq = t & 3;       // Cs staging: d = d0+crow, i = ic+cq*16+e
  int prow_ = t >> 2, ppart = t & 3;   // Pt staging: j = j0+prow_, 16 shorts each
  int wd = (w >> 1) * 32, wj = (w & 1) * 32;
  f32x4 acc[2][2] = {};

  for (int ic = icb; ic < icb + NC / K4SPLIT; ic += 64) {
    __syncthreads();
    // --- stage Cs (f32 -> bf16, slot-XOR)
    {
      const float* src = Cb + (size_t)(d0 + crow) * NC + ic + cq * 16;
      float4 v0 = *(const float4*)(src);
      float4 v1 = *(const float4*)(src + 4);
      float4 v2 = *(const float4*)(src + 8);
      float4 v3 = *(const float4*)(src + 12);
      u16x8 o0, o1;
      o0[0] = f2bf(v0.x); o0[1] = f2bf(v0.y); o0[2] = f2bf(v0.z); o0[3] = f2bf(v0.w);
      o0[4] = f2bf(v1.x); o0[5] = f2bf(v1.y); o0[6] = f2bf(v1.z); o0[7] = f2bf(v1.w);
      o1[0] = f2bf(v2.x); o1[1] = f2bf(v2.y); o1[2] = f2bf(v2.z); o1[3] = f2bf(v2.w);
      o1[4] = f2bf(v3.x); o1[5] = f2bf(v3.y); o1[6] = f2bf(v3.z); o1[7] = f2bf(v3.w);
      int s0 = (cq * 2 + 0) ^ (crow & 7), s1 = (cq * 2 + 1) ^ (crow & 7);
      *(u16x8*)&Cs[crow * 64 + s0 * 8] = o0;
      *(u16x8*)&Cs[crow * 64 + s1 * 8] = o1;
    }
    // --- stage Pt: pure copy (swizzle baked into pSwzC)
    {
      const unsigned short* psrc = pSwzC + ((size_t)b * NQ + j0 + prow_) * NC + ic + ppart * 16;
      *(u16x8*)&Pt[prow_ * 64 + ppart * 16] = *(const u16x8*)psrc;
      *(u16x8*)&Pt[prow_ * 64 + ppart * 16 + 8] = *(const u16x8*)(psrc + 8);
    }
    __syncthreads();
    #pragma unroll
    for (int ks = 0; ks < 2; ++ks) {
      bf16x8 aC[2], bP[2];
      #pragma unroll
      for (int mi = 0; mi < 2; ++mi) {
        int row = wd + mi * 16 + lr;
        aC[mi] = *(const bf16x8*)&Cs[row * 64 + (((ks * 4 + h) ^ (lr & 7)) * 8)];
      }
      #pragma unroll
      for (int nf = 0; nf < 2; ++nf) {
        int row = wj + nf * 16 + lr;
        bP[nf] = *(const bf16x8*)&Pt[row * 64 + (((ks * 4 + h) ^ (lr & 7)) * 8)];
      }
      #pragma unroll
      for (int mi = 0; mi < 2; ++mi)
        #pragma unroll
        for (int nf = 0; nf < 2; ++nf)
          acc[mi][nf] = __builtin_amdgcn_mfma_f32_16x16x32_bf16(aC[mi], bP[nf], acc[mi][nf], 0, 0, 0);
    }
  }
  float* pout = partial + ((size_t)(split * NB + b) * ND) * NQ;
  #pragma unroll
  for (int mi = 0; mi < 2; ++mi)
    #pragma unroll
    for (int nf = 0; nf < 2; ++nf)
      #pragma unroll
      for (int r = 0; r < 4; ++r) {
        int d = d0 + wd + mi * 16 + h * 4 + r;
        int j = j0 + wj + nf * 16 + lr;
        pout[(size_t)d * NQ + j] = acc[mi][nf][r];
      }
}

// ---------------- K4c: combine split-K partials -> bf16 iSwz (pre-swizzled)
__global__ __launch_bounds__(256) void k4_combine(const float* __restrict__ partial,
                                                  unsigned short* __restrict__ iSwz) {
  int idx = blockIdx.x * 256 + threadIdx.x;   // over NB*ND*NQ/4
  const size_t n = (size_t)NB * ND * NQ / 4;
  const float4* p = (const float4*)partial;
  float4 a = p[idx], b4 = p[n + idx], c4 = p[2 * n + idx], d4 = p[3 * n + idx];
  u16x4 o;
  o[0] = f2bf(a.x + b4.x + c4.x + d4.x);
  o[1] = f2bf(a.y + b4.y + c4.y + d4.y);
  o[2] = f2bf(a.z + b4.z + c4.z + d4.z);
  o[3] = f2bf(a.w + b4.w + c4.w + d4.w);
  int lin = idx * 4;
  int j = lin & 255, dd = (lin >> 8) & 127, bb = lin >> 15;
  int g = (j >> 3) & 7, e0 = j & 7;
  int outoff = ((bb * 128 + dd) << 8) + (j & 192) + ((g ^ (dd & 7)) << 3) + e0;
  *(u16x4*)&iSwz[outoff] = o;
}

// ---------------- K5 (MFMA): A[i][d] = Pbar@Q^T, Bm[i][d] = Pbar@inner; write concat x (bf16)
__global__ __launch_bounds__(256) void k5_mfma(const unsigned short* __restrict__ pSwz, const float* __restrict__ C,
                                               const unsigned short* __restrict__ qSwz,
                                               const unsigned short* __restrict__ iSwz,
                                               unsigned short* __restrict__ xB) {
  extern __shared__ char sm[];
  unsigned short* Pl = (unsigned short*)sm;            // [32][64] bf16
  unsigned short* Qb = (unsigned short*)(sm + 4096);   // [128][64] bf16
  unsigned short* Ib = (unsigned short*)(sm + 20480);  // [128][64] bf16
  float* As = (float*)sm;                              // [32][133] f32 (aliases, post-compute)
  float* Bs = (float*)(sm + 17024);                    // [32][133] f32
  int b = blockIdx.y, i0 = blockIdx.x * 32;
  int t = threadIdx.x, w = t >> 6, l = t & 63;
  int h = l >> 4, lr = l & 15;
  int pr_ = t >> 3, ps_ = t & 7;

  f32x4 accA[2][2] = {};
  f32x4 accB[2][2] = {};

  for (int jc = 0; jc < 4; ++jc) {
    int j0 = jc * 64;
    __syncthreads();
    // --- stage Pl (copy, swizzle baked)
    *(u16x8*)&Pl[pr_ * 64 + ps_ * 8] =
        *(const u16x8*)(pSwz + ((size_t)b * NC + i0 + pr_) * NQ + j0 + ps_ * 8);
    // --- stage Qb, Ib (copy)
    #pragma unroll
    for (int k = 0; k < 4; ++k) {
      int u = t + k * 256;
      int d_ = u >> 3, s_ = u & 7;
      *(u16x8*)&Qb[d_ * 64 + s_ * 8] = *(const u16x8*)(qSwz + ((size_t)b * ND + d_) * NQ + j0 + s_ * 8);
      *(u16x8*)&Ib[d_ * 64 + s_ * 8] = *(const u16x8*)(iSwz + ((size_t)b * ND + d_) * NQ + j0 + s_ * 8);
    }
    __syncthreads();
    #pragma unroll
    for (int ks = 0; ks < 2; ++ks) {
      bf16x8 aP[2], bQ[2], bI[2];
      #pragma unroll
      for (int mi = 0; mi < 2; ++mi) {
        int i = mi * 16 + lr;
        int slot = (ks * 4 + h) ^ (i & 7);
        aP[mi] = *(const bf16x8*)&Pl[i * 64 + slot * 8];
      }
      #pragma unroll
      for (int nd = 0; nd < 2; ++nd) {
        int d = w * 32 + nd * 16 + lr;
        int slot = (ks * 4 + h) ^ (d & 7);
        bQ[nd] = *(const bf16x8*)&Qb[d * 64 + slot * 8];
        bI[nd] = *(const bf16x8*)&Ib[d * 64 + slot * 8];
      }
      #pragma unroll
      for (int mi = 0; mi < 2; ++mi)
        #pragma unroll
        for (int nd = 0; nd < 2; ++nd) {
          accA[mi][nd] = __builtin_amdgcn_mfma_f32_16x16x32_bf16(aP[mi], bQ[nd], accA[mi][nd], 0, 0, 0);
          accB[mi][nd] = __builtin_amdgcn_mfma_f32_16x16x32_bf16(aP[mi], bI[nd], accB[mi][nd], 0, 0, 0);
        }
    }
  }
  __syncthreads();
  #pragma unroll
  for (int mi = 0; mi < 2; ++mi)
    #pragma unroll
    for (int nd = 0; nd < 2; ++nd) {
      int d = w * 32 + nd * 16 + lr;
      #pragma unroll
      for (int r = 0; r < 4; ++r) {
        int i = mi * 16 + h * 4 + r;
        As[i * 133 + d] = accA[mi][nd][r];
        Bs[i * 133 + d] = accB[mi][nd][r];
      }
    }
  __syncthreads();
  {
    int i4 = (t & 7) * 4, db = t >> 3;
    const float* Cb = C + (size_t)b * ND * NC;
    unsigned short* xb = xB + (size_t)b * 4 * ND * NC;
    #pragma unroll
    for (int p = 0; p < 4; ++p) {
      int d = db + p * 32;
      float4 c4 = *(const float4*)&Cb[(size_t)d * NC + i0 + i4];
      float4 a4, b4;
      a4.x = As[(i4 + 0) * 133 + d]; a4.y = As[(i4 + 1) * 133 + d];
      a4.z = As[(i4 + 2) * 133 + d]; a4.w = As[(i4 + 3) * 133 + d];
      b4.x = Bs[(i4 + 0) * 133 + d]; b4.y = Bs[(i4 + 1) * 133 + d];
      b4.z = Bs[(i4 + 2) * 133 + d]; b4.w = Bs[(i4 + 3) * 133 + d];
      u16x4 o0, o1, o2, o3;
      o0[0] = f2bf(c4.x); o0[1] = f2bf(c4.y); o0[2] = f2bf(c4.z); o0[3] = f2bf(c4.w);
      o1[0] = f2bf(a4.x); o1[1] = f2bf(a4.y); o1[2] = f2bf(a4.z); o1[3] = f2bf(a4.w);
      o2[0] = f2bf(c4.x * a4.x); o2[1] = f2bf(c4.y * a4.y); o2[2] = f2bf(c4.z * a4.z); o2[3] = f2bf(c4.w * a4.w);
      o3[0] = f2bf(c4.x * b4.x); o3[1] = f2bf(c4.y * b4.y); o3[2] = f2bf(c4.z * b4.z); o3[3] = f2bf(c4.w * b4.w);
      *(u16x4*)&xb[(size_t)(0 * ND + d) * NC + i0 + i4] = o0;
      *(u16x4*)&xb[(size_t)(1 * ND + d) * NC + i0 + i4] = o1;
      *(u16x4*)&xb[(size_t)(2 * ND + d) * NC + i0 + i4] = o2;
      *(u16x4*)&xb[(size_t)(3 * ND + d) * NC + i0 + i4] = o3;
    }
  }
}

// ---------------- K6 (MFMA): depthwise(k=5,pad2) + pointwise GEMM
__global__ __launch_bounds__(256) void k6_mfma(const unsigned short* __restrict__ x,
                                               const float* __restrict__ dwW, const float* __restrict__ dwB,
                                               const unsigned short* __restrict__ pwB16,
                                               const float* __restrict__ pwB, float* __restrict__ out) {
  extern __shared__ char sm6[];
  unsigned short* xs = (unsigned short*)sm6;            // [64][56]
  unsigned short* x1s = (unsigned short*)(sm6 + 7168);  // [32][72]
  unsigned short* pws = (unsigned short*)(sm6 + 11776); // [128][72]
  int b = blockIdx.y, l0 = blockIdx.x * 32;
  int t = threadIdx.x, w = t >> 6, l = t & 63, h = l >> 4, lr = l & 15;
  const unsigned short* xb = x + (size_t)b * 4 * ND * NC;
  f32x4 acc[2][2] = {};
  int cgw = t & 63, lb = w * 8;

  for (int ch = 0; ch < 8; ++ch) {
    int cg0 = ch * 64;
    __syncthreads();
    #pragma unroll
    for (int k = 0; k < 2; ++k) {
      int id2 = t + k * 256;
      if (id2 < 384) {
        int row = id2 / 6, seg = id2 % 6;
        int gl = l0 - 8 + seg * 8;
        u16x8 v = {};
        if ((unsigned)gl <= 1016u)
          v = *(const u16x8*)(xb + (size_t)(cg0 + row) * NC + gl);
        *(u16x8*)&xs[row * 56 + seg * 8] = v;
      }
    }
    #pragma unroll
    for (int k = 0; k < 4; ++k) {
      int id2 = t + k * 256;
      int o = id2 >> 3, s8 = id2 & 7;
      *(u16x8*)&pws[o * 72 + s8 * 8] = *(const u16x8*)(pwB16 + (size_t)o * 512 + cg0 + s8 * 8);
    }
    __syncthreads();
    {
      int gch = cg0 + cgw;
      float bias = dwB[gch];
      float dwv[5];
      #pragma unroll
      for (int tp = 0; tp < 5; ++tp) dwv[tp] = dwW[gch * 5 + tp];
      float f[24];
      #pragma unroll
      for (int s = 0; s < 3; ++s) {
        u16x8 v = *(const u16x8*)&xs[cgw * 56 + lb + s * 8];
        #pragma unroll
        for (int e = 0; e < 8; ++e) f[s * 8 + e] = bf2f(v[e]);
      }
      #pragma unroll
      for (int e = 0; e < 8; ++e) {
        float a = bias;
        #pragma unroll
        for (int tp = 0; tp < 5; ++tp)
          a = fmaf(f[e + 6 + tp], dwv[tp], a);
        x1s[(lb + e) * 72 + cgw] = f2bf(a);
      }
    }
    __syncthreads();
    #pragma unroll
    for (int ks = 0; ks < 2; ++ks) {
      bf16x8 aW[2], bX[2];
      #pragma unroll
      for (int mi = 0; mi < 2; ++mi) {
        int o = w * 32 + mi * 16 + lr;
        aW[mi] = *(const bf16x8*)&pws[o * 72 + ks * 32 + h * 8];
      }
      #pragma unroll
      for (int nf = 0; nf < 2; ++nf) {
        int ll = nf * 16 + lr;
        bX[nf] = *(const bf16x8*)&x1s[ll * 72 + ks * 32 + h * 8];
      }
      #pragma unroll
      for (int mi = 0; mi < 2; ++mi)
        #pragma unroll
        for (int nf = 0; nf < 2; ++nf)
          acc[mi][nf] = __builtin_amdgcn_mfma_f32_16x16x32_bf16(aW[mi], bX[nf], acc[mi][nf], 0, 0, 0);
    }
  }
  #pragma unroll
  for (int mi = 0; mi < 2; ++mi) {
    #pragma unroll
    for (int r = 0; r < 4; ++r) {
      int o = w * 32 + mi * 16 + h * 4 + r;
      float bv = pwB[o];
      #pragma unroll
      for (int nf = 0; nf < 2; ++nf)
        out[((size_t)b * ND + o) * NC + l0 + nf * 16 + lr] = acc[mi][nf][r] + bv;
    }
  }
}

extern "C" void kernel_launch(void* const* d_in, const int* in_sizes, int n_in,
                              void* d_out, int out_size, void* d_ws, size_t ws_size,
                              hipStream_t stream) {
  const float* C = (const float*)d_in[0];
  const float* Q = (const float*)d_in[1];
  const float* c_mask = (const float*)d_in[2];
  const float* q_mask = (const float*)d_in[3];
  const float* W0 = (const float*)d_in[4];
  const float* dwW = (const float*)d_in[5];
  const float* dwB = (const float*)d_in[6];
  const float* pwW = (const float*)d_in[7];
  const float* pwB = (const float*)d_in[8];
  float* out = (float*)d_out;
  float* ws = (float*)d_ws;

  float* S = ws;                                   // 32*1024*256 f32 (aliased by partial after k_pexp)
  float* rowmax = S + (size_t)NB * NC * NQ;
  float* rowsum = rowmax + NB * NC;
  float* colmax = rowsum + NB * NC;
  float* colsum = colmax + NB * NQ;
  float* cb = colsum + NB * NQ;
  float* qb = cb + NB * NC;
  float* colPm = qb + NB * NQ;                     // 16*NB*NQ
  float* colPs = colPm + 16 * NB * NQ;             // 16*NB*NQ
  unsigned short* qSwz = (unsigned short*)(colPs + 16 * NB * NQ);   // NB*ND*NQ bf16
  unsigned short* iSwz = qSwz + (size_t)NB * ND * NQ;               // NB*ND*NQ bf16
  unsigned short* pwB16 = iSwz + (size_t)NB * ND * NQ;              // 128*512 bf16
  unsigned short* pSwz = pwB16 + ND * 512;                          // NB*NC*NQ bf16
  unsigned short* pSwzC = pSwz + (size_t)NB * NC * NQ;              // NB*NQ*NC bf16
  unsigned short* xB = pSwzC;                      // ALIAS: xB overlaps pSwzC (dead after k4) + tail
  float* partial = S;                              // ALIAS: S dead after k_pexp

  k_pwcvt<<<dim3(32), 256, 0, stream>>>(pwW, pwB16);
  k_qcvt<<<dim3(64), 256, 0, stream>>>(Q, qSwz);
  k0_bias<<<dim3((NB * (NC + NQ) + 255) / 256), 256, 0, stream>>>(C, Q, W0, cb, qb);
  k1_s<<<dim3(64, NB), 256, 2 * ND * 64 * sizeof(float), stream>>>(C, Q, W0, cb, qb, S);
  k23_stats<<<dim3(16, NB), 256, 0, stream>>>(S, q_mask, c_mask, rowmax, rowsum, colPm, colPs);
  k3c_combine<<<dim3(NB * NQ / 256), 256, 0, stream>>>(colPm, colPs, colmax, colsum);
  k_pexp<<<dim3(16, NB), 256, 0, stream>>>(S, q_mask, c_mask, rowmax, rowsum, colmax, colsum, pSwz, pSwzC);
  k4_mfma<<<dim3(8 * K4SPLIT, NB), 256, 0, stream>>>(pSwzC, C, partial);
  k4_combine<<<dim3(NB * ND * NQ / 4 / 256), 256, 0, stream>>>(partial, iSwz);
  k5_mfma<<<dim3(NC / 32, NB), 256, 36864, stream>>>(pSwz, C, qSwz, iSwz, xB);
  k6_mfma<<<dim3(NC / 32, NB), 256, 30208, stream>>>(xB, dwW, dwB, pwB16, pwB, out);
}

// Round 8
// 163.876 us; speedup vs baseline: 4.2307x; 1.0788x over previous
//
#include <hip/hip_runtime.h>
#include <math.h>

#define NB 32
#define ND 128
#define NC 1024
#define NQ 256
#define NEGV (-1e30f)
#define K4SPLIT 4

typedef __attribute__((ext_vector_type(8))) __bf16 bf16x8;
typedef __attribute__((ext_vector_type(4))) float f32x4;
typedef __attribute__((ext_vector_type(8))) unsigned short u16x8;
typedef __attribute__((ext_vector_type(4))) unsigned short u16x4;

__device__ inline unsigned short f2bf(float f) {
  unsigned u = __builtin_bit_cast(unsigned, f);
  u += 0x7FFFu + ((u >> 16) & 1u);
  return (unsigned short)(u >> 16);
}
__device__ inline float bf2f(unsigned short u) {
  return __builtin_bit_cast(float, (unsigned)u << 16);
}

// ---------------- K0: bias vectors cb/qb
__global__ __launch_bounds__(256) void k0_bias(const float* __restrict__ C, const float* __restrict__ Q,
                                               const float* __restrict__ W0,
                                               float* __restrict__ cb, float* __restrict__ qb) {
  int idx = blockIdx.x * 256 + threadIdx.x;
  if (idx < NB * NC) {
    int b = idx >> 10, i = idx & (NC - 1);
    const float* base = C + ((size_t)b * ND) * NC + i;
    float s = 0.f;
    #pragma unroll 8
    for (int k = 0; k < ND; ++k) s += base[(size_t)k * NC] * W0[k];
    cb[idx] = s;
  } else {
    int r = idx - NB * NC;
    if (r < NB * NQ) {
      int b = r >> 8, j = r & (NQ - 1);
      const float* base = Q + ((size_t)b * ND) * NQ + j;
      float s = 0.f;
      #pragma unroll 8
      for (int k = 0; k < ND; ++k) s += base[(size_t)k * NQ] * W0[ND + k];
      qb[r] = s;
    }
  }
}

// ---------------- K0b: pwW f32 -> bf16
__global__ __launch_bounds__(256) void k_pwcvt(const float* __restrict__ pwW, unsigned short* __restrict__ pwB16) {
  int idx = blockIdx.x * 256 + threadIdx.x;   // 0..8191
  const float4* src = (const float4*)pwW;
  float4 v0 = src[idx * 2], v1 = src[idx * 2 + 1];
  u16x8 o;
  o[0] = f2bf(v0.x); o[1] = f2bf(v0.y); o[2] = f2bf(v0.z); o[3] = f2bf(v0.w);
  o[4] = f2bf(v1.x); o[5] = f2bf(v1.y); o[6] = f2bf(v1.z); o[7] = f2bf(v1.w);
  ((u16x8*)pwB16)[idx] = o;
}

// ---------------- K0c: Q f32 -> bf16 pre-swizzled [b][d][j-slots] (K=j, for k5)
__global__ __launch_bounds__(256) void k_qcvt(const float* __restrict__ Q, unsigned short* __restrict__ qSwz) {
  int t = threadIdx.x;
  int rowg = blockIdx.x * 64 + (t >> 2);   // b*128+d
  int d = rowg & 127;
  int jq = t & 3;
  const float* src = Q + (size_t)rowg * NQ + jq * 64;
  unsigned short* dst = qSwz + (size_t)rowg * NQ + jq * 64;
  #pragma unroll
  for (int g = 0; g < 8; ++g) {
    float4 v0 = ((const float4*)src)[g * 2];
    float4 v1 = ((const float4*)src)[g * 2 + 1];
    u16x8 o;
    o[0] = f2bf(v0.x); o[1] = f2bf(v0.y); o[2] = f2bf(v0.z); o[3] = f2bf(v0.w);
    o[4] = f2bf(v1.x); o[5] = f2bf(v1.y); o[6] = f2bf(v1.z); o[7] = f2bf(v1.w);
    *(u16x8*)&dst[(g ^ (d & 7)) * 8] = o;
  }
}

// ---------------- K0d: Q^T bf16 swizzled [b][j][d-slots] (K=d, for k1f B-operand)
__global__ __launch_bounds__(256) void k_qtcvt(const float* __restrict__ Q, unsigned short* __restrict__ qT) {
  __shared__ unsigned short T2[128 * 66];
  int b = blockIdx.y, j0 = blockIdx.x * 64, t = threadIdx.x;
  int d = t >> 1, half = t & 1;
  const float* src = Q + ((size_t)b * ND + d) * NQ + j0 + half * 32;
  #pragma unroll
  for (int q = 0; q < 4; ++q) {
    float4 v0 = ((const float4*)src)[q * 2];
    float4 v1 = ((const float4*)src)[q * 2 + 1];
    u16x8 o;
    o[0] = f2bf(v0.x); o[1] = f2bf(v0.y); o[2] = f2bf(v0.z); o[3] = f2bf(v0.w);
    o[4] = f2bf(v1.x); o[5] = f2bf(v1.y); o[6] = f2bf(v1.z); o[7] = f2bf(v1.w);
    *(u16x8*)&T2[d * 66 + half * 32 + q * 8] = o;
  }
  __syncthreads();
  int jj = t >> 2, p = t & 3;
  unsigned short* dst = qT + ((size_t)b * NQ + j0 + jj) * ND;
  #pragma unroll
  for (int q = 0; q < 4; ++q) {
    int g = p * 4 + q;
    u16x8 o;
    #pragma unroll
    for (int e = 0; e < 8; ++e) o[e] = T2[(g * 8 + e) * 66 + jj];
    int sg = (g & 8) | ((g & 7) ^ (jj & 7));
    *(u16x8*)&dst[sg * 8] = o;
  }
}

// ---------------- K0e: (C*w3)^T bf16 swizzled [b][i][k-slots] (K=k, for k1f A-operand)
__global__ __launch_bounds__(256) void k_ccvt(const float* __restrict__ C, const float* __restrict__ W0,
                                              unsigned short* __restrict__ cw3T) {
  __shared__ unsigned short T2[128 * 66];
  int b = blockIdx.y, i0 = blockIdx.x * 64, t = threadIdx.x;
  int k = t >> 1, half = t & 1;
  float wv = W0[2 * ND + k];
  const float* src = C + ((size_t)b * ND + k) * NC + i0 + half * 32;
  #pragma unroll
  for (int q = 0; q < 4; ++q) {
    float4 v0 = ((const float4*)src)[q * 2];
    float4 v1 = ((const float4*)src)[q * 2 + 1];
    u16x8 o;
    o[0] = f2bf(v0.x * wv); o[1] = f2bf(v0.y * wv); o[2] = f2bf(v0.z * wv); o[3] = f2bf(v0.w * wv);
    o[4] = f2bf(v1.x * wv); o[5] = f2bf(v1.y * wv); o[6] = f2bf(v1.z * wv); o[7] = f2bf(v1.w * wv);
    *(u16x8*)&T2[k * 66 + half * 32 + q * 8] = o;
  }
  __syncthreads();
  int ii = t >> 2, p = t & 3;
  unsigned short* dst = cw3T + ((size_t)b * NC + i0 + ii) * ND;
  #pragma unroll
  for (int q = 0; q < 4; ++q) {
    int g = p * 4 + q;
    u16x8 o;
    #pragma unroll
    for (int e = 0; e < 8; ++e) o[e] = T2[(g * 8 + e) * 66 + ii];
    int sg = (g & 8) | ((g & 7) ^ (ii & 7));
    *(u16x8*)&dst[sg * 8] = o;
  }
}

// ---------------- K0f: C bf16 swizzled [b][d][i-slots] (K=i, for k4 A-operand)
__global__ __launch_bounds__(256) void k_ccvt2(const float* __restrict__ C, unsigned short* __restrict__ cSwz) {
  int t = threadIdx.x;
  int rowg = blockIdx.x * 64 + (t >> 2);   // b*128+d
  int d = rowg & 127;
  int iq = t & 3;
  const float* src = C + (size_t)rowg * NC + iq * 256;
  unsigned short* dst = cSwz + (size_t)rowg * NC;
  #pragma unroll
  for (int g2 = 0; g2 < 32; ++g2) {
    int g = iq * 32 + g2;
    float4 v0 = ((const float4*)src)[g2 * 2];
    float4 v1 = ((const float4*)src)[g2 * 2 + 1];
    u16x8 o;
    o[0] = f2bf(v0.x); o[1] = f2bf(v0.y); o[2] = f2bf(v0.z); o[3] = f2bf(v0.w);
    o[4] = f2bf(v1.x); o[5] = f2bf(v1.y); o[6] = f2bf(v1.z); o[7] = f2bf(v1.w);
    int cc = g >> 3, gl = g & 7;
    *(u16x8*)&dst[cc * 64 + ((gl ^ (d & 7)) * 8)] = o;
  }
}

// ---------------- K1f: S via MFMA + row stats + col partials + S(bf16) + pSwz out. Tile 64i x 256j.
__global__ __launch_bounds__(256) void k1f(const unsigned short* __restrict__ cw3T,
                                           const unsigned short* __restrict__ qT,
                                           const float* __restrict__ cb, const float* __restrict__ qb,
                                           const float* __restrict__ q_mask, const float* __restrict__ c_mask,
                                           unsigned short* __restrict__ Sb16, unsigned short* __restrict__ pSwz,
                                           float* __restrict__ colPm, float* __restrict__ colPs) {
  __shared__ unsigned short Pbuf[64 * 256];     // 32 KB
  __shared__ float rmP[64][4], rsP[64][4];
  __shared__ float frm[64], fri[64];
  __shared__ float cbL[64], cmL[64], qbL[256], qmL[256];
  int b = blockIdx.y, i0 = blockIdx.x * 64;
  int t = threadIdx.x, w = t >> 6, l = t & 63, h = l >> 4, lr = l & 15;
  int wj = w * 64;
  if (t < 64) { cbL[t] = cb[b * NC + i0 + t]; cmL[t] = c_mask[b * NC + i0 + t]; }
  qbL[t] = qb[b * NQ + t];
  qmL[t] = q_mask[b * NQ + t];
  const unsigned short* Arow = cw3T + ((size_t)b * NC + i0) * ND;
  const unsigned short* Brow = qT + (size_t)b * NQ * ND;
  f32x4 acc[4][4] = {};
  #pragma unroll
  for (int ks = 0; ks < 4; ++ks) {
    int g = ks * 4 + h;
    int off = ((g & 8) | ((g & 7) ^ (lr & 7))) * 8;
    bf16x8 a[4], bq[4];
    #pragma unroll
    for (int mi = 0; mi < 4; ++mi)
      a[mi] = *(const bf16x8*)&Arow[(size_t)(mi * 16 + lr) * ND + off];
    #pragma unroll
    for (int nf = 0; nf < 4; ++nf)
      bq[nf] = *(const bf16x8*)&Brow[(size_t)(wj + nf * 16 + lr) * ND + off];
    #pragma unroll
    for (int mi = 0; mi < 4; ++mi)
      #pragma unroll
      for (int nf = 0; nf < 4; ++nf)
        acc[mi][nf] = __builtin_amdgcn_mfma_f32_16x16x32_bf16(a[mi], bq[nf], acc[mi][nf], 0, 0, 0);
  }
  __syncthreads();   // LDS tables ready
  float qbv[4], qmv[4];
  #pragma unroll
  for (int nf = 0; nf < 4; ++nf) {
    int j = wj + nf * 16 + lr;
    qbv[nf] = qbL[j]; qmv[nf] = qmL[j];
  }
  float rmv[4][4], rsv[4][4];
  #pragma unroll
  for (int mi = 0; mi < 4; ++mi)
    #pragma unroll
    for (int r = 0; r < 4; ++r) { rmv[mi][r] = -3.0e38f; rsv[mi][r] = 0.f; }
  // biases + S scatter (linear) + row-stat online over nf
  #pragma unroll
  for (int mi = 0; mi < 4; ++mi) {
    #pragma unroll
    for (int r = 0; r < 4; ++r) {
      int row = mi * 16 + h * 4 + r;
      float cbr = cbL[row];
      #pragma unroll
      for (int nf = 0; nf < 4; ++nf) {
        float sv = acc[mi][nf][r] + cbr + qbv[nf];
        acc[mi][nf][r] = sv;
        Pbuf[row * 256 + wj + nf * 16 + lr] = f2bf(sv);
        float vq = sv * qmv[nf] + NEGV * (1.f - qmv[nf]);
        float mn = fmaxf(rmv[mi][r], vq);
        rsv[mi][r] = rsv[mi][r] * __expf(rmv[mi][r] - mn) + __expf(vq - mn);
        rmv[mi][r] = mn;
      }
    }
  }
  #pragma unroll
  for (int off = 1; off < 16; off <<= 1) {
    #pragma unroll
    for (int mi = 0; mi < 4; ++mi)
      #pragma unroll
      for (int r = 0; r < 4; ++r) {
        float mo = __shfl_xor(rmv[mi][r], off);
        float so = __shfl_xor(rsv[mi][r], off);
        float mn = fmaxf(rmv[mi][r], mo);
        rsv[mi][r] = rsv[mi][r] * __expf(rmv[mi][r] - mn) + so * __expf(mo - mn);
        rmv[mi][r] = mn;
      }
  }
  if (lr == 0) {
    #pragma unroll
    for (int mi = 0; mi < 4; ++mi)
      #pragma unroll
      for (int r = 0; r < 4; ++r) {
        rmP[mi * 16 + h * 4 + r][w] = rmv[mi][r];
        rsP[mi * 16 + h * 4 + r][w] = rsv[mi][r];
      }
  }
  // col partials (over this block's 64 i-rows)
  float pm[4], ps[4];
  #pragma unroll
  for (int nf = 0; nf < 4; ++nf) { pm[nf] = -3.0e38f; ps[nf] = 0.f; }
  #pragma unroll
  for (int mi = 0; mi < 4; ++mi)
    #pragma unroll
    for (int r = 0; r < 4; ++r) {
      int row = mi * 16 + h * 4 + r;
      float cm = cmL[row];
      float cbias = NEGV * (1.f - cm);
      #pragma unroll
      for (int nf = 0; nf < 4; ++nf) {
        float v = acc[mi][nf][r] * cm + cbias;
        float mn = fmaxf(pm[nf], v);
        ps[nf] = ps[nf] * __expf(pm[nf] - mn) + __expf(v - mn);
        pm[nf] = mn;
      }
    }
  #pragma unroll
  for (int off = 16; off < 64; off <<= 1) {
    #pragma unroll
    for (int nf = 0; nf < 4; ++nf) {
      float mo = __shfl_xor(pm[nf], off);
      float so = __shfl_xor(ps[nf], off);
      float mn = fmaxf(pm[nf], mo);
      ps[nf] = ps[nf] * __expf(pm[nf] - mn) + so * __expf(mo - mn);
      pm[nf] = mn;
    }
  }
  if (h == 0) {
    #pragma unroll
    for (int nf = 0; nf < 4; ++nf) {
      int j = wj + nf * 16 + lr;
      colPm[((size_t)blockIdx.x * NB + b) * NQ + j] = pm[nf];
      colPs[((size_t)blockIdx.x * NB + b) * NQ + j] = ps[nf];
    }
  }
  __syncthreads();
  if (t < 64) {
    float m = rmP[t][0], s = rsP[t][0];
    #pragma unroll
    for (int k = 1; k < 4; ++k) {
      float mo = rmP[t][k], so = rsP[t][k];
      float mn = fmaxf(m, mo);
      s = s * __expf(m - mn) + so * __expf(mo - mn);
      m = mn;
    }
    frm[t] = m; fri[t] = 1.0f / s;
  }
  // copy S (bf16) out
  {
    int row = t >> 2, part = t & 3;
    unsigned short* dst = Sb16 + ((size_t)b * NC + i0 + row) * NQ + part * 64;
    #pragma unroll
    for (int q = 0; q < 8; ++q)
      *(u16x8*)&dst[q * 8] = *(const u16x8*)&Pbuf[row * 256 + part * 64 + q * 8];
  }
  __syncthreads();
  // P_bar into Pbuf (swizzled), then copy out
  #pragma unroll
  for (int mi = 0; mi < 4; ++mi)
    #pragma unroll
    for (int r = 0; r < 4; ++r) {
      int row = mi * 16 + h * 4 + r;
      float fm = frm[row], fv = fri[row];
      #pragma unroll
      for (int nf = 0; nf < 4; ++nf) {
        int jl = nf * 16 + lr;
        float vq = acc[mi][nf][r] * qmv[nf] + NEGV * (1.f - qmv[nf]);
        float p = __expf(vq - fm) * fv;
        Pbuf[row * 256 + wj + (((jl >> 3) ^ (row & 7)) & 7) * 8 + (jl & 7)] = f2bf(p);
      }
    }
  __syncthreads();
  {
    int row = t >> 2, part = t & 3;
    unsigned short* dst = pSwz + ((size_t)b * NC + i0 + row) * NQ + part * 64;
    #pragma unroll
    for (int q = 0; q < 8; ++q)
      *(u16x8*)&dst[q * 8] = *(const u16x8*)&Pbuf[row * 256 + part * 64 + q * 8];
  }
}

// ---------------- K3c: combine 16 col partials
__global__ __launch_bounds__(256) void k3c_combine(const float* __restrict__ colPm, const float* __restrict__ colPs,
                                                   float* __restrict__ colmax, float* __restrict__ colsum) {
  int idx = blockIdx.x * 256 + threadIdx.x;   // b*NQ + j
  float m = -3.0e38f, s = 0.f;
  #pragma unroll
  for (int tl = 0; tl < 16; ++tl) {
    float mo = colPm[(size_t)tl * NB * NQ + idx];
    float so = colPs[(size_t)tl * NB * NQ + idx];
    float mn = fmaxf(m, mo);
    s = s * __expf(m - mn) + so * __expf(mo - mn);
    m = mn;
  }
  colmax[idx] = m; colsum[idx] = s;
}

// ---------------- K_pc: S(bf16) -> P_bbar^T (col softmax, [b][j][i] swz)
__global__ __launch_bounds__(256) void k_pc(const unsigned short* __restrict__ Sb16,
                                            const float* __restrict__ c_mask,
                                            const float* __restrict__ colmax, const float* __restrict__ colsum,
                                            unsigned short* __restrict__ pSwzC) {
  __shared__ unsigned short T[64 * 256];
  __shared__ float cmxL[256], cinvL[256];
  int b = blockIdx.y, i0 = blockIdx.x * 64, t = threadIdx.x;
  cmxL[t] = colmax[b * NQ + t];
  cinvL[t] = 1.0f / colsum[b * NQ + t];
  __syncthreads();
  int li = t >> 2, jq = t & 3;
  int i = i0 + li;
  float cmi = c_mask[b * NC + i];
  float cbias = NEGV * (1.f - cmi);
  const unsigned short* srow = Sb16 + ((size_t)b * NC + i) * NQ + jq * 64;
  #pragma unroll
  for (int g = 0; g < 8; ++g) {
    u16x8 v = *(const u16x8*)&srow[g * 8];
    u16x8 pc;
    #pragma unroll
    for (int e = 0; e < 8; ++e) {
      int j = jq * 64 + g * 8 + e;
      pc[e] = f2bf(__expf(bf2f(v[e]) * cmi + cbias - cmxL[j]) * cinvL[j]);
    }
    int slot = g ^ (li & 7);
    *(u16x8*)&T[li * 256 + jq * 64 + slot * 8] = pc;
  }
  __syncthreads();
  int j = t, jq2 = j >> 6, jg = (j >> 3) & 7, je = j & 7;
  unsigned short* orow = pSwzC + ((size_t)b * NQ + j) * NC + i0;
  #pragma unroll
  for (int s8 = 0; s8 < 8; ++s8) {
    int ig = s8 ^ (j & 7);
    u16x8 o;
    #pragma unroll
    for (int e = 0; e < 8; ++e) {
      int ii = ig * 8 + e;
      o[e] = T[ii * 256 + jq2 * 64 + ((jg ^ e) << 3) + je];
    }
    *(u16x8*)&orow[s8 * 8] = o;
  }
}

// ---------------- K4 (MFMA, split-K): partial += Pbbar^T x C (both pre-staged bf16, pure-copy LDS)
__global__ __launch_bounds__(256) void k4_mfma(const unsigned short* __restrict__ pSwzC,
                                               const unsigned short* __restrict__ cSwz,
                                               float* __restrict__ partial) {
  __shared__ unsigned short Cs[64 * 64];
  __shared__ unsigned short Pt[64 * 64];
  int b = blockIdx.y;
  int tile = blockIdx.x & 7, split = blockIdx.x >> 3;
  int d0 = (tile & 1) * 64;
  int j0 = (tile >> 1) * 64;
  int icb = split * (NC / K4SPLIT);
  int t = threadIdx.x, w = t >> 6, l = t & 63, h = l >> 4, lr = l & 15;
  int crow = t >> 2, cq = t & 3;
  int wd = (w >> 1) * 32, wj = (w & 1) * 32;
  f32x4 acc[2][2] = {};

  for (int ic = icb; ic < icb + NC / K4SPLIT; ic += 64) {
    __syncthreads();
    {
      const unsigned short* csrc = cSwz + ((size_t)b * ND + d0 + crow) * NC + ic + cq * 16;
      *(u16x8*)&Cs[crow * 64 + cq * 16] = *(const u16x8*)csrc;
      *(u16x8*)&Cs[crow * 64 + cq * 16 + 8] = *(const u16x8*)(csrc + 8);
    }
    {
      const unsigned short* psrc = pSwzC + ((size_t)b * NQ + j0 + crow) * NC + ic + cq * 16;
      *(u16x8*)&Pt[crow * 64 + cq * 16] = *(const u16x8*)psrc;
      *(u16x8*)&Pt[crow * 64 + cq * 16 + 8] = *(const u16x8*)(psrc + 8);
    }
    __syncthreads();
    #pragma unroll
    for (int ks = 0; ks < 2; ++ks) {
      bf16x8 aC[2], bP[2];
      #pragma unroll
      for (int mi = 0; mi < 2; ++mi) {
        int row = wd + mi * 16 + lr;
        aC[mi] = *(const bf16x8*)&Cs[row * 64 + (((ks * 4 + h) ^ (lr & 7)) * 8)];
      }
      #pragma unroll
      for (int nf = 0; nf < 2; ++nf) {
        int row = wj + nf * 16 + lr;
        bP[nf] = *(const bf16x8*)&Pt[row * 64 + (((ks * 4 + h) ^ (lr & 7)) * 8)];
      }
      #pragma unroll
      for (int mi = 0; mi < 2; ++mi)
        #pragma unroll
        for (int nf = 0; nf < 2; ++nf)
          acc[mi][nf] = __builtin_amdgcn_mfma_f32_16x16x32_bf16(aC[mi], bP[nf], acc[mi][nf], 0, 0, 0);
    }
  }
  float* pout = partial + ((size_t)(split * NB + b) * ND) * NQ;
  #pragma unroll
  for (int mi = 0; mi < 2; ++mi)
    #pragma unroll
    for (int nf = 0; nf < 2; ++nf)
      #pragma unroll
      for (int r = 0; r < 4; ++r) {
        int d = d0 + wd + mi * 16 + h * 4 + r;
        int j = j0 + wj + nf * 16 + lr;
        pout[(size_t)d * NQ + j] = acc[mi][nf][r];
      }
}

// ---------------- K4c: combine split-K partials -> bf16 iSwz (pre-swizzled)
__global__ __launch_bounds__(256) void k4_combine(const float* __restrict__ partial,
                                                  unsigned short* __restrict__ iSwz) {
  int idx = blockIdx.x * 256 + threadIdx.x;   // over NB*ND*NQ/4
  const size_t n = (size_t)NB * ND * NQ / 4;
  const float4* p = (const float4*)partial;
  float4 a = p[idx], b4 = p[n + idx], c4 = p[2 * n + idx], d4 = p[3 * n + idx];
  u16x4 o;
  o[0] = f2bf(a.x + b4.x + c4.x + d4.x);
  o[1] = f2bf(a.y + b4.y + c4.y + d4.y);
  o[2] = f2bf(a.z + b4.z + c4.z + d4.z);
  o[3] = f2bf(a.w + b4.w + c4.w + d4.w);
  int lin = idx * 4;
  int j = lin & 255, dd = (lin >> 8) & 127, bb = lin >> 15;
  int g = (j >> 3) & 7, e0 = j & 7;
  int outoff = ((bb * 128 + dd) << 8) + (j & 192) + ((g ^ (dd & 7)) << 3) + e0;
  *(u16x4*)&iSwz[outoff] = o;
}

// ---------------- K5 (MFMA): A = Pbar@Q^T, Bm = Pbar@inner; write concat x (bf16)
__global__ __launch_bounds__(256) void k5_mfma(const unsigned short* __restrict__ pSwz, const float* __restrict__ C,
                                               const unsigned short* __restrict__ qSwz,
                                               const unsigned short* __restrict__ iSwz,
                                               unsigned short* __restrict__ xB) {
  extern __shared__ char sm[];
  unsigned short* Pl = (unsigned short*)sm;            // [32][64] bf16
  unsigned short* Qb = (unsigned short*)(sm + 4096);   // [128][64] bf16
  unsigned short* Ib = (unsigned short*)(sm + 20480);  // [128][64] bf16
  float* As = (float*)sm;                              // [32][133] f32 (aliases)
  float* Bs = (float*)(sm + 17024);                    // [32][133] f32
  int b = blockIdx.y, i0 = blockIdx.x * 32;
  int t = threadIdx.x, w = t >> 6, l = t & 63;
  int h = l >> 4, lr = l & 15;
  int pr_ = t >> 3, ps_ = t & 7;

  f32x4 accA[2][2] = {};
  f32x4 accB[2][2] = {};

  for (int jc = 0; jc < 4; ++jc) {
    int j0 = jc * 64;
    __syncthreads();
    *(u16x8*)&Pl[pr_ * 64 + ps_ * 8] =
        *(const u16x8*)(pSwz + ((size_t)b * NC + i0 + pr_) * NQ + j0 + ps_ * 8);
    #pragma unroll
    for (int k = 0; k < 4; ++k) {
      int u = t + k * 256;
      int d_ = u >> 3, s_ = u & 7;
      *(u16x8*)&Qb[d_ * 64 + s_ * 8] = *(const u16x8*)(qSwz + ((size_t)b * ND + d_) * NQ + j0 + s_ * 8);
      *(u16x8*)&Ib[d_ * 64 + s_ * 8] = *(const u16x8*)(iSwz + ((size_t)b * ND + d_) * NQ + j0 + s_ * 8);
    }
    __syncthreads();
    #pragma unroll
    for (int ks = 0; ks < 2; ++ks) {
      bf16x8 aP[2], bQ[2], bI[2];
      #pragma unroll
      for (int mi = 0; mi < 2; ++mi) {
        int i = mi * 16 + lr;
        int slot = (ks * 4 + h) ^ (i & 7);
        aP[mi] = *(const bf16x8*)&Pl[i * 64 + slot * 8];
      }
      #pragma unroll
      for (int nd = 0; nd < 2; ++nd) {
        int d = w * 32 + nd * 16 + lr;
        int slot = (ks * 4 + h) ^ (d & 7);
        bQ[nd] = *(const bf16x8*)&Qb[d * 64 + slot * 8];
        bI[nd] = *(const bf16x8*)&Ib[d * 64 + slot * 8];
      }
      #pragma unroll
      for (int mi = 0; mi < 2; ++mi)
        #pragma unroll
        for (int nd = 0; nd < 2; ++nd) {
          accA[mi][nd] = __builtin_amdgcn_mfma_f32_16x16x32_bf16(aP[mi], bQ[nd], accA[mi][nd], 0, 0, 0);
          accB[mi][nd] = __builtin_amdgcn_mfma_f32_16x16x32_bf16(aP[mi], bI[nd], accB[mi][nd], 0, 0, 0);
        }
    }
  }
  __syncthreads();
  #pragma unroll
  for (int mi = 0; mi < 2; ++mi)
    #pragma unroll
    for (int nd = 0; nd < 2; ++nd) {
      int d = w * 32 + nd * 16 + lr;
      #pragma unroll
      for (int r = 0; r < 4; ++r) {
        int i = mi * 16 + h * 4 + r;
        As[i * 133 + d] = accA[mi][nd][r];
        Bs[i * 133 + d] = accB[mi][nd][r];
      }
    }
  __syncthreads();
  {
    int i4 = (t & 7) * 4, db = t >> 3;
    const float* Cb = C + (size_t)b * ND * NC;
    unsigned short* xb = xB + (size_t)b * 4 * ND * NC;
    #pragma unroll
    for (int p = 0; p < 4; ++p) {
      int d = db + p * 32;
      float4 c4 = *(const float4*)&Cb[(size_t)d * NC + i0 + i4];
      float4 a4, b4;
      a4.x = As[(i4 + 0) * 133 + d]; a4.y = As[(i4 + 1) * 133 + d];
      a4.z = As[(i4 + 2) * 133 + d]; a4.w = As[(i4 + 3) * 133 + d];
      b4.x = Bs[(i4 + 0) * 133 + d]; b4.y = Bs[(i4 + 1) * 133 + d];
      b4.z = Bs[(i4 + 2) * 133 + d]; b4.w = Bs[(i4 + 3) * 133 + d];
      u16x4 o0, o1, o2, o3;
      o0[0] = f2bf(c4.x); o0[1] = f2bf(c4.y); o0[2] = f2bf(c4.z); o0[3] = f2bf(c4.w);
      o1[0] = f2bf(a4.x); o1[1] = f2bf(a4.y); o1[2] = f2bf(a4.z); o1[3] = f2bf(a4.w);
      o2[0] = f2bf(c4.x * a4.x); o2[1] = f2bf(c4.y * a4.y); o2[2] = f2bf(c4.z * a4.z); o2[3] = f2bf(c4.w * a4.w);
      o3[0] = f2bf(c4.x * b4.x); o3[1] = f2bf(c4.y * b4.y); o3[2] = f2bf(c4.z * b4.z); o3[3] = f2bf(c4.w * b4.w);
      *(u16x4*)&xb[(size_t)(0 * ND + d) * NC + i0 + i4] = o0;
      *(u16x4*)&xb[(size_t)(1 * ND + d) * NC + i0 + i4] = o1;
      *(u16x4*)&xb[(size_t)(2 * ND + d) * NC + i0 + i4] = o2;
      *(u16x4*)&xb[(size_t)(3 * ND + d) * NC + i0 + i4] = o3;
    }
  }
}

// ---------------- K6 (MFMA): depthwise(k=5,pad2) + pointwise GEMM
__global__ __launch_bounds__(256) void k6_mfma(const unsigned short* __restrict__ x,
                                               const float* __restrict__ dwW, const float* __restrict__ dwB,
                                               const unsigned short* __restrict__ pwB16,
                                               const float* __restrict__ pwB, float* __restrict__ out) {
  extern __shared__ char sm6[];
  unsigned short* xs = (unsigned short*)sm6;            // [64][56]
  unsigned short* x1s = (unsigned short*)(sm6 + 7168);  // [32][72]
  unsigned short* pws = (unsigned short*)(sm6 + 11776); // [128][72]
  int b = blockIdx.y, l0 = blockIdx.x * 32;
  int t = threadIdx.x, w = t >> 6, l = t & 63, h = l >> 4, lr = l & 15;
  const unsigned short* xb = x + (size_t)b * 4 * ND * NC;
  f32x4 acc[2][2] = {};
  int cgw = t & 63, lb = w * 8;

  for (int ch = 0; ch < 8; ++ch) {
    int cg0 = ch * 64;
    __syncthreads();
    #pragma unroll
    for (int k = 0; k < 2; ++k) {
      int id2 = t + k * 256;
      if (id2 < 384) {
        int row = id2 / 6, seg = id2 % 6;
        int gl = l0 - 8 + seg * 8;
        u16x8 v = {};
        if ((unsigned)gl <= 1016u)
          v = *(const u16x8*)(xb + (size_t)(cg0 + row) * NC + gl);
        *(u16x8*)&xs[row * 56 + seg * 8] = v;
      }
    }
    #pragma unroll
    for (int k = 0; k < 4; ++k) {
      int id2 = t + k * 256;
      int o = id2 >> 3, s8 = id2 & 7;
      *(u16x8*)&pws[o * 72 + s8 * 8] = *(const u16x8*)(pwB16 + (size_t)o * 512 + cg0 + s8 * 8);
    }
    __syncthreads();
    {
      int gch = cg0 + cgw;
      float bias = dwB[gch];
      float dwv[5];
      #pragma unroll
      for (int tp = 0; tp < 5; ++tp) dwv[tp] = dwW[gch * 5 + tp];
      float f[24];
      #pragma unroll
      for (int s = 0; s < 3; ++s) {
        u16x8 v = *(const u16x8*)&xs[cgw * 56 + lb + s * 8];
        #pragma unroll
        for (int e = 0; e < 8; ++e) f[s * 8 + e] = bf2f(v[e]);
      }
      #pragma unroll
      for (int e = 0; e < 8; ++e) {
        float a = bias;
        #pragma unroll
        for (int tp = 0; tp < 5; ++tp)
          a = fmaf(f[e + 6 + tp], dwv[tp], a);
        x1s[(lb + e) * 72 + cgw] = f2bf(a);
      }
    }
    __syncthreads();
    #pragma unroll
    for (int ks = 0; ks < 2; ++ks) {
      bf16x8 aW[2], bX[2];
      #pragma unroll
      for (int mi = 0; mi < 2; ++mi) {
        int o = w * 32 + mi * 16 + lr;
        aW[mi] = *(const bf16x8*)&pws[o * 72 + ks * 32 + h * 8];
      }
      #pragma unroll
      for (int nf = 0; nf < 2; ++nf) {
        int ll = nf * 16 + lr;
        bX[nf] = *(const bf16x8*)&x1s[ll * 72 + ks * 32 + h * 8];
      }
      #pragma unroll
      for (int mi = 0; mi < 2; ++mi)
        #pragma unroll
        for (int nf = 0; nf < 2; ++nf)
          acc[mi][nf] = __builtin_amdgcn_mfma_f32_16x16x32_bf16(aW[mi], bX[nf], acc[mi][nf], 0, 0, 0);
    }
  }
  #pragma unroll
  for (int mi = 0; mi < 2; ++mi) {
    #pragma unroll
    for (int r = 0; r < 4; ++r) {
      int o = w * 32 + mi * 16 + h * 4 + r;
      float bv = pwB[o];
      #pragma unroll
      for (int nf = 0; nf < 2; ++nf)
        out[((size_t)b * ND + o) * NC + l0 + nf * 16 + lr] = acc[mi][nf][r] + bv;
    }
  }
}

extern "C" void kernel_launch(void* const* d_in, const int* in_sizes, int n_in,
                              void* d_out, int out_size, void* d_ws, size_t ws_size,
                              hipStream_t stream) {
  const float* C = (const float*)d_in[0];
  const float* Q = (const float*)d_in[1];
  const float* c_mask = (const float*)d_in[2];
  const float* q_mask = (const float*)d_in[3];
  const float* W0 = (const float*)d_in[4];
  const float* dwW = (const float*)d_in[5];
  const float* dwB = (const float*)d_in[6];
  const float* pwW = (const float*)d_in[7];
  const float* pwB = (const float*)d_in[8];
  float* out = (float*)d_out;
  float* ws = (float*)d_ws;

  float* colmax = ws;                                  // NB*NQ
  float* colsum = colmax + NB * NQ;
  float* cb = colsum + NB * NQ;                        // NB*NC
  float* qb = cb + NB * NC;                            // NB*NQ
  float* colPm = qb + NB * NQ;                         // 16*NB*NQ
  float* colPs = colPm + 16 * NB * NQ;                 // 16*NB*NQ
  unsigned short* qSwz = (unsigned short*)(colPs + 16 * NB * NQ);   // NB*ND*NQ
  unsigned short* qT = qSwz + (size_t)NB * ND * NQ;                 // NB*NQ*ND
  unsigned short* iSwz = qT;                           // ALIAS: qT dead after k1f
  unsigned short* cw3T = qT + (size_t)NB * NQ * ND;                 // NB*NC*ND
  unsigned short* cSwz = cw3T + (size_t)NB * NC * ND;               // NB*ND*NC
  unsigned short* pwB16 = cSwz + (size_t)NB * ND * NC;              // 128*512
  unsigned short* Sb16 = pwB16 + ND * 512;                          // NB*NC*NQ bf16
  float* partial = (float*)Sb16;                       // ALIAS: Sb16 dead after k_pc (same byte size)
  unsigned short* pSwz = Sb16 + (size_t)NB * NC * NQ;               // NB*NC*NQ
  unsigned short* pSwzC = pSwz + (size_t)NB * NC * NQ;              // NB*NQ*NC
  unsigned short* xB = pSwzC;                          // ALIAS: pSwzC dead after k4 (+tail)

  k_pwcvt<<<dim3(32), 256, 0, stream>>>(pwW, pwB16);
  k_qcvt<<<dim3(64), 256, 0, stream>>>(Q, qSwz);
  k_qtcvt<<<dim3(4, NB), 256, 0, stream>>>(Q, qT);
  k_ccvt<<<dim3(16, NB), 256, 0, stream>>>(C, W0, cw3T);
  k_ccvt2<<<dim3(64), 256, 0, stream>>>(C, cSwz);
  k0_bias<<<dim3((NB * (NC + NQ) + 255) / 256), 256, 0, stream>>>(C, Q, W0, cb, qb);
  k1f<<<dim3(16, NB), 256, 0, stream>>>(cw3T, qT, cb, qb, q_mask, c_mask, Sb16, pSwz, colPm, colPs);
  k3c_combine<<<dim3(NB * NQ / 256), 256, 0, stream>>>(colPm, colPs, colmax, colsum);
  k_pc<<<dim3(16, NB), 256, 0, stream>>>(Sb16, c_mask, colmax, colsum, pSwzC);
  k4_mfma<<<dim3(8 * K4SPLIT, NB), 256, 0, stream>>>(pSwzC, cSwz, partial);
  k4_combine<<<dim3(NB * ND * NQ / 4 / 256), 256, 0, stream>>>(partial, iSwz);
  k5_mfma<<<dim3(NC / 32, NB), 256, 36864, stream>>>(pSwz, C, qSwz, iSwz, xB);
  k6_mfma<<<dim3(NC / 32, NB), 256, 30208, stream>>>(xB, dwW, dwB, pwB16, pwB, out);
}

// Round 9
// 146.948 us; speedup vs baseline: 4.7181x; 1.1152x over previous
//
#include <hip/hip_runtime.h>
#include <math.h>

#define NB 32
#define ND 128
#define NC 1024
#define NQ 256
#define NEGV (-1e30f)

typedef __attribute__((ext_vector_type(8))) __bf16 bf16x8;
typedef __attribute__((ext_vector_type(4))) float f32x4;
typedef __attribute__((ext_vector_type(8))) unsigned short u16x8;
typedef __attribute__((ext_vector_type(4))) unsigned short u16x4;

__device__ inline unsigned short f2bf(float f) {
  unsigned u = __builtin_bit_cast(unsigned, f);
  u += 0x7FFFu + ((u >> 16) & 1u);
  return (unsigned short)(u >> 16);
}
__device__ inline float bf2f(unsigned short u) {
  return __builtin_bit_cast(float, (unsigned)u << 16);
}

// ---------------- K0b: pwW f32 -> bf16
__global__ __launch_bounds__(256) void k_pwcvt(const float* __restrict__ pwW, unsigned short* __restrict__ pwB16) {
  int idx = blockIdx.x * 256 + threadIdx.x;   // 0..8191
  const float4* src = (const float4*)pwW;
  float4 v0 = src[idx * 2], v1 = src[idx * 2 + 1];
  u16x8 o;
  o[0] = f2bf(v0.x); o[1] = f2bf(v0.y); o[2] = f2bf(v0.z); o[3] = f2bf(v0.w);
  o[4] = f2bf(v1.x); o[5] = f2bf(v1.y); o[6] = f2bf(v1.z); o[7] = f2bf(v1.w);
  ((u16x8*)pwB16)[idx] = o;
}

// ---------------- k_qprep: one Q pass -> qSwz [b][d][j-slots], qT [b][j][d-slots], qb
__global__ __launch_bounds__(256) void k_qprep(const float* __restrict__ Q, const float* __restrict__ W0,
                                               unsigned short* __restrict__ qSwz, unsigned short* __restrict__ qT,
                                               float* __restrict__ qb) {
  __shared__ unsigned short T2[128 * 66];
  __shared__ float w2L[128];
  __shared__ float qbP[4][64];
  int b = blockIdx.y, jc = blockIdx.x, j0 = jc * 64, t = threadIdx.x;
  if (t < 128) w2L[t] = W0[ND + t];
  int d = t >> 1, half = t & 1;
  const float* src = Q + ((size_t)b * ND + d) * NQ + j0 + half * 32;
  unsigned short* qdst = qSwz + ((size_t)b * ND + d) * NQ + jc * 64;
  #pragma unroll
  for (int q = 0; q < 4; ++q) {
    float4 v0 = ((const float4*)src)[q * 2];
    float4 v1 = ((const float4*)src)[q * 2 + 1];
    u16x8 o;
    o[0] = f2bf(v0.x); o[1] = f2bf(v0.y); o[2] = f2bf(v0.z); o[3] = f2bf(v0.w);
    o[4] = f2bf(v1.x); o[5] = f2bf(v1.y); o[6] = f2bf(v1.z); o[7] = f2bf(v1.w);
    *(u16x8*)&T2[d * 66 + half * 32 + q * 8] = o;
    int g = half * 4 + q;
    *(u16x8*)&qdst[(g ^ (d & 7)) * 8] = o;
  }
  __syncthreads();
  {
    int jj = t & 63, dq = t >> 6;
    float s = 0.f;
    #pragma unroll 8
    for (int k = 0; k < 32; ++k) {
      int dd = dq * 32 + k;
      s += bf2f(T2[dd * 66 + jj]) * w2L[dd];
    }
    qbP[dq][jj] = s;
  }
  __syncthreads();
  if (t < 64)
    qb[b * NQ + j0 + t] = qbP[0][t] + qbP[1][t] + qbP[2][t] + qbP[3][t];
  {
    int jj = t >> 2, p = t & 3;
    unsigned short* dst = qT + ((size_t)b * NQ + j0 + jj) * ND;
    #pragma unroll
    for (int q = 0; q < 4; ++q) {
      int g = p * 4 + q;
      u16x8 o;
      #pragma unroll
      for (int e = 0; e < 8; ++e) o[e] = T2[(g * 8 + e) * 66 + jj];
      int sg = (g & 8) | ((g & 7) ^ (jj & 7));
      *(u16x8*)&dst[sg * 8] = o;
    }
  }
}

// ---------------- k_cprep: one C pass -> cw3T [b][i][k-slots], cSwz [b][d][i-slots], cb
__global__ __launch_bounds__(256) void k_cprep(const float* __restrict__ C, const float* __restrict__ W0,
                                               unsigned short* __restrict__ cw3T, unsigned short* __restrict__ cSwz,
                                               float* __restrict__ cb) {
  __shared__ unsigned short T2[128 * 66];
  __shared__ float w1L[128], w3L[128];
  __shared__ float cbP[4][64];
  int b = blockIdx.y, i0 = blockIdx.x * 64, t = threadIdx.x;
  if (t < 128) { w1L[t] = W0[t]; w3L[t] = W0[2 * ND + t]; }
  int k = t >> 1, half = t & 1;
  const float* src = C + ((size_t)b * ND + k) * NC + i0 + half * 32;
  unsigned short* cdst = cSwz + ((size_t)b * ND + k) * NC + blockIdx.x * 64;
  #pragma unroll
  for (int q = 0; q < 4; ++q) {
    float4 v0 = ((const float4*)src)[q * 2];
    float4 v1 = ((const float4*)src)[q * 2 + 1];
    u16x8 o;
    o[0] = f2bf(v0.x); o[1] = f2bf(v0.y); o[2] = f2bf(v0.z); o[3] = f2bf(v0.w);
    o[4] = f2bf(v1.x); o[5] = f2bf(v1.y); o[6] = f2bf(v1.z); o[7] = f2bf(v1.w);
    *(u16x8*)&T2[k * 66 + half * 32 + q * 8] = o;
    int g = half * 4 + q;
    *(u16x8*)&cdst[(g ^ (k & 7)) * 8] = o;
  }
  __syncthreads();
  {
    int ii = t & 63, kq = t >> 6;
    float s = 0.f;
    #pragma unroll 8
    for (int kk = 0; kk < 32; ++kk) {
      int dd = kq * 32 + kk;
      s += bf2f(T2[dd * 66 + ii]) * w1L[dd];
    }
    cbP[kq][ii] = s;
  }
  __syncthreads();
  if (t < 64)
    cb[b * NC + i0 + t] = cbP[0][t] + cbP[1][t] + cbP[2][t] + cbP[3][t];
  {
    int ii = t >> 2, p = t & 3;
    unsigned short* dst = cw3T + ((size_t)b * NC + i0 + ii) * ND;
    #pragma unroll
    for (int q = 0; q < 4; ++q) {
      int g = p * 4 + q;
      u16x8 o;
      #pragma unroll
      for (int e = 0; e < 8; ++e)
        o[e] = f2bf(bf2f(T2[(g * 8 + e) * 66 + ii]) * w3L[g * 8 + e]);
      int sg = (g & 8) | ((g & 7) ^ (ii & 7));
      *(u16x8*)&dst[sg * 8] = o;
    }
  }
}

// ---------------- k_stats: MFMA S + full row stats + col partials (no S output). Tile 64i x 256j.
__global__ __launch_bounds__(256) void k_stats(const unsigned short* __restrict__ cw3T,
                                               const unsigned short* __restrict__ qT,
                                               const float* __restrict__ cb, const float* __restrict__ qb,
                                               const float* __restrict__ q_mask, const float* __restrict__ c_mask,
                                               float* __restrict__ rowmax, float* __restrict__ rowsum,
                                               float* __restrict__ colPm, float* __restrict__ colPs) {
  __shared__ float rmP[64][4], rsP[64][4];
  __shared__ float cbL[64], cmL[64], qbL[256], qmL[256];
  int b = blockIdx.y, i0 = blockIdx.x * 64;
  int t = threadIdx.x, w = t >> 6, l = t & 63, h = l >> 4, lr = l & 15;
  int wj = w * 64;
  if (t < 64) { cbL[t] = cb[b * NC + i0 + t]; cmL[t] = c_mask[b * NC + i0 + t]; }
  qbL[t] = qb[b * NQ + t];
  qmL[t] = q_mask[b * NQ + t];
  const unsigned short* Arow = cw3T + ((size_t)b * NC + i0) * ND;
  const unsigned short* Brow = qT + (size_t)b * NQ * ND;
  f32x4 acc[4][4] = {};
  #pragma unroll
  for (int ks = 0; ks < 4; ++ks) {
    int g = ks * 4 + h;
    int off = ((g & 8) | ((g & 7) ^ (lr & 7))) * 8;
    bf16x8 a[4], bq[4];
    #pragma unroll
    for (int mi = 0; mi < 4; ++mi)
      a[mi] = *(const bf16x8*)&Arow[(size_t)(mi * 16 + lr) * ND + off];
    #pragma unroll
    for (int nf = 0; nf < 4; ++nf)
      bq[nf] = *(const bf16x8*)&Brow[(size_t)(wj + nf * 16 + lr) * ND + off];
    #pragma unroll
    for (int mi = 0; mi < 4; ++mi)
      #pragma unroll
      for (int nf = 0; nf < 4; ++nf)
        acc[mi][nf] = __builtin_amdgcn_mfma_f32_16x16x32_bf16(a[mi], bq[nf], acc[mi][nf], 0, 0, 0);
  }
  __syncthreads();
  float qbv[4], qmv[4];
  #pragma unroll
  for (int nf = 0; nf < 4; ++nf) {
    int j = wj + nf * 16 + lr;
    qbv[nf] = qbL[j]; qmv[nf] = qmL[j];
  }
  float rmv[4][4], rsv[4][4];
  #pragma unroll
  for (int mi = 0; mi < 4; ++mi)
    #pragma unroll
    for (int r = 0; r < 4; ++r) { rmv[mi][r] = -3.0e38f; rsv[mi][r] = 0.f; }
  #pragma unroll
  for (int mi = 0; mi < 4; ++mi) {
    #pragma unroll
    for (int r = 0; r < 4; ++r) {
      int row = mi * 16 + h * 4 + r;
      float cbr = cbL[row];
      #pragma unroll
      for (int nf = 0; nf < 4; ++nf) {
        float sv = acc[mi][nf][r] + cbr + qbv[nf];
        acc[mi][nf][r] = sv;
        float vq = sv * qmv[nf] + NEGV * (1.f - qmv[nf]);
        float mn = fmaxf(rmv[mi][r], vq);
        rsv[mi][r] = rsv[mi][r] * __expf(rmv[mi][r] - mn) + __expf(vq - mn);
        rmv[mi][r] = mn;
      }
    }
  }
  #pragma unroll
  for (int off = 1; off < 16; off <<= 1) {
    #pragma unroll
    for (int mi = 0; mi < 4; ++mi)
      #pragma unroll
      for (int r = 0; r < 4; ++r) {
        float mo = __shfl_xor(rmv[mi][r], off);
        float so = __shfl_xor(rsv[mi][r], off);
        float mn = fmaxf(rmv[mi][r], mo);
        rsv[mi][r] = rsv[mi][r] * __expf(rmv[mi][r] - mn) + so * __expf(mo - mn);
        rmv[mi][r] = mn;
      }
  }
  if (lr == 0) {
    #pragma unroll
    for (int mi = 0; mi < 4; ++mi)
      #pragma unroll
      for (int r = 0; r < 4; ++r) {
        rmP[mi * 16 + h * 4 + r][w] = rmv[mi][r];
        rsP[mi * 16 + h * 4 + r][w] = rsv[mi][r];
      }
  }
  // col partials over this block's 64 i-rows
  float pm[4], ps[4];
  #pragma unroll
  for (int nf = 0; nf < 4; ++nf) { pm[nf] = -3.0e38f; ps[nf] = 0.f; }
  #pragma unroll
  for (int mi = 0; mi < 4; ++mi)
    #pragma unroll
    for (int r = 0; r < 4; ++r) {
      int row = mi * 16 + h * 4 + r;
      float cm = cmL[row];
      float cbias = NEGV * (1.f - cm);
      #pragma unroll
      for (int nf = 0; nf < 4; ++nf) {
        float v = acc[mi][nf][r] * cm + cbias;
        float mn = fmaxf(pm[nf], v);
        ps[nf] = ps[nf] * __expf(pm[nf] - mn) + __expf(v - mn);
        pm[nf] = mn;
      }
    }
  #pragma unroll
  for (int off = 16; off < 64; off <<= 1) {
    #pragma unroll
    for (int nf = 0; nf < 4; ++nf) {
      float mo = __shfl_xor(pm[nf], off);
      float so = __shfl_xor(ps[nf], off);
      float mn = fmaxf(pm[nf], mo);
      ps[nf] = ps[nf] * __expf(pm[nf] - mn) + so * __expf(mo - mn);
      pm[nf] = mn;
    }
  }
  if (h == 0) {
    #pragma unroll
    for (int nf = 0; nf < 4; ++nf) {
      int j = wj + nf * 16 + lr;
      colPm[((size_t)blockIdx.x * NB + b) * NQ + j] = pm[nf];
      colPs[((size_t)blockIdx.x * NB + b) * NQ + j] = ps[nf];
    }
  }
  __syncthreads();
  if (t < 64) {
    float m = rmP[t][0], s = rsP[t][0];
    #pragma unroll
    for (int k = 1; k < 4; ++k) {
      float mo = rmP[t][k], so = rsP[t][k];
      float mn = fmaxf(m, mo);
      s = s * __expf(m - mn) + so * __expf(mo - mn);
      m = mn;
    }
    rowmax[b * NC + i0 + t] = m;
    rowsum[b * NC + i0 + t] = s;
  }
}

// ---------------- K3c: combine 16 col partials
__global__ __launch_bounds__(256) void k3c_combine(const float* __restrict__ colPm, const float* __restrict__ colPs,
                                                   float* __restrict__ colmax, float* __restrict__ colsum) {
  int idx = blockIdx.x * 256 + threadIdx.x;   // b*NQ + j
  float m = -3.0e38f, s = 0.f;
  #pragma unroll
  for (int tl = 0; tl < 16; ++tl) {
    float mo = colPm[(size_t)tl * NB * NQ + idx];
    float so = colPs[(size_t)tl * NB * NQ + idx];
    float mn = fmaxf(m, mo);
    s = s * __expf(m - mn) + so * __expf(mo - mn);
    m = mn;
  }
  colmax[idx] = m; colsum[idx] = s;
}

// ---------------- k4f: fused S -> P_bbar^T -> inner (split-i 2). Block: 128d x 32j.
__global__ __launch_bounds__(256) void k4f(const unsigned short* __restrict__ cw3T,
                                           const unsigned short* __restrict__ qT,
                                           const unsigned short* __restrict__ cSwz,
                                           const float* __restrict__ cb, const float* __restrict__ qb,
                                           const float* __restrict__ c_mask,
                                           const float* __restrict__ colmax, const float* __restrict__ colsum,
                                           float* __restrict__ partial) {
  __shared__ unsigned short Acw[64 * 128];   // cw3T i-chunk rows (16 KB)
  __shared__ unsigned short Cs[128 * 64];    // cSwz d-rows, i-chunk (16 KB)
  __shared__ unsigned short Bq[32 * 128];    // qT j-rows (8 KB)
  __shared__ unsigned short Pt[32 * 64];     // P^T operand (4 KB)
  __shared__ float cmxL[32], cinvL[32], qbL2[32], cbL[64], cmL[64];
  int b = blockIdx.y;
  int jt = blockIdx.x & 7, split = blockIdx.x >> 3;
  int j0 = jt * 32;
  int t = threadIdx.x, w = t >> 6, l = t & 63, h = l >> 4, lr = l & 15;
  {
    int r = t >> 3, p = t & 7;   // Bq stage: 32 rows x 16 shorts/thread
    const unsigned short* src = qT + ((size_t)b * NQ + j0 + r) * ND + p * 16;
    *(u16x8*)&Bq[r * 128 + p * 16] = *(const u16x8*)src;
    *(u16x8*)&Bq[r * 128 + p * 16 + 8] = *(const u16x8*)(src + 8);
  }
  if (t < 32) {
    cmxL[t] = colmax[b * NQ + j0 + t];
    cinvL[t] = 1.0f / colsum[b * NQ + j0 + t];
    qbL2[t] = qb[b * NQ + j0 + t];
  }
  f32x4 accI[2][2] = {};
  for (int ic8 = 0; ic8 < 8; ++ic8) {
    int ic = split * 512 + ic8 * 64;
    __syncthreads();
    {
      int r = t >> 2, p = t & 3;   // Acw: 64 rows x 32 shorts/thread
      const unsigned short* src = cw3T + ((size_t)b * NC + ic + r) * ND + p * 32;
      *(u16x8*)&Acw[r * 128 + p * 32] = *(const u16x8*)src;
      *(u16x8*)&Acw[r * 128 + p * 32 + 8] = *(const u16x8*)(src + 8);
      *(u16x8*)&Acw[r * 128 + p * 32 + 16] = *(const u16x8*)(src + 16);
      *(u16x8*)&Acw[r * 128 + p * 32 + 24] = *(const u16x8*)(src + 24);
    }
    {
      int r = t >> 1, p = t & 1;   // Cs: 128 rows x 32 shorts/thread
      const unsigned short* src = cSwz + ((size_t)b * ND + r) * NC + ic + p * 32;
      *(u16x8*)&Cs[r * 64 + p * 32] = *(const u16x8*)src;
      *(u16x8*)&Cs[r * 64 + p * 32 + 8] = *(const u16x8*)(src + 8);
      *(u16x8*)&Cs[r * 64 + p * 32 + 16] = *(const u16x8*)(src + 16);
      *(u16x8*)&Cs[r * 64 + p * 32 + 24] = *(const u16x8*)(src + 24);
    }
    if (t < 64) { cbL[t] = cb[b * NC + ic + t]; cmL[t] = c_mask[b * NC + ic + t]; }
    __syncthreads();
    // phase A: S chunk [64i x 32j]; wave w owns i-frag w
    f32x4 sA[2] = {};
    #pragma unroll
    for (int ks = 0; ks < 4; ++ks) {
      int g = ks * 4 + h;
      int off = ((g & 8) | ((g & 7) ^ (lr & 7))) * 8;
      bf16x8 av = *(const bf16x8*)&Acw[(w * 16 + lr) * 128 + off];
      #pragma unroll
      for (int jf = 0; jf < 2; ++jf) {
        bf16x8 bv = *(const bf16x8*)&Bq[(jf * 16 + lr) * 128 + off];
        sA[jf] = __builtin_amdgcn_mfma_f32_16x16x32_bf16(av, bv, sA[jf], 0, 0, 0);
      }
    }
    #pragma unroll
    for (int jf = 0; jf < 2; ++jf)
      #pragma unroll
      for (int r = 0; r < 4; ++r) {
        int i_ = w * 16 + h * 4 + r;
        int j_ = jf * 16 + lr;
        float sfull = sA[jf][r] + cbL[i_] + qbL2[j_];
        float cm = cmL[i_];
        float vc = sfull * cm + NEGV * (1.f - cm);
        float p = __expf(vc - cmxL[j_]) * cinvL[j_];
        Pt[j_ * 64 + (((i_ >> 3) ^ (j_ & 7)) << 3) + (i_ & 7)] = f2bf(p);
      }
    __syncthreads();
    // phase B: inner += C x P^T
    #pragma unroll
    for (int ks = 0; ks < 2; ++ks) {
      bf16x8 aC[2], bP[2];
      #pragma unroll
      for (int mf = 0; mf < 2; ++mf) {
        int d = w * 32 + mf * 16 + lr;
        aC[mf] = *(const bf16x8*)&Cs[d * 64 + (((ks * 4 + h) ^ (lr & 7)) * 8)];
      }
      #pragma unroll
      for (int jf = 0; jf < 2; ++jf) {
        int j_ = jf * 16 + lr;
        bP[jf] = *(const bf16x8*)&Pt[j_ * 64 + (((ks * 4 + h) ^ (j_ & 7)) * 8)];
      }
      #pragma unroll
      for (int mf = 0; mf < 2; ++mf)
        #pragma unroll
        for (int jf = 0; jf < 2; ++jf)
          accI[mf][jf] = __builtin_amdgcn_mfma_f32_16x16x32_bf16(aC[mf], bP[jf], accI[mf][jf], 0, 0, 0);
    }
  }
  float* pout = partial + ((size_t)(split * NB + b) * ND) * NQ;
  #pragma unroll
  for (int mf = 0; mf < 2; ++mf)
    #pragma unroll
    for (int jf = 0; jf < 2; ++jf)
      #pragma unroll
      for (int r = 0; r < 4; ++r) {
        int d = w * 32 + mf * 16 + h * 4 + r;
        int j = j0 + jf * 16 + lr;
        pout[(size_t)d * NQ + j] = accI[mf][jf][r];
      }
}

// ---------------- k4c2: combine 2 split partials -> bf16 iSwz (pre-swizzled)
__global__ __launch_bounds__(256) void k4c2(const float* __restrict__ partial,
                                            unsigned short* __restrict__ iSwz) {
  int idx = blockIdx.x * 256 + threadIdx.x;   // over NB*ND*NQ/4
  const size_t n = (size_t)NB * ND * NQ / 4;
  const float4* p = (const float4*)partial;
  float4 a = p[idx], b4 = p[n + idx];
  u16x4 o;
  o[0] = f2bf(a.x + b4.x);
  o[1] = f2bf(a.y + b4.y);
  o[2] = f2bf(a.z + b4.z);
  o[3] = f2bf(a.w + b4.w);
  int lin = idx * 4;
  int j = lin & 255, dd = (lin >> 8) & 127, bb = lin >> 15;
  int g = (j >> 3) & 7, e0 = j & 7;
  int outoff = ((bb * 128 + dd) << 8) + (j & 192) + ((g ^ (dd & 7)) << 3) + e0;
  *(u16x4*)&iSwz[outoff] = o;
}

// ---------------- k5f: fused S -> P_bar -> {A, Bm} -> concat x (bf16). Block: 32i x 128d.
__global__ __launch_bounds__(256) void k5f(const unsigned short* __restrict__ cw3T,
                                           const unsigned short* __restrict__ qT,
                                           const unsigned short* __restrict__ qSwz,
                                           const unsigned short* __restrict__ iSwz,
                                           const float* __restrict__ C,
                                           const float* __restrict__ cb, const float* __restrict__ qb,
                                           const float* __restrict__ q_mask,
                                           const float* __restrict__ rowmax, const float* __restrict__ rowsum,
                                           unsigned short* __restrict__ xB) {
  extern __shared__ char sm[];
  unsigned short* cwA = (unsigned short*)sm;            // [32][128] 8KB
  unsigned short* R1 = (unsigned short*)(sm + 8192);    // Bq [64][128] then Qb [128][64] (16KB)
  unsigned short* IbL = (unsigned short*)(sm + 24576);  // [128][64] 16KB
  unsigned short* Pl = (unsigned short*)(sm + 40960);   // [32][64] 4KB
  float* As = (float*)sm;                               // epilogue alias [32][133]
  float* Bs = (float*)(sm + 17024);
  __shared__ float rmL[32], riL[32], cbI[32], qbL[256], qmL[256];
  int b = blockIdx.y, i0 = blockIdx.x * 32;
  int t = threadIdx.x, w = t >> 6, l = t & 63, h = l >> 4, lr = l & 15;
  {
    int r = t >> 3, p = t & 7;   // cwA: 32 rows x 16 shorts/thread
    const unsigned short* src = cw3T + ((size_t)b * NC + i0 + r) * ND + p * 16;
    *(u16x8*)&cwA[r * 128 + p * 16] = *(const u16x8*)src;
    *(u16x8*)&cwA[r * 128 + p * 16 + 8] = *(const u16x8*)(src + 8);
  }
  if (t < 32) {
    rmL[t] = rowmax[b * NC + i0 + t];
    riL[t] = 1.0f / rowsum[b * NC + i0 + t];
    cbI[t] = cb[b * NC + i0 + t];
  }
  qbL[t] = qb[b * NQ + t];
  qmL[t] = q_mask[b * NQ + t];

  f32x4 accA[2][2] = {};
  f32x4 accB[2][2] = {};

  for (int jc = 0; jc < 4; ++jc) {
    int j0 = jc * 64;
    __syncthreads();
    {
      int r = t >> 2, p = t & 3;   // Bq: 64 rows x 32 shorts/thread
      const unsigned short* src = qT + ((size_t)b * NQ + j0 + r) * ND + p * 32;
      *(u16x8*)&R1[r * 128 + p * 32] = *(const u16x8*)src;
      *(u16x8*)&R1[r * 128 + p * 32 + 8] = *(const u16x8*)(src + 8);
      *(u16x8*)&R1[r * 128 + p * 32 + 16] = *(const u16x8*)(src + 16);
      *(u16x8*)&R1[r * 128 + p * 32 + 24] = *(const u16x8*)(src + 24);
    }
    #pragma unroll
    for (int k = 0; k < 4; ++k) {
      int u = t + k * 256;
      int d_ = u >> 3, s_ = u & 7;
      *(u16x8*)&IbL[d_ * 64 + s_ * 8] = *(const u16x8*)(iSwz + ((size_t)b * ND + d_) * NQ + j0 + s_ * 8);
    }
    __syncthreads();
    // phase A: S [32i x 64j]; wave w owns j-frag group w
    f32x4 sA[2] = {};
    #pragma unroll
    for (int ks = 0; ks < 4; ++ks) {
      int g = ks * 4 + h;
      int off = ((g & 8) | ((g & 7) ^ (lr & 7))) * 8;
      bf16x8 bv = *(const bf16x8*)&R1[(w * 16 + lr) * 128 + off];
      #pragma unroll
      for (int mi = 0; mi < 2; ++mi) {
        bf16x8 av = *(const bf16x8*)&cwA[(mi * 16 + lr) * 128 + off];
        sA[mi] = __builtin_amdgcn_mfma_f32_16x16x32_bf16(av, bv, sA[mi], 0, 0, 0);
      }
    }
    #pragma unroll
    for (int mi = 0; mi < 2; ++mi)
      #pragma unroll
      for (int r = 0; r < 4; ++r) {
        int i_ = mi * 16 + h * 4 + r;
        int j_ = w * 16 + lr;
        float sfull = sA[mi][r] + cbI[i_] + qbL[j0 + j_];
        float qm = qmL[j0 + j_];
        float vq = sfull * qm + NEGV * (1.f - qm);
        float p = __expf(vq - rmL[i_]) * riL[i_];
        Pl[i_ * 64 + (((j_ >> 3) ^ (i_ & 7)) << 3) + (j_ & 7)] = f2bf(p);
      }
    __syncthreads();
    #pragma unroll
    for (int k = 0; k < 4; ++k) {
      int u = t + k * 256;
      int d_ = u >> 3, s_ = u & 7;
      *(u16x8*)&R1[d_ * 64 + s_ * 8] = *(const u16x8*)(qSwz + ((size_t)b * ND + d_) * NQ + j0 + s_ * 8);
    }
    __syncthreads();
    // phase B: A += P x Q^T, Bm += P x inner
    #pragma unroll
    for (int ks = 0; ks < 2; ++ks) {
      bf16x8 aP[2], bQ[2], bI[2];
      #pragma unroll
      for (int mi = 0; mi < 2; ++mi) {
        int i = mi * 16 + lr;
        int slot = (ks * 4 + h) ^ (i & 7);
        aP[mi] = *(const bf16x8*)&Pl[i * 64 + slot * 8];
      }
      #pragma unroll
      for (int nd = 0; nd < 2; ++nd) {
        int d = w * 32 + nd * 16 + lr;
        int slot = (ks * 4 + h) ^ (d & 7);
        bQ[nd] = *(const bf16x8*)&R1[d * 64 + slot * 8];
        bI[nd] = *(const bf16x8*)&IbL[d * 64 + slot * 8];
      }
      #pragma unroll
      for (int mi = 0; mi < 2; ++mi)
        #pragma unroll
        for (int nd = 0; nd < 2; ++nd) {
          accA[mi][nd] = __builtin_amdgcn_mfma_f32_16x16x32_bf16(aP[mi], bQ[nd], accA[mi][nd], 0, 0, 0);
          accB[mi][nd] = __builtin_amdgcn_mfma_f32_16x16x32_bf16(aP[mi], bI[nd], accB[mi][nd], 0, 0, 0);
        }
    }
  }
  __syncthreads();
  #pragma unroll
  for (int mi = 0; mi < 2; ++mi)
    #pragma unroll
    for (int nd = 0; nd < 2; ++nd) {
      int d = w * 32 + nd * 16 + lr;
      #pragma unroll
      for (int r = 0; r < 4; ++r) {
        int i = mi * 16 + h * 4 + r;
        As[i * 133 + d] = accA[mi][nd][r];
        Bs[i * 133 + d] = accB[mi][nd][r];
      }
    }
  __syncthreads();
  {
    int i4 = (t & 7) * 4, db = t >> 3;
    const float* Cb = C + (size_t)b * ND * NC;
    unsigned short* xb = xB + (size_t)b * 4 * ND * NC;
    #pragma unroll
    for (int p = 0; p < 4; ++p) {
      int d = db + p * 32;
      float4 c4 = *(const float4*)&Cb[(size_t)d * NC + i0 + i4];
      float4 a4, b4;
      a4.x = As[(i4 + 0) * 133 + d]; a4.y = As[(i4 + 1) * 133 + d];
      a4.z = As[(i4 + 2) * 133 + d]; a4.w = As[(i4 + 3) * 133 + d];
      b4.x = Bs[(i4 + 0) * 133 + d]; b4.y = Bs[(i4 + 1) * 133 + d];
      b4.z = Bs[(i4 + 2) * 133 + d]; b4.w = Bs[(i4 + 3) * 133 + d];
      u16x4 o0, o1, o2, o3;
      o0[0] = f2bf(c4.x); o0[1] = f2bf(c4.y); o0[2] = f2bf(c4.z); o0[3] = f2bf(c4.w);
      o1[0] = f2bf(a4.x); o1[1] = f2bf(a4.y); o1[2] = f2bf(a4.z); o1[3] = f2bf(a4.w);
      o2[0] = f2bf(c4.x * a4.x); o2[1] = f2bf(c4.y * a4.y); o2[2] = f2bf(c4.z * a4.z); o2[3] = f2bf(c4.w * a4.w);
      o3[0] = f2bf(c4.x * b4.x); o3[1] = f2bf(c4.y * b4.y); o3[2] = f2bf(c4.z * b4.z); o3[3] = f2bf(c4.w * b4.w);
      *(u16x4*)&xb[(size_t)(0 * ND + d) * NC + i0 + i4] = o0;
      *(u16x4*)&xb[(size_t)(1 * ND + d) * NC + i0 + i4] = o1;
      *(u16x4*)&xb[(size_t)(2 * ND + d) * NC + i0 + i4] = o2;
      *(u16x4*)&xb[(size_t)(3 * ND + d) * NC + i0 + i4] = o3;
    }
  }
}

// ---------------- K6 (MFMA): depthwise(k=5,pad2) + pointwise GEMM
__global__ __launch_bounds__(256) void k6_mfma(const unsigned short* __restrict__ x,
                                               const float* __restrict__ dwW, const float* __restrict__ dwB,
                                               const unsigned short* __restrict__ pwB16,
                                               const float* __restrict__ pwB, float* __restrict__ out) {
  extern __shared__ char sm6[];
  unsigned short* xs = (unsigned short*)sm6;            // [64][56]
  unsigned short* x1s = (unsigned short*)(sm6 + 7168);  // [32][72]
  unsigned short* pws = (unsigned short*)(sm6 + 11776); // [128][72]
  int b = blockIdx.y, l0 = blockIdx.x * 32;
  int t = threadIdx.x, w = t >> 6, l = t & 63, h = l >> 4, lr = l & 15;
  const unsigned short* xb = x + (size_t)b * 4 * ND * NC;
  f32x4 acc[2][2] = {};
  int cgw = t & 63, lb = w * 8;

  for (int ch = 0; ch < 8; ++ch) {
    int cg0 = ch * 64;
    __syncthreads();
    #pragma unroll
    for (int k = 0; k < 2; ++k) {
      int id2 = t + k * 256;
      if (id2 < 384) {
        int row = id2 / 6, seg = id2 % 6;
        int gl = l0 - 8 + seg * 8;
        u16x8 v = {};
        if ((unsigned)gl <= 1016u)
          v = *(const u16x8*)(xb + (size_t)(cg0 + row) * NC + gl);
        *(u16x8*)&xs[row * 56 + seg * 8] = v;
      }
    }
    #pragma unroll
    for (int k = 0; k < 4; ++k) {
      int id2 = t + k * 256;
      int o = id2 >> 3, s8 = id2 & 7;
      *(u16x8*)&pws[o * 72 + s8 * 8] = *(const u16x8*)(pwB16 + (size_t)o * 512 + cg0 + s8 * 8);
    }
    __syncthreads();
    {
      int gch = cg0 + cgw;
      float bias = dwB[gch];
      float dwv[5];
      #pragma unroll
      for (int tp = 0; tp < 5; ++tp) dwv[tp] = dwW[gch * 5 + tp];
      float f[24];
      #pragma unroll
      for (int s = 0; s < 3; ++s) {
        u16x8 v = *(const u16x8*)&xs[cgw * 56 + lb + s * 8];
        #pragma unroll
        for (int e = 0; e < 8; ++e) f[s * 8 + e] = bf2f(v[e]);
      }
      #pragma unroll
      for (int e = 0; e < 8; ++e) {
        float a = bias;
        #pragma unroll
        for (int tp = 0; tp < 5; ++tp)
          a = fmaf(f[e + 6 + tp], dwv[tp], a);
        x1s[(lb + e) * 72 + cgw] = f2bf(a);
      }
    }
    __syncthreads();
    #pragma unroll
    for (int ks = 0; ks < 2; ++ks) {
      bf16x8 aW[2], bX[2];
      #pragma unroll
      for (int mi = 0; mi < 2; ++mi) {
        int o = w * 32 + mi * 16 + lr;
        aW[mi] = *(const bf16x8*)&pws[o * 72 + ks * 32 + h * 8];
      }
      #pragma unroll
      for (int nf = 0; nf < 2; ++nf) {
        int ll = nf * 16 + lr;
        bX[nf] = *(const bf16x8*)&x1s[ll * 72 + ks * 32 + h * 8];
      }
      #pragma unroll
      for (int mi = 0; mi < 2; ++mi)
        #pragma unroll
        for (int nf = 0; nf < 2; ++nf)
          acc[mi][nf] = __builtin_amdgcn_mfma_f32_16x16x32_bf16(aW[mi], bX[nf], acc[mi][nf], 0, 0, 0);
    }
  }
  #pragma unroll
  for (int mi = 0; mi < 2; ++mi) {
    #pragma unroll
    for (int r = 0; r < 4; ++r) {
      int o = w * 32 + mi * 16 + h * 4 + r;
      float bv = pwB[o];
      #pragma unroll
      for (int nf = 0; nf < 2; ++nf)
        out[((size_t)b * ND + o) * NC + l0 + nf * 16 + lr] = acc[mi][nf][r] + bv;
    }
  }
}

extern "C" void kernel_launch(void* const* d_in, const int* in_sizes, int n_in,
                              void* d_out, int out_size, void* d_ws, size_t ws_size,
                              hipStream_t stream) {
  const float* C = (const float*)d_in[0];
  const float* Q = (const float*)d_in[1];
  const float* c_mask = (const float*)d_in[2];
  const float* q_mask = (const float*)d_in[3];
  const float* W0 = (const float*)d_in[4];
  const float* dwW = (const float*)d_in[5];
  const float* dwB = (const float*)d_in[6];
  const float* pwW = (const float*)d_in[7];
  const float* pwB = (const float*)d_in[8];
  float* out = (float*)d_out;
  float* ws = (float*)d_ws;

  float* rowmax = ws;                                  // NB*NC
  float* rowsum = rowmax + NB * NC;
  float* colmax = rowsum + NB * NC;                    // NB*NQ
  float* colsum = colmax + NB * NQ;
  float* cb = colsum + NB * NQ;                        // NB*NC
  float* qb = cb + NB * NC;                            // NB*NQ
  float* colPm = qb + NB * NQ;                         // 16*NB*NQ
  float* colPs = colPm + 16 * NB * NQ;                 // 16*NB*NQ
  unsigned short* qSwz = (unsigned short*)(colPs + 16 * NB * NQ);   // NB*ND*NQ
  unsigned short* qT = qSwz + (size_t)NB * ND * NQ;                 // NB*NQ*ND
  unsigned short* iSwz = qT + (size_t)NB * NQ * ND;                 // NB*ND*NQ
  unsigned short* cw3T = iSwz + (size_t)NB * ND * NQ;               // NB*NC*ND
  unsigned short* cSwz = cw3T + (size_t)NB * NC * ND;               // NB*ND*NC
  unsigned short* pwB16 = cSwz + (size_t)NB * ND * NC;              // 128*512
  float* partial = (float*)(pwB16 + ND * 512);                      // 2*NB*ND*NQ f32
  unsigned short* xB = (unsigned short*)(partial + 2 * (size_t)NB * ND * NQ);  // NB*4*ND*NC

  k_pwcvt<<<dim3(32), 256, 0, stream>>>(pwW, pwB16);
  k_qprep<<<dim3(4, NB), 256, 0, stream>>>(Q, W0, qSwz, qT, qb);
  k_cprep<<<dim3(16, NB), 256, 0, stream>>>(C, W0, cw3T, cSwz, cb);
  k_stats<<<dim3(16, NB), 256, 0, stream>>>(cw3T, qT, cb, qb, q_mask, c_mask, rowmax, rowsum, colPm, colPs);
  k3c_combine<<<dim3(NB * NQ / 256), 256, 0, stream>>>(colPm, colPs, colmax, colsum);
  k4f<<<dim3(16, NB), 256, 0, stream>>>(cw3T, qT, cSwz, cb, qb, c_mask, colmax, colsum, partial);
  k4c2<<<dim3(NB * ND * NQ / 4 / 256), 256, 0, stream>>>(partial, iSwz);
  k5f<<<dim3(NC / 32, NB), 256, 45056, stream>>>(cw3T, qT, qSwz, iSwz, C, cb, qb, q_mask, rowmax, rowsum, xB);
  k6_mfma<<<dim3(NC / 32, NB), 256, 30208, stream>>>(xB, dwW, dwB, pwB16, pwB, out);
}

// Round 10
// 119.388 us; speedup vs baseline: 5.8072x; 1.2308x over previous
//
#include <hip/hip_runtime.h>
#include <math.h>

#define NB 32
#define ND 128
#define NC 1024
#define NQ 256
#define NEGV (-1e30f)

typedef __attribute__((ext_vector_type(8))) __bf16 bf16x8;
typedef __attribute__((ext_vector_type(4))) float f32x4;
typedef __attribute__((ext_vector_type(8))) unsigned short u16x8;
typedef __attribute__((ext_vector_type(4))) unsigned short u16x4;

__device__ inline unsigned short f2bf(float f) {
  unsigned u = __builtin_bit_cast(unsigned, f);
  u += 0x7FFFu + ((u >> 16) & 1u);
  return (unsigned short)(u >> 16);
}
__device__ inline float bf2f(unsigned short u) {
  return __builtin_bit_cast(float, (unsigned)u << 16);
}

// ---------------- K0b: pwW f32 -> bf16
__global__ __launch_bounds__(256) void k_pwcvt(const float* __restrict__ pwW, unsigned short* __restrict__ pwB16) {
  int idx = blockIdx.x * 256 + threadIdx.x;   // 0..8191
  const float4* src = (const float4*)pwW;
  float4 v0 = src[idx * 2], v1 = src[idx * 2 + 1];
  u16x8 o;
  o[0] = f2bf(v0.x); o[1] = f2bf(v0.y); o[2] = f2bf(v0.z); o[3] = f2bf(v0.w);
  o[4] = f2bf(v1.x); o[5] = f2bf(v1.y); o[6] = f2bf(v1.z); o[7] = f2bf(v1.w);
  ((u16x8*)pwB16)[idx] = o;
}

// ---------------- k_qprep: one Q pass -> qSwz [b][d][j-slots], qT [b][j][d-slots], qb
__global__ __launch_bounds__(256) void k_qprep(const float* __restrict__ Q, const float* __restrict__ W0,
                                               unsigned short* __restrict__ qSwz, unsigned short* __restrict__ qT,
                                               float* __restrict__ qb) {
  __shared__ unsigned short T2[128 * 66];
  __shared__ float w2L[128];
  __shared__ float qbP[4][64];
  int b = blockIdx.y, jc = blockIdx.x, j0 = jc * 64, t = threadIdx.x;
  if (t < 128) w2L[t] = W0[ND + t];
  int d = t >> 1, half = t & 1;
  const float* src = Q + ((size_t)b * ND + d) * NQ + j0 + half * 32;
  unsigned short* qdst = qSwz + ((size_t)b * ND + d) * NQ + jc * 64;
  #pragma unroll
  for (int q = 0; q < 4; ++q) {
    float4 v0 = ((const float4*)src)[q * 2];
    float4 v1 = ((const float4*)src)[q * 2 + 1];
    u16x8 o;
    o[0] = f2bf(v0.x); o[1] = f2bf(v0.y); o[2] = f2bf(v0.z); o[3] = f2bf(v0.w);
    o[4] = f2bf(v1.x); o[5] = f2bf(v1.y); o[6] = f2bf(v1.z); o[7] = f2bf(v1.w);
    *(u16x8*)&T2[d * 66 + half * 32 + q * 8] = o;
    int g = half * 4 + q;
    *(u16x8*)&qdst[(g ^ (d & 7)) * 8] = o;
  }
  __syncthreads();
  {
    int jj = t & 63, dq = t >> 6;
    float s = 0.f;
    #pragma unroll 8
    for (int k = 0; k < 32; ++k) {
      int dd = dq * 32 + k;
      s += bf2f(T2[dd * 66 + jj]) * w2L[dd];
    }
    qbP[dq][jj] = s;
  }
  __syncthreads();
  if (t < 64)
    qb[b * NQ + j0 + t] = qbP[0][t] + qbP[1][t] + qbP[2][t] + qbP[3][t];
  {
    int jj = t >> 2, p = t & 3;
    unsigned short* dst = qT + ((size_t)b * NQ + j0 + jj) * ND;
    #pragma unroll
    for (int q = 0; q < 4; ++q) {
      int g = p * 4 + q;
      u16x8 o;
      #pragma unroll
      for (int e = 0; e < 8; ++e) o[e] = T2[(g * 8 + e) * 66 + jj];
      int sg = (g & 8) | ((g & 7) ^ (jj & 7));
      *(u16x8*)&dst[sg * 8] = o;
    }
  }
}

// ---------------- k_cprep: one C pass -> cw3T [b][i][k-slots], cSwz [b][d][i-slots], cb
__global__ __launch_bounds__(256) void k_cprep(const float* __restrict__ C, const float* __restrict__ W0,
                                               unsigned short* __restrict__ cw3T, unsigned short* __restrict__ cSwz,
                                               float* __restrict__ cb) {
  __shared__ unsigned short T2[128 * 66];
  __shared__ float w1L[128], w3L[128];
  __shared__ float cbP[4][64];
  int b = blockIdx.y, i0 = blockIdx.x * 64, t = threadIdx.x;
  if (t < 128) { w1L[t] = W0[t]; w3L[t] = W0[2 * ND + t]; }
  int k = t >> 1, half = t & 1;
  const float* src = C + ((size_t)b * ND + k) * NC + i0 + half * 32;
  unsigned short* cdst = cSwz + ((size_t)b * ND + k) * NC + blockIdx.x * 64;
  #pragma unroll
  for (int q = 0; q < 4; ++q) {
    float4 v0 = ((const float4*)src)[q * 2];
    float4 v1 = ((const float4*)src)[q * 2 + 1];
    u16x8 o;
    o[0] = f2bf(v0.x); o[1] = f2bf(v0.y); o[2] = f2bf(v0.z); o[3] = f2bf(v0.w);
    o[4] = f2bf(v1.x); o[5] = f2bf(v1.y); o[6] = f2bf(v1.z); o[7] = f2bf(v1.w);
    *(u16x8*)&T2[k * 66 + half * 32 + q * 8] = o;
    int g = half * 4 + q;
    *(u16x8*)&cdst[(g ^ (k & 7)) * 8] = o;
  }
  __syncthreads();
  {
    int ii = t & 63, kq = t >> 6;
    float s = 0.f;
    #pragma unroll 8
    for (int kk = 0; kk < 32; ++kk) {
      int dd = kq * 32 + kk;
      s += bf2f(T2[dd * 66 + ii]) * w1L[dd];
    }
    cbP[kq][ii] = s;
  }
  __syncthreads();
  if (t < 64)
    cb[b * NC + i0 + t] = cbP[0][t] + cbP[1][t] + cbP[2][t] + cbP[3][t];
  {
    int ii = t >> 2, p = t & 3;
    unsigned short* dst = cw3T + ((size_t)b * NC + i0 + ii) * ND;
    #pragma unroll
    for (int q = 0; q < 4; ++q) {
      int g = p * 4 + q;
      u16x8 o;
      #pragma unroll
      for (int e = 0; e < 8; ++e)
        o[e] = f2bf(bf2f(T2[(g * 8 + e) * 66 + ii]) * w3L[g * 8 + e]);
      int sg = (g & 8) | ((g & 7) ^ (ii & 7));
      *(u16x8*)&dst[sg * 8] = o;
    }
  }
}

// ---------------- k_stats: MFMA S + full row stats + col partials (no S output). Tile 64i x 256j.
__global__ __launch_bounds__(256) void k_stats(const unsigned short* __restrict__ cw3T,
                                               const unsigned short* __restrict__ qT,
                                               const float* __restrict__ cb, const float* __restrict__ qb,
                                               const float* __restrict__ q_mask, const float* __restrict__ c_mask,
                                               float* __restrict__ rowmax, float* __restrict__ rowsum,
                                               float* __restrict__ colPm, float* __restrict__ colPs) {
  __shared__ float rmP[64][4], rsP[64][4];
  __shared__ float cbL[64], cmL[64], qbL[256], qmL[256];
  int b = blockIdx.y, i0 = blockIdx.x * 64;
  int t = threadIdx.x, w = t >> 6, l = t & 63, h = l >> 4, lr = l & 15;
  int wj = w * 64;
  if (t < 64) { cbL[t] = cb[b * NC + i0 + t]; cmL[t] = c_mask[b * NC + i0 + t]; }
  qbL[t] = qb[b * NQ + t];
  qmL[t] = q_mask[b * NQ + t];
  const unsigned short* Arow = cw3T + ((size_t)b * NC + i0) * ND;
  const unsigned short* Brow = qT + (size_t)b * NQ * ND;
  f32x4 acc[4][4] = {};
  #pragma unroll
  for (int ks = 0; ks < 4; ++ks) {
    int g = ks * 4 + h;
    int off = ((g & 8) | ((g & 7) ^ (lr & 7))) * 8;
    bf16x8 a[4], bq[4];
    #pragma unroll
    for (int mi = 0; mi < 4; ++mi)
      a[mi] = *(const bf16x8*)&Arow[(size_t)(mi * 16 + lr) * ND + off];
    #pragma unroll
    for (int nf = 0; nf < 4; ++nf)
      bq[nf] = *(const bf16x8*)&Brow[(size_t)(wj + nf * 16 + lr) * ND + off];
    #pragma unroll
    for (int mi = 0; mi < 4; ++mi)
      #pragma unroll
      for (int nf = 0; nf < 4; ++nf)
        acc[mi][nf] = __builtin_amdgcn_mfma_f32_16x16x32_bf16(a[mi], bq[nf], acc[mi][nf], 0, 0, 0);
  }
  __syncthreads();
  float qbv[4], qmv[4];
  #pragma unroll
  for (int nf = 0; nf < 4; ++nf) {
    int j = wj + nf * 16 + lr;
    qbv[nf] = qbL[j]; qmv[nf] = qmL[j];
  }
  float rmv[4][4], rsv[4][4];
  #pragma unroll
  for (int mi = 0; mi < 4; ++mi)
    #pragma unroll
    for (int r = 0; r < 4; ++r) { rmv[mi][r] = -3.0e38f; rsv[mi][r] = 0.f; }
  #pragma unroll
  for (int mi = 0; mi < 4; ++mi) {
    #pragma unroll
    for (int r = 0; r < 4; ++r) {
      int row = mi * 16 + h * 4 + r;
      float cbr = cbL[row];
      #pragma unroll
      for (int nf = 0; nf < 4; ++nf) {
        float sv = acc[mi][nf][r] + cbr + qbv[nf];
        acc[mi][nf][r] = sv;
        float vq = sv * qmv[nf] + NEGV * (1.f - qmv[nf]);
        float mn = fmaxf(rmv[mi][r], vq);
        rsv[mi][r] = rsv[mi][r] * __expf(rmv[mi][r] - mn) + __expf(vq - mn);
        rmv[mi][r] = mn;
      }
    }
  }
  #pragma unroll
  for (int off = 1; off < 16; off <<= 1) {
    #pragma unroll
    for (int mi = 0; mi < 4; ++mi)
      #pragma unroll
      for (int r = 0; r < 4; ++r) {
        float mo = __shfl_xor(rmv[mi][r], off);
        float so = __shfl_xor(rsv[mi][r], off);
        float mn = fmaxf(rmv[mi][r], mo);
        rsv[mi][r] = rsv[mi][r] * __expf(rmv[mi][r] - mn) + so * __expf(mo - mn);
        rmv[mi][r] = mn;
      }
  }
  if (lr == 0) {
    #pragma unroll
    for (int mi = 0; mi < 4; ++mi)
      #pragma unroll
      for (int r = 0; r < 4; ++r) {
        rmP[mi * 16 + h * 4 + r][w] = rmv[mi][r];
        rsP[mi * 16 + h * 4 + r][w] = rsv[mi][r];
      }
  }
  float pm[4], ps[4];
  #pragma unroll
  for (int nf = 0; nf < 4; ++nf) { pm[nf] = -3.0e38f; ps[nf] = 0.f; }
  #pragma unroll
  for (int mi = 0; mi < 4; ++mi)
    #pragma unroll
    for (int r = 0; r < 4; ++r) {
      int row = mi * 16 + h * 4 + r;
      float cm = cmL[row];
      float cbias = NEGV * (1.f - cm);
      #pragma unroll
      for (int nf = 0; nf < 4; ++nf) {
        float v = acc[mi][nf][r] * cm + cbias;
        float mn = fmaxf(pm[nf], v);
        ps[nf] = ps[nf] * __expf(pm[nf] - mn) + __expf(v - mn);
        pm[nf] = mn;
      }
    }
  #pragma unroll
  for (int off = 16; off < 64; off <<= 1) {
    #pragma unroll
    for (int nf = 0; nf < 4; ++nf) {
      float mo = __shfl_xor(pm[nf], off);
      float so = __shfl_xor(ps[nf], off);
      float mn = fmaxf(pm[nf], mo);
      ps[nf] = ps[nf] * __expf(pm[nf] - mn) + so * __expf(mo - mn);
      pm[nf] = mn;
    }
  }
  if (h == 0) {
    #pragma unroll
    for (int nf = 0; nf < 4; ++nf) {
      int j = wj + nf * 16 + lr;
      colPm[((size_t)blockIdx.x * NB + b) * NQ + j] = pm[nf];
      colPs[((size_t)blockIdx.x * NB + b) * NQ + j] = ps[nf];
    }
  }
  __syncthreads();
  if (t < 64) {
    float m = rmP[t][0], s = rsP[t][0];
    #pragma unroll
    for (int k = 1; k < 4; ++k) {
      float mo = rmP[t][k], so = rsP[t][k];
      float mn = fmaxf(m, mo);
      s = s * __expf(m - mn) + so * __expf(mo - mn);
      m = mn;
    }
    rowmax[b * NC + i0 + t] = m;
    rowsum[b * NC + i0 + t] = s;
  }
}

// ---------------- K3c: combine 16 col partials
__global__ __launch_bounds__(256) void k3c_combine(const float* __restrict__ colPm, const float* __restrict__ colPs,
                                                   float* __restrict__ colmax, float* __restrict__ colsum) {
  int idx = blockIdx.x * 256 + threadIdx.x;   // b*NQ + j
  float m = -3.0e38f, s = 0.f;
  #pragma unroll
  for (int tl = 0; tl < 16; ++tl) {
    float mo = colPm[(size_t)tl * NB * NQ + idx];
    float so = colPs[(size_t)tl * NB * NQ + idx];
    float mn = fmaxf(m, mo);
    s = s * __expf(m - mn) + so * __expf(mo - mn);
    m = mn;
  }
  colmax[idx] = m; colsum[idx] = s;
}

// ---------------- k4f: fused S -> P_bbar^T -> inner (split-i 2). Block: 128d x 32j.
// All GEMM operands read direct from global (L2); only P^T tile in LDS (rows padded to 72).
__global__ __launch_bounds__(256) void k4f(const unsigned short* __restrict__ cw3T,
                                           const unsigned short* __restrict__ qT,
                                           const unsigned short* __restrict__ cSwz,
                                           const float* __restrict__ cb, const float* __restrict__ qb,
                                           const float* __restrict__ c_mask,
                                           const float* __restrict__ colmax, const float* __restrict__ colsum,
                                           float* __restrict__ partial) {
  __shared__ unsigned short Pt[32 * 72];     // P^T operand, padded rows
  __shared__ float cmxL[32], cinvL[32], qbL2[32], cbL[64], cmL[64];
  int b = blockIdx.y;
  int jt = blockIdx.x & 7, split = blockIdx.x >> 3;
  int j0 = jt * 32;
  int t = threadIdx.x, w = t >> 6, l = t & 63, h = l >> 4, lr = l & 15;
  if (t < 32) {
    cmxL[t] = colmax[b * NQ + j0 + t];
    cinvL[t] = 1.0f / colsum[b * NQ + j0 + t];
    qbL2[t] = qb[b * NQ + j0 + t];
  }
  const unsigned short* Ab = cw3T + (size_t)b * NC * ND;
  const unsigned short* Bb = qT + ((size_t)b * NQ + j0) * ND;
  const unsigned short* Cb2 = cSwz + (size_t)b * ND * NC;
  f32x4 accI[2][2] = {};
  for (int ic8 = 0; ic8 < 8; ++ic8) {
    int ic = split * 512 + ic8 * 64;
    if (t < 64) { cbL[t] = cb[b * NC + ic + t]; cmL[t] = c_mask[b * NC + ic + t]; }
    __syncthreads();
    // phase A: S chunk [64i x 32j], frags direct from global
    f32x4 sA[2] = {};
    #pragma unroll
    for (int ks = 0; ks < 4; ++ks) {
      int g = ks * 4 + h;
      int off = ((g & 8) | ((g & 7) ^ (lr & 7))) * 8;
      bf16x8 av = *(const bf16x8*)&Ab[(size_t)(ic + w * 16 + lr) * ND + off];
      #pragma unroll
      for (int jf = 0; jf < 2; ++jf) {
        bf16x8 bv = *(const bf16x8*)&Bb[(size_t)(jf * 16 + lr) * ND + off];
        sA[jf] = __builtin_amdgcn_mfma_f32_16x16x32_bf16(av, bv, sA[jf], 0, 0, 0);
      }
    }
    #pragma unroll
    for (int jf = 0; jf < 2; ++jf)
      #pragma unroll
      for (int r = 0; r < 4; ++r) {
        int i_ = w * 16 + h * 4 + r;
        int j_ = jf * 16 + lr;
        float sfull = sA[jf][r] + cbL[i_] + qbL2[j_];
        float cm = cmL[i_];
        float vc = sfull * cm + NEGV * (1.f - cm);
        float p = __expf(vc - cmxL[j_]) * cinvL[j_];
        Pt[j_ * 72 + (((i_ >> 3) ^ (j_ & 7)) << 3) + (i_ & 7)] = f2bf(p);
      }
    __syncthreads();
    // phase B: inner += C x P^T (C frags direct from global)
    #pragma unroll
    for (int ks = 0; ks < 2; ++ks) {
      bf16x8 aC[2], bP[2];
      #pragma unroll
      for (int mf = 0; mf < 2; ++mf) {
        int d = w * 32 + mf * 16 + lr;
        aC[mf] = *(const bf16x8*)&Cb2[(size_t)d * NC + ic + (((ks * 4 + h) ^ (lr & 7)) * 8)];
      }
      #pragma unroll
      for (int jf = 0; jf < 2; ++jf) {
        int j_ = jf * 16 + lr;
        bP[jf] = *(const bf16x8*)&Pt[j_ * 72 + (((ks * 4 + h) ^ (j_ & 7)) * 8)];
      }
      #pragma unroll
      for (int mf = 0; mf < 2; ++mf)
        #pragma unroll
        for (int jf = 0; jf < 2; ++jf)
          accI[mf][jf] = __builtin_amdgcn_mfma_f32_16x16x32_bf16(aC[mf], bP[jf], accI[mf][jf], 0, 0, 0);
    }
  }
  float* pout = partial + ((size_t)(split * NB + b) * ND) * NQ;
  #pragma unroll
  for (int mf = 0; mf < 2; ++mf)
    #pragma unroll
    for (int jf = 0; jf < 2; ++jf)
      #pragma unroll
      for (int r = 0; r < 4; ++r) {
        int d = w * 32 + mf * 16 + h * 4 + r;
        int j = j0 + jf * 16 + lr;
        pout[(size_t)d * NQ + j] = accI[mf][jf][r];
      }
}

// ---------------- k4c2: combine 2 split partials -> bf16 iSwz (pre-swizzled)
__global__ __launch_bounds__(256) void k4c2(const float* __restrict__ partial,
                                            unsigned short* __restrict__ iSwz) {
  int idx = blockIdx.x * 256 + threadIdx.x;   // over NB*ND*NQ/4
  const size_t n = (size_t)NB * ND * NQ / 4;
  const float4* p = (const float4*)partial;
  float4 a = p[idx], b4 = p[n + idx];
  u16x4 o;
  o[0] = f2bf(a.x + b4.x);
  o[1] = f2bf(a.y + b4.y);
  o[2] = f2bf(a.z + b4.z);
  o[3] = f2bf(a.w + b4.w);
  int lin = idx * 4;
  int j = lin & 255, dd = (lin >> 8) & 127, bb = lin >> 15;
  int g = (j >> 3) & 7, e0 = j & 7;
  int outoff = ((bb * 128 + dd) << 8) + (j & 192) + ((g ^ (dd & 7)) << 3) + e0;
  *(u16x4*)&iSwz[outoff] = o;
}

// ---------------- k5f: fused S -> P_bar -> {A, Bm} -> concat x (bf16). Block: 32i x 128d.
// Operand frags direct from global; LDS only for cwA (reused) + P (padded rows) + epilogue.
__global__ __launch_bounds__(256) void k5f(const unsigned short* __restrict__ cw3T,
                                           const unsigned short* __restrict__ qT,
                                           const unsigned short* __restrict__ qSwz,
                                           const unsigned short* __restrict__ iSwz,
                                           const float* __restrict__ C,
                                           const float* __restrict__ cb, const float* __restrict__ qb,
                                           const float* __restrict__ q_mask,
                                           const float* __restrict__ rowmax, const float* __restrict__ rowsum,
                                           unsigned short* __restrict__ xB) {
  extern __shared__ char sm[];
  unsigned short* cwA = (unsigned short*)sm;            // [32][128] 8KB
  unsigned short* Pl = (unsigned short*)(sm + 8192);    // [32][72] 4.6KB
  float* As = (float*)sm;                               // epilogue alias [32][133]
  float* Bs = (float*)(sm + 17024);
  __shared__ float rmL[32], riL[32], cbI[32], qbL[256], qmL[256];
  int b = blockIdx.y, i0 = blockIdx.x * 32;
  int t = threadIdx.x, w = t >> 6, l = t & 63, h = l >> 4, lr = l & 15;
  {
    const unsigned short* src = cw3T + ((size_t)b * NC + i0) * ND;   // 32x128 contiguous
    #pragma unroll
    for (int k = 0; k < 2; ++k) {
      int u = t + k * 256;
      *(u16x8*)&cwA[u * 8] = *(const u16x8*)(src + u * 8);
    }
  }
  if (t < 32) {
    rmL[t] = rowmax[b * NC + i0 + t];
    riL[t] = 1.0f / rowsum[b * NC + i0 + t];
    cbI[t] = cb[b * NC + i0 + t];
  }
  qbL[t] = qb[b * NQ + t];
  qmL[t] = q_mask[b * NQ + t];
  __syncthreads();

  const unsigned short* qTb = qT + (size_t)b * NQ * ND;
  const unsigned short* qSb = qSwz + (size_t)b * ND * NQ;
  const unsigned short* iSb = iSwz + (size_t)b * ND * NQ;
  f32x4 accA[2][2] = {};
  f32x4 accB[2][2] = {};

  for (int jc = 0; jc < 4; ++jc) {
    int j0 = jc * 64;
    // phase A: S [32i x 64j]; B-frags direct from qT global
    f32x4 sA[2] = {};
    #pragma unroll
    for (int ks = 0; ks < 4; ++ks) {
      int g = ks * 4 + h;
      int off = ((g & 8) | ((g & 7) ^ (lr & 7))) * 8;
      bf16x8 bv = *(const bf16x8*)&qTb[(size_t)(j0 + w * 16 + lr) * ND + off];
      #pragma unroll
      for (int mi = 0; mi < 2; ++mi) {
        bf16x8 av = *(const bf16x8*)&cwA[(mi * 16 + lr) * 128 + off];
        sA[mi] = __builtin_amdgcn_mfma_f32_16x16x32_bf16(av, bv, sA[mi], 0, 0, 0);
      }
    }
    #pragma unroll
    for (int mi = 0; mi < 2; ++mi)
      #pragma unroll
      for (int r = 0; r < 4; ++r) {
        int i_ = mi * 16 + h * 4 + r;
        int j_ = w * 16 + lr;
        float sfull = sA[mi][r] + cbI[i_] + qbL[j0 + j_];
        float qm = qmL[j0 + j_];
        float vq = sfull * qm + NEGV * (1.f - qm);
        float p = __expf(vq - rmL[i_]) * riL[i_];
        Pl[i_ * 72 + (((j_ >> 3) ^ (i_ & 7)) << 3) + (j_ & 7)] = f2bf(p);
      }
    __syncthreads();
    // phase B: A += P x Q^T, Bm += P x inner (B-frags direct from global)
    #pragma unroll
    for (int ks = 0; ks < 2; ++ks) {
      bf16x8 aP[2], bQ[2], bI[2];
      #pragma unroll
      for (int mi = 0; mi < 2; ++mi) {
        int i = mi * 16 + lr;
        int slot = (ks * 4 + h) ^ (i & 7);
        aP[mi] = *(const bf16x8*)&Pl[i * 72 + slot * 8];
      }
      #pragma unroll
      for (int nd = 0; nd < 2; ++nd) {
        int d = w * 32 + nd * 16 + lr;
        int slot = (ks * 4 + h) ^ (d & 7);
        bQ[nd] = *(const bf16x8*)&qSb[(size_t)d * NQ + j0 + slot * 8];
        bI[nd] = *(const bf16x8*)&iSb[(size_t)d * NQ + j0 + slot * 8];
      }
      #pragma unroll
      for (int mi = 0; mi < 2; ++mi)
        #pragma unroll
        for (int nd = 0; nd < 2; ++nd) {
          accA[mi][nd] = __builtin_amdgcn_mfma_f32_16x16x32_bf16(aP[mi], bQ[nd], accA[mi][nd], 0, 0, 0);
          accB[mi][nd] = __builtin_amdgcn_mfma_f32_16x16x32_bf16(aP[mi], bI[nd], accB[mi][nd], 0, 0, 0);
        }
    }
    __syncthreads();
  }
  // epilogue (aliases cwA/Pl region)
  #pragma unroll
  for (int mi = 0; mi < 2; ++mi)
    #pragma unroll
    for (int nd = 0; nd < 2; ++nd) {
      int d = w * 32 + nd * 16 + lr;
      #pragma unroll
      for (int r = 0; r < 4; ++r) {
        int i = mi * 16 + h * 4 + r;
        As[i * 133 + d] = accA[mi][nd][r];
        Bs[i * 133 + d] = accB[mi][nd][r];
      }
    }
  __syncthreads();
  {
    int i4 = (t & 7) * 4, db = t >> 3;
    const float* Cb = C + (size_t)b * ND * NC;
    unsigned short* xb = xB + (size_t)b * 4 * ND * NC;
    #pragma unroll
    for (int p = 0; p < 4; ++p) {
      int d = db + p * 32;
      float4 c4 = *(const float4*)&Cb[(size_t)d * NC + i0 + i4];
      float4 a4, b4;
      a4.x = As[(i4 + 0) * 133 + d]; a4.y = As[(i4 + 1) * 133 + d];
      a4.z = As[(i4 + 2) * 133 + d]; a4.w = As[(i4 + 3) * 133 + d];
      b4.x = Bs[(i4 + 0) * 133 + d]; b4.y = Bs[(i4 + 1) * 133 + d];
      b4.z = Bs[(i4 + 2) * 133 + d]; b4.w = Bs[(i4 + 3) * 133 + d];
      u16x4 o0, o1, o2, o3;
      o0[0] = f2bf(c4.x); o0[1] = f2bf(c4.y); o0[2] = f2bf(c4.z); o0[3] = f2bf(c4.w);
      o1[0] = f2bf(a4.x); o1[1] = f2bf(a4.y); o1[2] = f2bf(a4.z); o1[3] = f2bf(a4.w);
      o2[0] = f2bf(c4.x * a4.x); o2[1] = f2bf(c4.y * a4.y); o2[2] = f2bf(c4.z * a4.z); o2[3] = f2bf(c4.w * a4.w);
      o3[0] = f2bf(c4.x * b4.x); o3[1] = f2bf(c4.y * b4.y); o3[2] = f2bf(c4.z * b4.z); o3[3] = f2bf(c4.w * b4.w);
      *(u16x4*)&xb[(size_t)(0 * ND + d) * NC + i0 + i4] = o0;
      *(u16x4*)&xb[(size_t)(1 * ND + d) * NC + i0 + i4] = o1;
      *(u16x4*)&xb[(size_t)(2 * ND + d) * NC + i0 + i4] = o2;
      *(u16x4*)&xb[(size_t)(3 * ND + d) * NC + i0 + i4] = o3;
    }
  }
}

// ---------------- K6 (MFMA): depthwise(k=5,pad2) + pointwise GEMM
__global__ __launch_bounds__(256) void k6_mfma(const unsigned short* __restrict__ x,
                                               const float* __restrict__ dwW, const float* __restrict__ dwB,
                                               const unsigned short* __restrict__ pwB16,
                                               const float* __restrict__ pwB, float* __restrict__ out) {
  extern __shared__ char sm6[];
  unsigned short* xs = (unsigned short*)sm6;            // [64][56]
  unsigned short* x1s = (unsigned short*)(sm6 + 7168);  // [32][72]
  unsigned short* pws = (unsigned short*)(sm6 + 11776); // [128][72]
  int b = blockIdx.y, l0 = blockIdx.x * 32;
  int t = threadIdx.x, w = t >> 6, l = t & 63, h = l >> 4, lr = l & 15;
  const unsigned short* xb = x + (size_t)b * 4 * ND * NC;
  f32x4 acc[2][2] = {};
  int cgw = t & 63, lb = w * 8;

  for (int ch = 0; ch < 8; ++ch) {
    int cg0 = ch * 64;
    __syncthreads();
    #pragma unroll
    for (int k = 0; k < 2; ++k) {
      int id2 = t + k * 256;
      if (id2 < 384) {
        int row = id2 / 6, seg = id2 % 6;
        int gl = l0 - 8 + seg * 8;
        u16x8 v = {};
        if ((unsigned)gl <= 1016u)
          v = *(const u16x8*)(xb + (size_t)(cg0 + row) * NC + gl);
        *(u16x8*)&xs[row * 56 + seg * 8] = v;
      }
    }
    #pragma unroll
    for (int k = 0; k < 4; ++k) {
      int id2 = t + k * 256;
      int o = id2 >> 3, s8 = id2 & 7;
      *(u16x8*)&pws[o * 72 + s8 * 8] = *(const u16x8*)(pwB16 + (size_t)o * 512 + cg0 + s8 * 8);
    }
    __syncthreads();
    {
      int gch = cg0 + cgw;
      float bias = dwB[gch];
      float dwv[5];
      #pragma unroll
      for (int tp = 0; tp < 5; ++tp) dwv[tp] = dwW[gch * 5 + tp];
      float f[24];
      #pragma unroll
      for (int s = 0; s < 3; ++s) {
        u16x8 v = *(const u16x8*)&xs[cgw * 56 + lb + s * 8];
        #pragma unroll
        for (int e = 0; e < 8; ++e) f[s * 8 + e] = bf2f(v[e]);
      }
      #pragma unroll
      for (int e = 0; e < 8; ++e) {
        float a = bias;
        #pragma unroll
        for (int tp = 0; tp < 5; ++tp)
          a = fmaf(f[e + 6 + tp], dwv[tp], a);
        x1s[(lb + e) * 72 + cgw] = f2bf(a);
      }
    }
    __syncthreads();
    #pragma unroll
    for (int ks = 0; ks < 2; ++ks) {
      bf16x8 aW[2], bX[2];
      #pragma unroll
      for (int mi = 0; mi < 2; ++mi) {
        int o = w * 32 + mi * 16 + lr;
        aW[mi] = *(const bf16x8*)&pws[o * 72 + ks * 32 + h * 8];
      }
      #pragma unroll
      for (int nf = 0; nf < 2; ++nf) {
        int ll = nf * 16 + lr;
        bX[nf] = *(const bf16x8*)&x1s[ll * 72 + ks * 32 + h * 8];
      }
      #pragma unroll
      for (int mi = 0; mi < 2; ++mi)
        #pragma unroll
        for (int nf = 0; nf < 2; ++nf)
          acc[mi][nf] = __builtin_amdgcn_mfma_f32_16x16x32_bf16(aW[mi], bX[nf], acc[mi][nf], 0, 0, 0);
    }
  }
  #pragma unroll
  for (int mi = 0; mi < 2; ++mi) {
    #pragma unroll
    for (int r = 0; r < 4; ++r) {
      int o = w * 32 + mi * 16 + h * 4 + r;
      float bv = pwB[o];
      #pragma unroll
      for (int nf = 0; nf < 2; ++nf)
        out[((size_t)b * ND + o) * NC + l0 + nf * 16 + lr] = acc[mi][nf][r] + bv;
    }
  }
}

extern "C" void kernel_launch(void* const* d_in, const int* in_sizes, int n_in,
                              void* d_out, int out_size, void* d_ws, size_t ws_size,
                              hipStream_t stream) {
  const float* C = (const float*)d_in[0];
  const float* Q = (const float*)d_in[1];
  const float* c_mask = (const float*)d_in[2];
  const float* q_mask = (const float*)d_in[3];
  const float* W0 = (const float*)d_in[4];
  const float* dwW = (const float*)d_in[5];
  const float* dwB = (const float*)d_in[6];
  const float* pwW = (const float*)d_in[7];
  const float* pwB = (const float*)d_in[8];
  float* out = (float*)d_out;
  float* ws = (float*)d_ws;

  float* rowmax = ws;                                  // NB*NC
  float* rowsum = rowmax + NB * NC;
  float* colmax = rowsum + NB * NC;                    // NB*NQ
  float* colsum = colmax + NB * NQ;
  float* cb = colsum + NB * NQ;                        // NB*NC
  float* qb = cb + NB * NC;                            // NB*NQ
  float* colPm = qb + NB * NQ;                         // 16*NB*NQ
  float* colPs = colPm + 16 * NB * NQ;                 // 16*NB*NQ
  unsigned short* qSwz = (unsigned short*)(colPs + 16 * NB * NQ);   // NB*ND*NQ
  unsigned short* qT = qSwz + (size_t)NB * ND * NQ;                 // NB*NQ*ND
  unsigned short* iSwz = qT + (size_t)NB * NQ * ND;                 // NB*ND*NQ
  unsigned short* cw3T = iSwz + (size_t)NB * ND * NQ;               // NB*NC*ND
  unsigned short* cSwz = cw3T + (size_t)NB * NC * ND;               // NB*ND*NC
  unsigned short* pwB16 = cSwz + (size_t)NB * ND * NC;              // 128*512
  float* partial = (float*)(pwB16 + ND * 512);                      // 2*NB*ND*NQ f32
  unsigned short* xB = (unsigned short*)(partial + 2 * (size_t)NB * ND * NQ);  // NB*4*ND*NC

  k_pwcvt<<<dim3(32), 256, 0, stream>>>(pwW, pwB16);
  k_qprep<<<dim3(4, NB), 256, 0, stream>>>(Q, W0, qSwz, qT, qb);
  k_cprep<<<dim3(16, NB), 256, 0, stream>>>(C, W0, cw3T, cSwz, cb);
  k_stats<<<dim3(16, NB), 256, 0, stream>>>(cw3T, qT, cb, qb, q_mask, c_mask, rowmax, rowsum, colPm, colPs);
  k3c_combine<<<dim3(NB * NQ / 256), 256, 0, stream>>>(colPm, colPs, colmax, colsum);
  k4f<<<dim3(16, NB), 256, 0, stream>>>(cw3T, qT, cSwz, cb, qb, c_mask, colmax, colsum, partial);
  k4c2<<<dim3(NB * ND * NQ / 4 / 256), 256, 0, stream>>>(partial, iSwz);
  k5f<<<dim3(NC / 32, NB), 256, 34048, stream>>>(cw3T, qT, qSwz, iSwz, C, cb, qb, q_mask, rowmax, rowsum, xB);
  k6_mfma<<<dim3(NC / 32, NB), 256, 30208, stream>>>(xB, dwW, dwB, pwB16, pwB, out);
}